// Round 2
// 729.224 us; speedup vs baseline: 1.1915x; 1.1915x over previous
//
#include <hip/hip_runtime.h>
#include <stdint.h>

// FCOS bbox post-processing, B=4 images — bit-exact np/XLA-f32 replication
// (R7 semantics). R12: sparse-pair NMS. R13: kill same-address global-atomic
// serialization:
//  - k_compact: LDS-staged allocation; one global atomicAdd per (block,level)
//    instead of one per selected element (18,880 same-line atomics -> ~1.3k).
//    Downstream (k_emit/k_ties) rank by value, so entry order is free.
//  - k_sortimg: block-level max reduction; one atomicMax per block (76 total)
//    instead of per-element (18,880 on a single cacheline).

#define BN 4
#define NC 80
#define TOT 170720       // 128000+32000+8000+2000+720
#define KTOT 4720        // 1000*4+720
#define NWORDS 74        // ceil(4720/64)
#define NWIN 74
#define TIE_CAP 4096
#define IMGSZ 320.0f
#define WCH 2368         // uint4 chunks per 64-row window (64*74*8/16)
#define PAIR_CAP 131072  // pairs per image (global)
#define LDSP 12288       // pairs staged in LDS

struct InPtrs {
  const float* cls[5];
  const float* bbox[5];
  const float* ctr[5];
};

__device__ __forceinline__ uint32_t f2s(float f) {
  uint32_t x = __float_as_uint(f);
  return (x & 0x80000000u) ? ~x : (x | 0x80000000u);
}
__device__ __forceinline__ float s2f(uint32_t s) {
  uint32_t x = (s & 0x80000000u) ? (s & 0x7fffffffu) : ~s;
  return __uint_as_float(x);
}
// np/XLA logistic: 1/(1+exp(-x)) with per-op f32 rounding.
__device__ __forceinline__ float sigmoid32(float v) {
  float e = (float)exp(-(double)v);          // CR f32 exp(-v)
  return __fdiv_rn(1.0f, __fadd_rn(1.0f, e));
}
__device__ __forceinline__ void lvl_of(int e, int& l, int& le) {
  if (e < 128000)      { l = 0; le = e; }
  else if (e < 160000) { l = 1; le = e - 128000; }
  else if (e < 168000) { l = 2; le = e - 160000; }
  else if (e < 170000) { l = 3; le = e - 168000; }
  else                 { l = 4; le = e - 170000; }
}
__device__ __forceinline__ int kl_of(int l) {
  constexpr int KL[5] = {1000, 1000, 1000, 1000, 720};
  return KL[l];
}
__device__ __forceinline__ float clip32(float v) {
  return fminf(fmaxf(v, 0.0f), IMGSZ);
}
// IoU > 0.5 predicate, exact np f32 op chain (identical to R7-R11).
__device__ __forceinline__ int iou_gt(float bx1, float by1, float bx2, float by2,
                                      float bai, float4 o) {
  float ta_ = __fmul_rn(__fsub_rn(o.z, o.x), __fsub_rn(o.w, o.y));
  float ltx = fmaxf(bx1, o.x), lty = fmaxf(by1, o.y);
  float rbx = fminf(bx2, o.z), rby = fminf(by2, o.w);
  float wd = fmaxf(__fsub_rn(rbx, ltx), 0.0f);
  float hg = fmaxf(__fsub_rn(rby, lty), 0.0f);
  float inter = __fmul_rn(wd, hg);
  float asum = __fadd_rn(bai, ta_);
  float uni  = __fsub_rn(asum, inter);
  float iou  = (uni > 0.0f) ? __fdiv_rn(inter, uni) : 0.0f;
  return (iou > 0.5f) ? 1 : 0;
}

// ---------------- scores -> sortable u32 keys + pass-0 histogram ----------------
__global__ void k_score(InPtrs in, uint32_t* __restrict__ su, uint32_t* __restrict__ hist) {
  int b = blockIdx.y;
  int e = blockIdx.x * blockDim.x + threadIdx.x;
  if (e >= TOT) return;
  int l, le; lvl_of(e, l, le);
  constexpr int HWc[5] = {1600, 400, 100, 25, 9};
  int hw = HWc[l];
  int c = le % NC, p = le / NC;
  float v = in.cls[l][((size_t)b * NC + c) * hw + p];
  float s = sigmoid32(v);
  float m = (s > 0.025f) ? s : -1.0f;
  uint32_t u = f2s(m);
  su[(size_t)b * TOT + e] = u;
  atomicAdd(&hist[(size_t)(b * 5 + l) * 65536u + (u >> 16)], 1u);
}

// ---------------- radix pass 1: low-16 histogram of matching keys ---------------
__global__ void k_hist1(const uint32_t* __restrict__ su, const uint32_t* __restrict__ mpfx,
                        uint32_t* __restrict__ hist) {
  int b = blockIdx.y;
  int e = blockIdx.x * blockDim.x + threadIdx.x;
  if (e >= TOT) return;
  int l, le; lvl_of(e, l, le);
  int bl = b * 5 + l;
  uint32_t key = su[(size_t)b * TOT + e];
  if ((key >> 16) == (mpfx[bl] >> 16))
    atomicAdd(&hist[(size_t)bl * 65536u + (key & 0xFFFFu)], 1u);
}

__global__ void k_findp(const uint32_t* __restrict__ hist, uint32_t* __restrict__ mpfx,
                        uint32_t* __restrict__ mk, int pass) {
  int bl = blockIdx.x;
  uint32_t k = (pass == 0) ? (uint32_t)kl_of(bl % 5) : mk[bl];
  uint32_t pfx = (pass == 0) ? 0u : mpfx[bl];
  const uint32_t* h = hist + (size_t)bl * 65536;
  __shared__ uint32_t sh[1024];
  int tid = threadIdx.x;
  int base = tid * 64;
  uint32_t s = 0;
  for (int i = 0; i < 64; i++) s += h[base + i];
  sh[tid] = s;
  __syncthreads();
  uint32_t above = 0;
  for (int t = tid + 1; t < 1024; t++) above += sh[t];
  if (above < k && above + s >= k) {
    uint32_t cum = above;
    for (int bin = base + 63; bin >= base; bin--) {
      uint32_t c = h[bin];
      if (cum < k && cum + c >= k) {
        if (pass == 0) mpfx[bl] = (uint32_t)bin << 16;
        else           mpfx[bl] = pfx | (uint32_t)bin;
        mk[bl] = k - cum;
        break;
      }
      cum += c;
    }
  }
}

// ---------------- compact selected (LDS-staged, block-aggregated atomics) -------
// A 256-thread block spans at most 2 adjacent levels (min level size 720 > 256).
// Order within selu/seli/tiei is arbitrary (downstream ranks by value), so we
// only need a conflict-free allocator: LDS atomics for local slots, ONE global
// atomicAdd per (block, level) for the base, cooperative copy-out.
__global__ void k_compact(const uint32_t* __restrict__ su, const uint32_t* __restrict__ mpfx,
                          uint32_t* __restrict__ selcnt, uint32_t* __restrict__ tiecnt,
                          uint32_t* __restrict__ selu, uint32_t* __restrict__ seli,
                          uint32_t* __restrict__ tiei) {
  int b = blockIdx.y;
  int tid = threadIdx.x;
  int e0 = blockIdx.x * 256;
  int e = e0 + tid;
  int l0, le0; lvl_of(e0, l0, le0);
  __shared__ uint32_t cnt[2], tcnt[2], gbase[2], tgbase[2];
  __shared__ uint32_t su_s[2][256], si_s[2][256];   // staged selected (u, le)
  __shared__ uint32_t ti_s[2][256];                 // staged tie le
  if (tid < 2) { cnt[tid] = 0u; tcnt[tid] = 0u; }
  __syncthreads();
  if (e < TOT) {
    int l, le; lvl_of(e, l, le);
    int slot = l - l0;          // 0 or 1
    int bl = b * 5 + l;
    uint32_t u = su[(size_t)b * TOT + e];
    uint32_t C = mpfx[bl];
    if (u > C) {
      uint32_t p = atomicAdd(&cnt[slot], 1u);
      su_s[slot][p] = u;
      si_s[slot][p] = (uint32_t)le;
    } else if (u == C) {
      uint32_t p = atomicAdd(&tcnt[slot], 1u);
      ti_s[slot][p] = (uint32_t)le;
    }
  }
  __syncthreads();
  if (tid < 2) {
    int bl = b * 5 + l0 + tid;
    if (cnt[tid])  gbase[tid]  = atomicAdd(&selcnt[bl], cnt[tid]);
    if (tcnt[tid]) tgbase[tid] = atomicAdd(&tiecnt[bl], tcnt[tid]);
  }
  __syncthreads();
  for (int s = 0; s < 2; s++) {
    int bl = b * 5 + l0 + s;
    uint32_t n = cnt[s];
    for (uint32_t t = tid; t < n; t += 256) {
      uint32_t pos = gbase[s] + t;
      selu[(size_t)bl * 1024 + pos] = su_s[s][t];
      seli[(size_t)bl * 1024 + pos] = si_s[s][t];
    }
    uint32_t tn = tcnt[s];
    for (uint32_t t = tid; t < tn; t += 256) {
      uint32_t pos = tgbase[s] + t;
      if (pos < TIE_CAP) tiei[(size_t)bl * TIE_CAP + pos] = ti_s[s][t];
    }
  }
}

// Boundary ties: stable top_k -> smallest indices first.
__global__ void k_ties(const uint32_t* __restrict__ mpfx, const uint32_t* __restrict__ mk,
                       const uint32_t* __restrict__ tiecnt, const uint32_t* __restrict__ tiei,
                       uint32_t* __restrict__ selu, uint32_t* __restrict__ seli) {
  int bl = blockIdx.x;
  int l = bl % 5;
  uint32_t C = mpfx[bl];
  uint32_t T = mk[bl];
  uint32_t G = (uint32_t)kl_of(l) - T;
  uint32_t Tc = tiecnt[bl];
  if (Tc > TIE_CAP) Tc = TIE_CAP;
  __shared__ uint32_t sh[TIE_CAP];
  for (uint32_t t = threadIdx.x; t < Tc; t += blockDim.x) sh[t] = tiei[(size_t)bl * TIE_CAP + t];
  __syncthreads();
  for (uint32_t t = threadIdx.x; t < Tc; t += blockDim.x) {
    uint32_t my = sh[t];
    uint32_t rank = 0;
    for (uint32_t q = 0; q < Tc; q++) rank += (sh[q] < my) ? 1u : 0u;
    if (rank < T) {
      selu[(size_t)bl * 1024 + G + rank] = C;
      seli[(size_t)bl * 1024 + G + rank] = my;
    }
  }
}

// ---------------- exact rank within level + emit (packed u64 keys) --------------
__global__ void k_emit(InPtrs in, const uint32_t* __restrict__ selu, const uint32_t* __restrict__ seli,
                       float* __restrict__ ccs, uint32_t* __restrict__ ccl,
                       uint32_t* __restrict__ ccv, float* __restrict__ ccb) {
  int bl = blockIdx.x;
  int chunk = blockIdx.y;
  int b = bl / 5, l = bl % 5;
  int k = kl_of(l);
  __shared__ uint64_t z[1024];   // 8 KB
  int tid = threadIdx.x;
  for (int t = tid; t < 1024; t += 256) {
    if (t < k) {
      uint32_t u = selu[(size_t)bl * 1024 + t];
      uint32_t idx = seli[(size_t)bl * 1024 + t];
      z[t] = (((uint64_t)u) << 32) | (uint32_t)(~idx);
    } else z[t] = 0ull;
  }
  __syncthreads();
  int tg = chunk * 256 + tid;
  if (tg >= k) return;
  uint64_t zi = z[tg];
  uint32_t u = (uint32_t)(zi >> 32);
  uint32_t idx = ~(uint32_t)zi;
  int rank = 0;
  const uint4* z4 = (const uint4*)z;
  for (int j4 = 0; j4 < 512; j4++) {
    uint4 q = z4[j4];
    uint64_t za = (((uint64_t)q.y) << 32) | q.x;
    uint64_t zb = (((uint64_t)q.w) << 32) | q.z;
    rank += (za > zi) ? 1 : 0;
    rank += (zb > zi) ? 1 : 0;
  }
  constexpr int Wc[5]  = {40, 20, 10, 5, 3};
  constexpr int HWc[5] = {1600, 400, 100, 25, 9};
  constexpr float Sc[5] = {8.f, 16.f, 32.f, 64.f, 128.f};
  constexpr int COFF[5] = {0, 1000, 2000, 3000, 4000};
  int w = Wc[l], hw = HWc[l];
  float ms = s2f(u);
  int valid = (ms > 0.025f) ? 1 : 0;
  int p = (int)idx / NC, c = (int)idx % NC;
  int x = p % w, y = p / w;
  float sf = sigmoid32(in.ctr[l][(size_t)b * hw + p]);
  float score = valid ? __fmul_rn(ms, sf) : -1.0f;
  float px = __fmul_rn(__fadd_rn((float)x, 0.5f), Sc[l]);
  float py = __fmul_rn(__fadd_rn((float)y, 0.5f), Sc[l]);
  size_t bb = (size_t)b * 4 * hw;
  float d0 = in.bbox[l][bb + 0 * hw + p];
  float d1 = in.bbox[l][bb + 1 * hw + p];
  float d2 = in.bbox[l][bb + 2 * hw + p];
  float d3 = in.bbox[l][bb + 3 * hw + p];
  float x1 = clip32(__fsub_rn(px, d0)), y1 = clip32(__fsub_rn(py, d1));
  float x2 = clip32(__fadd_rn(px, d2)), y2 = clip32(__fadd_rn(py, d3));
  int o = b * KTOT + COFF[l] + rank;
  ccs[o] = score;
  ccl[o] = (uint32_t)c;
  ccv[o] = (uint32_t)valid;
  ccb[(size_t)o * 4 + 0] = x1; ccb[(size_t)o * 4 + 1] = y1;
  ccb[(size_t)o * 4 + 2] = x2; ccb[(size_t)o * 4 + 3] = y2;
}

// ---------------- per-image stable descending sort (rank method) ----------------
// maxcb update: block-level reduction -> ONE atomicMax per block (was 18,880
// same-cacheline atomics). Boxes are clipped to [0,320] >= 0 so uint-compare
// atomicMax is monotone and identity 0.0f is exact.
__global__ void k_sortimg(const float* __restrict__ ccs, const uint32_t* __restrict__ ccl,
                          const uint32_t* __restrict__ ccv, const float* __restrict__ ccb,
                          float* __restrict__ ss, uint32_t* __restrict__ sl,
                          uint32_t* __restrict__ sv, float* __restrict__ sb,
                          uint32_t* __restrict__ maxcb) {
  int b = blockIdx.y;
  __shared__ uint32_t key[KTOT];   // 18.9 KB
  __shared__ float red[4];
  int tid = threadIdx.x;
  for (int t = tid; t < KTOT; t += 256) key[t] = f2s(ccs[(size_t)b * KTOT + t]);
  __syncthreads();
  int e = blockIdx.x * 256 + tid;
  float mx = 0.0f;
  if (e < KTOT) {
    uint32_t ke = key[e];
    int rank = 0;
    const uint4* k4 = (const uint4*)key;
    for (int j4 = 0; j4 < KTOT / 4; j4++) {
      uint4 kk = k4[j4];
      int j = j4 * 4;
      rank += ((kk.x > ke) || (kk.x == ke && (j + 0) < e)) ? 1 : 0;
      rank += ((kk.y > ke) || (kk.y == ke && (j + 1) < e)) ? 1 : 0;
      rank += ((kk.z > ke) || (kk.z == ke && (j + 2) < e)) ? 1 : 0;
      rank += ((kk.w > ke) || (kk.w == ke && (j + 3) < e)) ? 1 : 0;
    }
    int sidx = b * KTOT + e;
    int d = b * KTOT + rank;
    ss[d] = ccs[sidx];
    sl[d] = ccl[sidx];
    sv[d] = ccv[sidx];
    float b0 = ccb[(size_t)sidx * 4 + 0], b1 = ccb[(size_t)sidx * 4 + 1];
    float b2 = ccb[(size_t)sidx * 4 + 2], b3 = ccb[(size_t)sidx * 4 + 3];
    sb[(size_t)d * 4 + 0] = b0; sb[(size_t)d * 4 + 1] = b1;
    sb[(size_t)d * 4 + 2] = b2; sb[(size_t)d * 4 + 3] = b3;
    mx = fmaxf(fmaxf(b0, b1), fmaxf(b2, b3));
  }
  for (int o = 32; o; o >>= 1) mx = fmaxf(mx, __shfl_xor(mx, o));
  if ((tid & 63) == 0) red[tid >> 6] = mx;
  __syncthreads();
  if (tid == 0)
    atomicMax(&maxcb[b], __float_as_uint(fmaxf(fmaxf(red[0], red[1]), fmaxf(red[2], red[3]))));
}

// ---------------- valid bits -> bitmask words ----------------
__global__ void k_bits(const uint32_t* __restrict__ sv, unsigned long long* __restrict__ vbits) {
  int w = blockIdx.x, b = blockIdx.y, lane = threadIdx.x;
  int e = w * 64 + lane;
  int pred = (e < KTOT) ? (sv[(size_t)b * KTOT + e] != 0u) : 0;
  unsigned long long m = __ballot(pred);
  if (lane == 0) vbits[b * NWIN + w] = m;
}

// ---------------- per-class offset boxes (f32); also zeroes paircnt -------------
__global__ void k_offset(const float* __restrict__ sb, const uint32_t* __restrict__ sl,
                         const uint32_t* __restrict__ maxcb, float* __restrict__ ob,
                         uint32_t* __restrict__ paircnt) {
  if (blockIdx.x == 0 && threadIdx.x < BN) paircnt[threadIdx.x] = 0u;
  int r = blockIdx.x * blockDim.x + threadIdx.x;
  if (r >= BN * KTOT) return;
  int b = r / KTOT;
  float scale = __fadd_rn(__uint_as_float(maxcb[b]), 1.0f);
  float offv = __fmul_rn((float)sl[r], scale);
  float x1 = __fadd_rn(sb[(size_t)r * 4 + 0], offv);
  float y1 = __fadd_rn(sb[(size_t)r * 4 + 1], offv);
  float x2 = __fadd_rn(sb[(size_t)r * 4 + 2], offv);
  float y2 = __fadd_rn(sb[(size_t)r * 4 + 3], offv);
  ob[(size_t)r * 4 + 0] = x1; ob[(size_t)r * 4 + 1] = y1;
  ob[(size_t)r * 4 + 2] = x2; ob[(size_t)r * 4 + 3] = y2;
}

// ---------------- IoU bitmask, 2D-tiled + pair emission ----------------
__global__ void k_mask(const float* __restrict__ ob, unsigned long long* __restrict__ mask,
                       unsigned long long* __restrict__ tdiag,
                       uint32_t* __restrict__ pairs, uint32_t* __restrict__ paircnt) {
  int b = blockIdx.z;
  int jt = blockIdx.y;
  int ib = blockIdx.x;
  int jbase = jt * 1024;
  int cnt = min(1024, KTOT - jbase);
  bool diagBlock = (jt == (ib >> 2));
  if (!diagBlock && (jbase + cnt - 1 <= ib * 256)) return;
  __shared__ float4 tb[1024];   // 16 KB
  int tid = threadIdx.x;
  for (int j = tid; j < cnt; j += 256)
    tb[j] = ((const float4*)ob)[(size_t)b * KTOT + jbase + j];
  __syncthreads();
  int i = ib * 256 + tid;
  bool act = (i < KTOT);
  float bx1 = 0, by1 = 0, bx2 = 0, by2 = 0, bai = 0;
  if (act) {
    float4 v = ((const float4*)ob)[(size_t)b * KTOT + i];
    bx1 = v.x; by1 = v.y; bx2 = v.z; by2 = v.w;
    bai = __fmul_rn(__fsub_rn(bx2, bx1), __fsub_rn(by2, by1));
  }
  int myw = i >> 6;
  unsigned long long dw = 0ull;
  if (act) {
    unsigned long long* mrow = mask + ((size_t)b * (KTOT + 64) + i) * NWORDS;
    int nw = (cnt + 63) >> 6;
    for (int w = 0; w < nw; w++) {
      int gw = jt * 16 + w;
      if (gw < myw) continue;
      unsigned long long bits = 0ull;
      int j0 = w * 64;
      int jn = min(64, cnt - j0);
      if (gw == myw) {
        for (int jj = 0; jj < jn; jj++) {
          if (jbase + j0 + jj > i)
            bits |= ((unsigned long long)iou_gt(bx1, by1, bx2, by2, bai, tb[j0 + jj])) << jj;
        }
        dw = bits;
      } else {
        for (int jj = 0; jj < jn; jj++)
          bits |= ((unsigned long long)iou_gt(bx1, by1, bx2, by2, bai, tb[j0 + jj])) << jj;
        mrow[gw] = bits;
        if (bits) {   // emit sparse pairs (i<<13)|j; jword>iword by construction
          uint32_t pos = atomicAdd(&paircnt[b], (uint32_t)__popcll(bits));
          unsigned long long t = bits;
          while (t) {
            int jj = __ffsll((long long)t) - 1; t &= t - 1;
            if (pos < PAIR_CAP)
              pairs[(size_t)b * PAIR_CAP + pos] = ((uint32_t)i << 13) | (uint32_t)(jbase + j0 + jj);
            pos++;
          }
        }
      }
    }
  }
  if (diagBlock) {
    int lane = tid & 63;
    unsigned long long col = 0ull;
#pragma unroll
    for (int j = 0; j < 64; j++) {
      unsigned long long bal = __ballot((int)((dw >> j) & 1ull));
      if (lane == j) col = bal;
    }
    if (myw < NWIN) tdiag[((size_t)b * NWIN + (size_t)myw) * 64 + lane] = col;
  }
}

// ---------------- sparse-pair blocked greedy NMS, 256 thr/image -----------------
__global__ void k_nms(const unsigned long long* __restrict__ mask,
                      const unsigned long long* __restrict__ tdiag,
                      const unsigned long long* __restrict__ vbits,
                      unsigned long long* __restrict__ keepw,
                      const uint32_t* __restrict__ pairs,
                      const uint32_t* __restrict__ paircnt) {
  int b = blockIdx.x;
  int tid = threadIdx.x;
  int lane = tid & 63;
  int wv = tid >> 6;
  const unsigned long long* mb = mask + (size_t)b * (KTOT + 64) * NWORDS;
  __shared__ unsigned long long tdl[NWIN * 64];   // 37888 B
  __shared__ unsigned long long svl[NWIN];
  __shared__ unsigned long long sup[NWIN];
  __shared__ unsigned long long kwsh;
  __shared__ uint32_t plp[LDSP];                  // 49152 B
  {
    const uint4* src = (const uint4*)(tdiag + (size_t)b * NWIN * 64);
    uint4* dst = (uint4*)tdl;
#pragma unroll
    for (int s = 0; s < 10; s++) {
      int c = tid + 256 * s;
      if (c < WCH) dst[c] = src[c];
    }
  }
  if (tid < NWIN) { svl[tid] = vbits[b * NWIN + tid]; sup[tid] = 0ull; }
  uint32_t npairs = paircnt[b];
  bool useP = (npairs <= (uint32_t)PAIR_CAP);
  bool useL = (npairs <= (uint32_t)LDSP);
  const uint32_t* gpl = pairs + (size_t)b * PAIR_CAP;
  if (useL) for (uint32_t t = tid; t < npairs; t += 256) plp[t] = gpl[t];
  __syncthreads();
  unsigned int* sup32 = (unsigned int*)sup;
  if (useP) {
    // -------- sparse path: no global loads in the loop --------
    for (int w = 0; w < NWIN; w++) {
      if (wv == 0) {
        unsigned long long T = tdl[w * 64 + lane];
        unsigned long long sval = svl[w];
        unsigned long long s_in = sup[w];
        unsigned int supb = (unsigned int)((s_in >> lane) & 1ull);
        unsigned int Tlo = (unsigned int)T, Thi = (unsigned int)(T >> 32);
        unsigned int svlo = (unsigned int)sval, svhi = (unsigned int)(sval >> 32);
        unsigned long long kw = 0ull;
#pragma unroll
        for (int i = 0; i < 64; i++) {
          unsigned int si = (unsigned int)__builtin_amdgcn_readlane((int)supb, i);
          unsigned int vi = ((i < 32 ? svlo : svhi) >> (i & 31)) & 1u;
          unsigned int kp = vi & (si ^ 1u) & 1u;
          kw |= ((unsigned long long)kp) << i;
          unsigned int tbv = ((i < 32 ? Tlo : Thi) >> (i & 31)) & 1u;
          supb |= tbv & kp;
        }
        if (lane == 0) { keepw[b * NWIN + w] = kw; kwsh = kw; }
      }
      __syncthreads();
      unsigned long long kw = kwsh;
      for (uint32_t t = tid; t < npairs; t += 256) {
        uint32_t p = useL ? plp[t] : gpl[t];
        int i = (int)(p >> 13);
        if ((i >> 6) != w) continue;
        if (!((kw >> (i & 63)) & 1ull)) continue;
        int j = (int)(p & 8191u);
        atomicOr(&sup32[j >> 5], 1u << (j & 31));
      }
      __syncthreads();
    }
  } else {
    // -------- dense fallback (R11) --------
    for (int w = 0; w < NWIN; w++) {
      uint4 q[10];
      const uint4* src4 = (const uint4*)(mb + (size_t)w * 64 * NWORDS);
#pragma unroll
      for (int s = 0; s < 10; s++) {
        int c = tid + 256 * s;
        if (c < WCH && (2 * (c % 37) + 1 > w)) q[s] = src4[c];
      }
      if (wv == 0) {
        unsigned long long T = tdl[w * 64 + lane];
        unsigned long long sval = svl[w];
        unsigned long long s_in = sup[w];
        unsigned int supb = (unsigned int)((s_in >> lane) & 1ull);
        unsigned int Tlo = (unsigned int)T, Thi = (unsigned int)(T >> 32);
        unsigned int svlo = (unsigned int)sval, svhi = (unsigned int)(sval >> 32);
        unsigned long long kw = 0ull;
#pragma unroll
        for (int i = 0; i < 64; i++) {
          unsigned int si = (unsigned int)__builtin_amdgcn_readlane((int)supb, i);
          unsigned int vi = ((i < 32 ? svlo : svhi) >> (i & 31)) & 1u;
          unsigned int kp = vi & (si ^ 1u) & 1u;
          kw |= ((unsigned long long)kp) << i;
          unsigned int tbv = ((i < 32 ? Tlo : Thi) >> (i & 31)) & 1u;
          supb |= tbv & kp;
        }
        if (lane == 0) { keepw[b * NWIN + w] = kw; kwsh = kw; }
      }
      __syncthreads();
      unsigned long long kw = kwsh;
#pragma unroll
      for (int s = 0; s < 10; s++) {
        int c = tid + 256 * s;
        if (c >= WCH) continue;
        int wp = c % 37;
        if (2 * wp + 1 <= w) continue;
        int r = c / 37;
        if (!((kw >> r) & 1ull)) continue;
        int wlo = 2 * wp, whi = 2 * wp + 1;
        if (wlo > w) {
          if (q[s].x) atomicOr(&sup32[2 * wlo + 0], q[s].x);
          if (q[s].y) atomicOr(&sup32[2 * wlo + 1], q[s].y);
        }
        if (whi > w) {
          if (q[s].z) atomicOr(&sup32[2 * whi + 0], q[s].z);
          if (q[s].w) atomicOr(&sup32[2 * whi + 1], q[s].w);
        }
      }
      __syncthreads();
    }
  }
}

// ---------------- final outputs ----------------
__global__ void k_out(const float* __restrict__ ss, const uint32_t* __restrict__ sl,
                      const float* __restrict__ sb, const unsigned long long* __restrict__ keepw,
                      float* __restrict__ out) {
  int r = blockIdx.x * blockDim.x + threadIdx.x;
  if (r >= BN * KTOT) return;
  int b = r / KTOT;
  int e = r - b * KTOT;
  unsigned int kp = (unsigned int)((keepw[b * NWIN + (e >> 6)] >> (e & 63)) & 1ull);
  out[(size_t)r * 5 + 0] = sb[(size_t)r * 4 + 0];
  out[(size_t)r * 5 + 1] = sb[(size_t)r * 4 + 1];
  out[(size_t)r * 5 + 2] = sb[(size_t)r * 4 + 2];
  out[(size_t)r * 5 + 3] = sb[(size_t)r * 4 + 3];
  out[(size_t)r * 5 + 4] = ss[r];
  out[(size_t)BN * KTOT * 5 + r] = (float)sl[r];
  out[(size_t)BN * KTOT * 6 + r] = kp ? 1.0f : 0.0f;
}

extern "C" void kernel_launch(void* const* d_in, const int* in_sizes, int n_in,
                              void* d_out, int out_size, void* d_ws, size_t ws_size,
                              hipStream_t stream) {
  InPtrs ip;
  for (int l = 0; l < 5; l++) {
    ip.cls[l]  = (const float*)d_in[3 * l + 0];
    ip.bbox[l] = (const float*)d_in[3 * l + 1];
    ip.ctr[l]  = (const float*)d_in[3 * l + 2];
  }

  size_t off = 0;
  auto alloc = [&](size_t n) {
    char* p = (char*)d_ws + off;
    off = (off + n + 255) & ~(size_t)255;
    return p;
  };
  // region0: su + hist + small counters (phase A) overlaid with padded mask
  // (phase B). Small counters (selcnt/tiecnt/maxcb) are consumed before
  // k_mask writes the mask over them.
  const size_t SU_BYTES   = (size_t)BN * TOT * 4;                  // 2.73 MB
  const size_t HIST_BYTES = 20ull * 65536 * 4;                     // 5.24 MB
  const size_t EXTRA      = 256;                                   // selcnt/tiecnt/maxcb
  const size_t MASK_BYTES = (size_t)BN * (KTOT + 64) * NWORDS * 8; // 11.3 MB
  size_t region0 = ((SU_BYTES + 255) & ~(size_t)255) + HIST_BYTES + EXTRA;
  if (MASK_BYTES > region0) region0 = MASK_BYTES;
  char* r0p = (char*)alloc(region0);
  uint32_t* su   = (uint32_t*)r0p;
  uint32_t* hist = (uint32_t*)(r0p + ((SU_BYTES + 255) & ~(size_t)255));
  uint32_t* selcnt = hist + 20ull * 65536;
  uint32_t* tiecnt = selcnt + 20;
  uint32_t* maxcb  = tiecnt + 20;
  unsigned long long* mask = (unsigned long long*)r0p;

  uint32_t* mpfx   = (uint32_t*)alloc(20 * 4);
  uint32_t* mk     = (uint32_t*)alloc(20 * 4);
  uint32_t* selu   = (uint32_t*)alloc(20ull * 1024 * 4);
  uint32_t* seli   = (uint32_t*)alloc(20ull * 1024 * 4);
  uint32_t* tiei   = (uint32_t*)alloc(20ull * TIE_CAP * 4);
  float*    ccs    = (float*)   alloc((size_t)BN * KTOT * 4);
  uint32_t* ccl    = (uint32_t*)alloc((size_t)BN * KTOT * 4);
  uint32_t* ccv    = (uint32_t*)alloc((size_t)BN * KTOT * 4);
  float*    ccb    = (float*)   alloc((size_t)BN * KTOT * 16);
  float*    ss     = (float*)   alloc((size_t)BN * KTOT * 4);
  uint32_t* sl     = (uint32_t*)alloc((size_t)BN * KTOT * 4);
  uint32_t* sv     = (uint32_t*)alloc((size_t)BN * KTOT * 4);
  float*    sb     = (float*)   alloc((size_t)BN * KTOT * 16);
  float*    ob     = (float*)   alloc((size_t)BN * KTOT * 16);
  unsigned long long* tdiag = (unsigned long long*)alloc((size_t)BN * NWIN * 64 * 8); // 148 KB
  unsigned long long* vbits = (unsigned long long*)alloc((size_t)BN * NWIN * 8);
  unsigned long long* keepw = (unsigned long long*)alloc((size_t)BN * NWIN * 8);
  uint32_t* pairs   = (uint32_t*)alloc((size_t)BN * PAIR_CAP * 4);  // 2 MB
  uint32_t* paircnt = (uint32_t*)alloc(BN * 4);
  (void)ws_size; (void)in_sizes; (void)n_in; (void)out_size;

  dim3 gscan((TOT + 255) / 256, BN);
  hipMemsetAsync(hist, 0, HIST_BYTES + EXTRA, stream);   // hist + counters
  k_score<<<gscan, 256, 0, stream>>>(ip, su, hist);
  k_findp<<<20, 1024, 0, stream>>>(hist, mpfx, mk, 0);
  hipMemsetAsync(hist, 0, HIST_BYTES, stream);
  k_hist1<<<gscan, 256, 0, stream>>>(su, mpfx, hist);
  k_findp<<<20, 1024, 0, stream>>>(hist, mpfx, mk, 1);
  k_compact<<<gscan, 256, 0, stream>>>(su, mpfx, selcnt, tiecnt, selu, seli, tiei);
  k_ties<<<20, 256, 0, stream>>>(mpfx, mk, tiecnt, tiei, selu, seli);
  k_emit<<<dim3(20, 4), 256, 0, stream>>>(ip, selu, seli, ccs, ccl, ccv, ccb);
  k_sortimg<<<dim3(19, BN), 256, 0, stream>>>(ccs, ccl, ccv, ccb, ss, sl, sv, sb, maxcb);
  k_bits<<<dim3(NWIN, BN), 64, 0, stream>>>(sv, vbits);
  k_offset<<<(BN * KTOT + 255) / 256, 256, 0, stream>>>(sb, sl, maxcb, ob, paircnt);
  k_mask<<<dim3(19, 5, BN), 256, 0, stream>>>(ob, mask, tdiag, pairs, paircnt);
  k_nms<<<BN, 256, 0, stream>>>(mask, tdiag, vbits, keepw, pairs, paircnt);
  k_out<<<(BN * KTOT + 255) / 256, 256, 0, stream>>>(ss, sl, sb, keepw, (float*)d_out);
}

// Round 3
// 650.287 us; speedup vs baseline: 1.3361x; 1.1214x over previous
//
#include <hip/hip_runtime.h>
#include <stdint.h>

// FCOS bbox post-processing, B=4 images — bit-exact np/XLA-f32 replication
// (R7 semantics). R12: sparse-pair NMS. R13: block-aggregated atomics in
// k_compact / k_sortimg. R14: k_mask occupancy fix — j-tile 1024 -> 256
// (grid 19x19xB, 190 active blocks/image instead of 59; per-thread serial
// IoU chain 1024 -> 256; LDS 16KB -> 4KB). Inner bit/pair/diag logic
// unchanged, mask layout unchanged.

#define BN 4
#define NC 80
#define TOT 170720       // 128000+32000+8000+2000+720
#define KTOT 4720        // 1000*4+720
#define NWORDS 74        // ceil(4720/64)
#define NWIN 74
#define TIE_CAP 4096
#define IMGSZ 320.0f
#define WCH 2368         // uint4 chunks per 64-row window (64*74*8/16)
#define PAIR_CAP 131072  // pairs per image (global)
#define LDSP 12288       // pairs staged in LDS

struct InPtrs {
  const float* cls[5];
  const float* bbox[5];
  const float* ctr[5];
};

__device__ __forceinline__ uint32_t f2s(float f) {
  uint32_t x = __float_as_uint(f);
  return (x & 0x80000000u) ? ~x : (x | 0x80000000u);
}
__device__ __forceinline__ float s2f(uint32_t s) {
  uint32_t x = (s & 0x80000000u) ? (s & 0x7fffffffu) : ~s;
  return __uint_as_float(x);
}
// np/XLA logistic: 1/(1+exp(-x)) with per-op f32 rounding.
__device__ __forceinline__ float sigmoid32(float v) {
  float e = (float)exp(-(double)v);          // CR f32 exp(-v)
  return __fdiv_rn(1.0f, __fadd_rn(1.0f, e));
}
__device__ __forceinline__ void lvl_of(int e, int& l, int& le) {
  if (e < 128000)      { l = 0; le = e; }
  else if (e < 160000) { l = 1; le = e - 128000; }
  else if (e < 168000) { l = 2; le = e - 160000; }
  else if (e < 170000) { l = 3; le = e - 168000; }
  else                 { l = 4; le = e - 170000; }
}
__device__ __forceinline__ int kl_of(int l) {
  constexpr int KL[5] = {1000, 1000, 1000, 1000, 720};
  return KL[l];
}
__device__ __forceinline__ float clip32(float v) {
  return fminf(fmaxf(v, 0.0f), IMGSZ);
}
// IoU > 0.5 predicate, exact np f32 op chain (identical to R7-R11).
__device__ __forceinline__ int iou_gt(float bx1, float by1, float bx2, float by2,
                                      float bai, float4 o) {
  float ta_ = __fmul_rn(__fsub_rn(o.z, o.x), __fsub_rn(o.w, o.y));
  float ltx = fmaxf(bx1, o.x), lty = fmaxf(by1, o.y);
  float rbx = fminf(bx2, o.z), rby = fminf(by2, o.w);
  float wd = fmaxf(__fsub_rn(rbx, ltx), 0.0f);
  float hg = fmaxf(__fsub_rn(rby, lty), 0.0f);
  float inter = __fmul_rn(wd, hg);
  float asum = __fadd_rn(bai, ta_);
  float uni  = __fsub_rn(asum, inter);
  float iou  = (uni > 0.0f) ? __fdiv_rn(inter, uni) : 0.0f;
  return (iou > 0.5f) ? 1 : 0;
}

// ---------------- scores -> sortable u32 keys + pass-0 histogram ----------------
__global__ void k_score(InPtrs in, uint32_t* __restrict__ su, uint32_t* __restrict__ hist) {
  int b = blockIdx.y;
  int e = blockIdx.x * blockDim.x + threadIdx.x;
  if (e >= TOT) return;
  int l, le; lvl_of(e, l, le);
  constexpr int HWc[5] = {1600, 400, 100, 25, 9};
  int hw = HWc[l];
  int c = le % NC, p = le / NC;
  float v = in.cls[l][((size_t)b * NC + c) * hw + p];
  float s = sigmoid32(v);
  float m = (s > 0.025f) ? s : -1.0f;
  uint32_t u = f2s(m);
  su[(size_t)b * TOT + e] = u;
  atomicAdd(&hist[(size_t)(b * 5 + l) * 65536u + (u >> 16)], 1u);
}

// ---------------- radix pass 1: low-16 histogram of matching keys ---------------
__global__ void k_hist1(const uint32_t* __restrict__ su, const uint32_t* __restrict__ mpfx,
                        uint32_t* __restrict__ hist) {
  int b = blockIdx.y;
  int e = blockIdx.x * blockDim.x + threadIdx.x;
  if (e >= TOT) return;
  int l, le; lvl_of(e, l, le);
  int bl = b * 5 + l;
  uint32_t key = su[(size_t)b * TOT + e];
  if ((key >> 16) == (mpfx[bl] >> 16))
    atomicAdd(&hist[(size_t)bl * 65536u + (key & 0xFFFFu)], 1u);
}

__global__ void k_findp(const uint32_t* __restrict__ hist, uint32_t* __restrict__ mpfx,
                        uint32_t* __restrict__ mk, int pass) {
  int bl = blockIdx.x;
  uint32_t k = (pass == 0) ? (uint32_t)kl_of(bl % 5) : mk[bl];
  uint32_t pfx = (pass == 0) ? 0u : mpfx[bl];
  const uint32_t* h = hist + (size_t)bl * 65536;
  __shared__ uint32_t sh[1024];
  int tid = threadIdx.x;
  int base = tid * 64;
  uint32_t s = 0;
  for (int i = 0; i < 64; i++) s += h[base + i];
  sh[tid] = s;
  __syncthreads();
  uint32_t above = 0;
  for (int t = tid + 1; t < 1024; t++) above += sh[t];
  if (above < k && above + s >= k) {
    uint32_t cum = above;
    for (int bin = base + 63; bin >= base; bin--) {
      uint32_t c = h[bin];
      if (cum < k && cum + c >= k) {
        if (pass == 0) mpfx[bl] = (uint32_t)bin << 16;
        else           mpfx[bl] = pfx | (uint32_t)bin;
        mk[bl] = k - cum;
        break;
      }
      cum += c;
    }
  }
}

// ---------------- compact selected (LDS-staged, block-aggregated atomics) -------
// A 256-thread block spans at most 2 adjacent levels (min level size 720 > 256).
// Order within selu/seli/tiei is arbitrary (downstream ranks by value), so we
// only need a conflict-free allocator: LDS atomics for local slots, ONE global
// atomicAdd per (block, level) for the base, cooperative copy-out.
__global__ void k_compact(const uint32_t* __restrict__ su, const uint32_t* __restrict__ mpfx,
                          uint32_t* __restrict__ selcnt, uint32_t* __restrict__ tiecnt,
                          uint32_t* __restrict__ selu, uint32_t* __restrict__ seli,
                          uint32_t* __restrict__ tiei) {
  int b = blockIdx.y;
  int tid = threadIdx.x;
  int e0 = blockIdx.x * 256;
  int e = e0 + tid;
  int l0, le0; lvl_of(e0, l0, le0);
  __shared__ uint32_t cnt[2], tcnt[2], gbase[2], tgbase[2];
  __shared__ uint32_t su_s[2][256], si_s[2][256];   // staged selected (u, le)
  __shared__ uint32_t ti_s[2][256];                 // staged tie le
  if (tid < 2) { cnt[tid] = 0u; tcnt[tid] = 0u; }
  __syncthreads();
  if (e < TOT) {
    int l, le; lvl_of(e, l, le);
    int slot = l - l0;          // 0 or 1
    int bl = b * 5 + l;
    uint32_t u = su[(size_t)b * TOT + e];
    uint32_t C = mpfx[bl];
    if (u > C) {
      uint32_t p = atomicAdd(&cnt[slot], 1u);
      su_s[slot][p] = u;
      si_s[slot][p] = (uint32_t)le;
    } else if (u == C) {
      uint32_t p = atomicAdd(&tcnt[slot], 1u);
      ti_s[slot][p] = (uint32_t)le;
    }
  }
  __syncthreads();
  if (tid < 2) {
    int bl = b * 5 + l0 + tid;
    if (cnt[tid])  gbase[tid]  = atomicAdd(&selcnt[bl], cnt[tid]);
    if (tcnt[tid]) tgbase[tid] = atomicAdd(&tiecnt[bl], tcnt[tid]);
  }
  __syncthreads();
  for (int s = 0; s < 2; s++) {
    int bl = b * 5 + l0 + s;
    uint32_t n = cnt[s];
    for (uint32_t t = tid; t < n; t += 256) {
      uint32_t pos = gbase[s] + t;
      selu[(size_t)bl * 1024 + pos] = su_s[s][t];
      seli[(size_t)bl * 1024 + pos] = si_s[s][t];
    }
    uint32_t tn = tcnt[s];
    for (uint32_t t = tid; t < tn; t += 256) {
      uint32_t pos = tgbase[s] + t;
      if (pos < TIE_CAP) tiei[(size_t)bl * TIE_CAP + pos] = ti_s[s][t];
    }
  }
}

// Boundary ties: stable top_k -> smallest indices first.
__global__ void k_ties(const uint32_t* __restrict__ mpfx, const uint32_t* __restrict__ mk,
                       const uint32_t* __restrict__ tiecnt, const uint32_t* __restrict__ tiei,
                       uint32_t* __restrict__ selu, uint32_t* __restrict__ seli) {
  int bl = blockIdx.x;
  int l = bl % 5;
  uint32_t C = mpfx[bl];
  uint32_t T = mk[bl];
  uint32_t G = (uint32_t)kl_of(l) - T;
  uint32_t Tc = tiecnt[bl];
  if (Tc > TIE_CAP) Tc = TIE_CAP;
  __shared__ uint32_t sh[TIE_CAP];
  for (uint32_t t = threadIdx.x; t < Tc; t += blockDim.x) sh[t] = tiei[(size_t)bl * TIE_CAP + t];
  __syncthreads();
  for (uint32_t t = threadIdx.x; t < Tc; t += blockDim.x) {
    uint32_t my = sh[t];
    uint32_t rank = 0;
    for (uint32_t q = 0; q < Tc; q++) rank += (sh[q] < my) ? 1u : 0u;
    if (rank < T) {
      selu[(size_t)bl * 1024 + G + rank] = C;
      seli[(size_t)bl * 1024 + G + rank] = my;
    }
  }
}

// ---------------- exact rank within level + emit (packed u64 keys) --------------
__global__ void k_emit(InPtrs in, const uint32_t* __restrict__ selu, const uint32_t* __restrict__ seli,
                       float* __restrict__ ccs, uint32_t* __restrict__ ccl,
                       uint32_t* __restrict__ ccv, float* __restrict__ ccb) {
  int bl = blockIdx.x;
  int chunk = blockIdx.y;
  int b = bl / 5, l = bl % 5;
  int k = kl_of(l);
  __shared__ uint64_t z[1024];   // 8 KB
  int tid = threadIdx.x;
  for (int t = tid; t < 1024; t += 256) {
    if (t < k) {
      uint32_t u = selu[(size_t)bl * 1024 + t];
      uint32_t idx = seli[(size_t)bl * 1024 + t];
      z[t] = (((uint64_t)u) << 32) | (uint32_t)(~idx);
    } else z[t] = 0ull;
  }
  __syncthreads();
  int tg = chunk * 256 + tid;
  if (tg >= k) return;
  uint64_t zi = z[tg];
  uint32_t u = (uint32_t)(zi >> 32);
  uint32_t idx = ~(uint32_t)zi;
  int rank = 0;
  const uint4* z4 = (const uint4*)z;
  for (int j4 = 0; j4 < 512; j4++) {
    uint4 q = z4[j4];
    uint64_t za = (((uint64_t)q.y) << 32) | q.x;
    uint64_t zb = (((uint64_t)q.w) << 32) | q.z;
    rank += (za > zi) ? 1 : 0;
    rank += (zb > zi) ? 1 : 0;
  }
  constexpr int Wc[5]  = {40, 20, 10, 5, 3};
  constexpr int HWc[5] = {1600, 400, 100, 25, 9};
  constexpr float Sc[5] = {8.f, 16.f, 32.f, 64.f, 128.f};
  constexpr int COFF[5] = {0, 1000, 2000, 3000, 4000};
  int w = Wc[l], hw = HWc[l];
  float ms = s2f(u);
  int valid = (ms > 0.025f) ? 1 : 0;
  int p = (int)idx / NC, c = (int)idx % NC;
  int x = p % w, y = p / w;
  float sf = sigmoid32(in.ctr[l][(size_t)b * hw + p]);
  float score = valid ? __fmul_rn(ms, sf) : -1.0f;
  float px = __fmul_rn(__fadd_rn((float)x, 0.5f), Sc[l]);
  float py = __fmul_rn(__fadd_rn((float)y, 0.5f), Sc[l]);
  size_t bb = (size_t)b * 4 * hw;
  float d0 = in.bbox[l][bb + 0 * hw + p];
  float d1 = in.bbox[l][bb + 1 * hw + p];
  float d2 = in.bbox[l][bb + 2 * hw + p];
  float d3 = in.bbox[l][bb + 3 * hw + p];
  float x1 = clip32(__fsub_rn(px, d0)), y1 = clip32(__fsub_rn(py, d1));
  float x2 = clip32(__fadd_rn(px, d2)), y2 = clip32(__fadd_rn(py, d3));
  int o = b * KTOT + COFF[l] + rank;
  ccs[o] = score;
  ccl[o] = (uint32_t)c;
  ccv[o] = (uint32_t)valid;
  ccb[(size_t)o * 4 + 0] = x1; ccb[(size_t)o * 4 + 1] = y1;
  ccb[(size_t)o * 4 + 2] = x2; ccb[(size_t)o * 4 + 3] = y2;
}

// ---------------- per-image stable descending sort (rank method) ----------------
__global__ void k_sortimg(const float* __restrict__ ccs, const uint32_t* __restrict__ ccl,
                          const uint32_t* __restrict__ ccv, const float* __restrict__ ccb,
                          float* __restrict__ ss, uint32_t* __restrict__ sl,
                          uint32_t* __restrict__ sv, float* __restrict__ sb,
                          uint32_t* __restrict__ maxcb) {
  int b = blockIdx.y;
  __shared__ uint32_t key[KTOT];   // 18.9 KB
  __shared__ float red[4];
  int tid = threadIdx.x;
  for (int t = tid; t < KTOT; t += 256) key[t] = f2s(ccs[(size_t)b * KTOT + t]);
  __syncthreads();
  int e = blockIdx.x * 256 + tid;
  float mx = 0.0f;
  if (e < KTOT) {
    uint32_t ke = key[e];
    int rank = 0;
    const uint4* k4 = (const uint4*)key;
    for (int j4 = 0; j4 < KTOT / 4; j4++) {
      uint4 kk = k4[j4];
      int j = j4 * 4;
      rank += ((kk.x > ke) || (kk.x == ke && (j + 0) < e)) ? 1 : 0;
      rank += ((kk.y > ke) || (kk.y == ke && (j + 1) < e)) ? 1 : 0;
      rank += ((kk.z > ke) || (kk.z == ke && (j + 2) < e)) ? 1 : 0;
      rank += ((kk.w > ke) || (kk.w == ke && (j + 3) < e)) ? 1 : 0;
    }
    int sidx = b * KTOT + e;
    int d = b * KTOT + rank;
    ss[d] = ccs[sidx];
    sl[d] = ccl[sidx];
    sv[d] = ccv[sidx];
    float b0 = ccb[(size_t)sidx * 4 + 0], b1 = ccb[(size_t)sidx * 4 + 1];
    float b2 = ccb[(size_t)sidx * 4 + 2], b3 = ccb[(size_t)sidx * 4 + 3];
    sb[(size_t)d * 4 + 0] = b0; sb[(size_t)d * 4 + 1] = b1;
    sb[(size_t)d * 4 + 2] = b2; sb[(size_t)d * 4 + 3] = b3;
    mx = fmaxf(fmaxf(b0, b1), fmaxf(b2, b3));
  }
  for (int o = 32; o; o >>= 1) mx = fmaxf(mx, __shfl_xor(mx, o));
  if ((tid & 63) == 0) red[tid >> 6] = mx;
  __syncthreads();
  if (tid == 0)
    atomicMax(&maxcb[b], __float_as_uint(fmaxf(fmaxf(red[0], red[1]), fmaxf(red[2], red[3]))));
}

// ---------------- valid bits -> bitmask words ----------------
__global__ void k_bits(const uint32_t* __restrict__ sv, unsigned long long* __restrict__ vbits) {
  int w = blockIdx.x, b = blockIdx.y, lane = threadIdx.x;
  int e = w * 64 + lane;
  int pred = (e < KTOT) ? (sv[(size_t)b * KTOT + e] != 0u) : 0;
  unsigned long long m = __ballot(pred);
  if (lane == 0) vbits[b * NWIN + w] = m;
}

// ---------------- per-class offset boxes (f32); also zeroes paircnt -------------
__global__ void k_offset(const float* __restrict__ sb, const uint32_t* __restrict__ sl,
                         const uint32_t* __restrict__ maxcb, float* __restrict__ ob,
                         uint32_t* __restrict__ paircnt) {
  if (blockIdx.x == 0 && threadIdx.x < BN) paircnt[threadIdx.x] = 0u;
  int r = blockIdx.x * blockDim.x + threadIdx.x;
  if (r >= BN * KTOT) return;
  int b = r / KTOT;
  float scale = __fadd_rn(__uint_as_float(maxcb[b]), 1.0f);
  float offv = __fmul_rn((float)sl[r], scale);
  float x1 = __fadd_rn(sb[(size_t)r * 4 + 0], offv);
  float y1 = __fadd_rn(sb[(size_t)r * 4 + 1], offv);
  float x2 = __fadd_rn(sb[(size_t)r * 4 + 2], offv);
  float y2 = __fadd_rn(sb[(size_t)r * 4 + 3], offv);
  ob[(size_t)r * 4 + 0] = x1; ob[(size_t)r * 4 + 1] = y1;
  ob[(size_t)r * 4 + 2] = x2; ob[(size_t)r * 4 + 3] = y2;
}

// ---------------- IoU bitmask, 2D-tiled (256x256) + pair emission ---------------
// R14: j-tile = 256 (4 words). Grid (19,19,B); triangle skip jt<ib; 190 active
// blocks/image (~12 waves/CU) vs 59 before. Same mask layout / pair encoding /
// diag transpose as R12-R13.
__global__ void k_mask(const float* __restrict__ ob, unsigned long long* __restrict__ mask,
                       unsigned long long* __restrict__ tdiag,
                       uint32_t* __restrict__ pairs, uint32_t* __restrict__ paircnt) {
  int b = blockIdx.z;
  int jt = blockIdx.y;
  int ib = blockIdx.x;
  int jbase = jt * 256;
  int cnt = min(256, KTOT - jbase);
  bool diagBlock = (jt == ib);
  if (!diagBlock && (jbase + cnt - 1 <= ib * 256)) return;   // jt < ib
  __shared__ float4 tb[256];   // 4 KB
  int tid = threadIdx.x;
  if (tid < cnt)
    tb[tid] = ((const float4*)ob)[(size_t)b * KTOT + jbase + tid];
  __syncthreads();
  int i = ib * 256 + tid;
  bool act = (i < KTOT);
  float bx1 = 0, by1 = 0, bx2 = 0, by2 = 0, bai = 0;
  if (act) {
    float4 v = ((const float4*)ob)[(size_t)b * KTOT + i];
    bx1 = v.x; by1 = v.y; bx2 = v.z; by2 = v.w;
    bai = __fmul_rn(__fsub_rn(bx2, bx1), __fsub_rn(by2, by1));
  }
  int myw = i >> 6;
  unsigned long long dw = 0ull;
  if (act) {
    unsigned long long* mrow = mask + ((size_t)b * (KTOT + 64) + i) * NWORDS;
    int nw = (cnt + 63) >> 6;
    for (int w = 0; w < nw; w++) {
      int gw = jt * 4 + w;
      if (gw < myw) continue;
      unsigned long long bits = 0ull;
      int j0 = w * 64;
      int jn = min(64, cnt - j0);
      if (gw == myw) {
        for (int jj = 0; jj < jn; jj++) {
          if (jbase + j0 + jj > i)
            bits |= ((unsigned long long)iou_gt(bx1, by1, bx2, by2, bai, tb[j0 + jj])) << jj;
        }
        dw = bits;
      } else {
        for (int jj = 0; jj < jn; jj++)
          bits |= ((unsigned long long)iou_gt(bx1, by1, bx2, by2, bai, tb[j0 + jj])) << jj;
        mrow[gw] = bits;
        if (bits) {   // emit sparse pairs (i<<13)|j; jword>iword by construction
          uint32_t pos = atomicAdd(&paircnt[b], (uint32_t)__popcll(bits));
          unsigned long long t = bits;
          while (t) {
            int jj = __ffsll((long long)t) - 1; t &= t - 1;
            if (pos < PAIR_CAP)
              pairs[(size_t)b * PAIR_CAP + pos] = ((uint32_t)i << 13) | (uint32_t)(jbase + j0 + jj);
            pos++;
          }
        }
      }
    }
  }
  if (diagBlock) {
    int lane = tid & 63;
    unsigned long long col = 0ull;
#pragma unroll
    for (int j = 0; j < 64; j++) {
      unsigned long long bal = __ballot((int)((dw >> j) & 1ull));
      if (lane == j) col = bal;
    }
    if (myw < NWIN) tdiag[((size_t)b * NWIN + (size_t)myw) * 64 + lane] = col;
  }
}

// ---------------- sparse-pair blocked greedy NMS, 256 thr/image -----------------
__global__ void k_nms(const unsigned long long* __restrict__ mask,
                      const unsigned long long* __restrict__ tdiag,
                      const unsigned long long* __restrict__ vbits,
                      unsigned long long* __restrict__ keepw,
                      const uint32_t* __restrict__ pairs,
                      const uint32_t* __restrict__ paircnt) {
  int b = blockIdx.x;
  int tid = threadIdx.x;
  int lane = tid & 63;
  int wv = tid >> 6;
  const unsigned long long* mb = mask + (size_t)b * (KTOT + 64) * NWORDS;
  __shared__ unsigned long long tdl[NWIN * 64];   // 37888 B
  __shared__ unsigned long long svl[NWIN];
  __shared__ unsigned long long sup[NWIN];
  __shared__ unsigned long long kwsh;
  __shared__ uint32_t plp[LDSP];                  // 49152 B
  {
    const uint4* src = (const uint4*)(tdiag + (size_t)b * NWIN * 64);
    uint4* dst = (uint4*)tdl;
#pragma unroll
    for (int s = 0; s < 10; s++) {
      int c = tid + 256 * s;
      if (c < WCH) dst[c] = src[c];
    }
  }
  if (tid < NWIN) { svl[tid] = vbits[b * NWIN + tid]; sup[tid] = 0ull; }
  uint32_t npairs = paircnt[b];
  bool useP = (npairs <= (uint32_t)PAIR_CAP);
  bool useL = (npairs <= (uint32_t)LDSP);
  const uint32_t* gpl = pairs + (size_t)b * PAIR_CAP;
  if (useL) for (uint32_t t = tid; t < npairs; t += 256) plp[t] = gpl[t];
  __syncthreads();
  unsigned int* sup32 = (unsigned int*)sup;
  if (useP) {
    // -------- sparse path: no global loads in the loop --------
    for (int w = 0; w < NWIN; w++) {
      if (wv == 0) {
        unsigned long long T = tdl[w * 64 + lane];
        unsigned long long sval = svl[w];
        unsigned long long s_in = sup[w];
        unsigned int supb = (unsigned int)((s_in >> lane) & 1ull);
        unsigned int Tlo = (unsigned int)T, Thi = (unsigned int)(T >> 32);
        unsigned int svlo = (unsigned int)sval, svhi = (unsigned int)(sval >> 32);
        unsigned long long kw = 0ull;
#pragma unroll
        for (int i = 0; i < 64; i++) {
          unsigned int si = (unsigned int)__builtin_amdgcn_readlane((int)supb, i);
          unsigned int vi = ((i < 32 ? svlo : svhi) >> (i & 31)) & 1u;
          unsigned int kp = vi & (si ^ 1u) & 1u;
          kw |= ((unsigned long long)kp) << i;
          unsigned int tbv = ((i < 32 ? Tlo : Thi) >> (i & 31)) & 1u;
          supb |= tbv & kp;
        }
        if (lane == 0) { keepw[b * NWIN + w] = kw; kwsh = kw; }
      }
      __syncthreads();
      unsigned long long kw = kwsh;
      for (uint32_t t = tid; t < npairs; t += 256) {
        uint32_t p = useL ? plp[t] : gpl[t];
        int i = (int)(p >> 13);
        if ((i >> 6) != w) continue;
        if (!((kw >> (i & 63)) & 1ull)) continue;
        int j = (int)(p & 8191u);
        atomicOr(&sup32[j >> 5], 1u << (j & 31));
      }
      __syncthreads();
    }
  } else {
    // -------- dense fallback (R11) --------
    for (int w = 0; w < NWIN; w++) {
      uint4 q[10];
      const uint4* src4 = (const uint4*)(mb + (size_t)w * 64 * NWORDS);
#pragma unroll
      for (int s = 0; s < 10; s++) {
        int c = tid + 256 * s;
        if (c < WCH && (2 * (c % 37) + 1 > w)) q[s] = src4[c];
      }
      if (wv == 0) {
        unsigned long long T = tdl[w * 64 + lane];
        unsigned long long sval = svl[w];
        unsigned long long s_in = sup[w];
        unsigned int supb = (unsigned int)((s_in >> lane) & 1ull);
        unsigned int Tlo = (unsigned int)T, Thi = (unsigned int)(T >> 32);
        unsigned int svlo = (unsigned int)sval, svhi = (unsigned int)(sval >> 32);
        unsigned long long kw = 0ull;
#pragma unroll
        for (int i = 0; i < 64; i++) {
          unsigned int si = (unsigned int)__builtin_amdgcn_readlane((int)supb, i);
          unsigned int vi = ((i < 32 ? svlo : svhi) >> (i & 31)) & 1u;
          unsigned int kp = vi & (si ^ 1u) & 1u;
          kw |= ((unsigned long long)kp) << i;
          unsigned int tbv = ((i < 32 ? Tlo : Thi) >> (i & 31)) & 1u;
          supb |= tbv & kp;
        }
        if (lane == 0) { keepw[b * NWIN + w] = kw; kwsh = kw; }
      }
      __syncthreads();
      unsigned long long kw = kwsh;
#pragma unroll
      for (int s = 0; s < 10; s++) {
        int c = tid + 256 * s;
        if (c >= WCH) continue;
        int wp = c % 37;
        if (2 * wp + 1 <= w) continue;
        int r = c / 37;
        if (!((kw >> r) & 1ull)) continue;
        int wlo = 2 * wp, whi = 2 * wp + 1;
        if (wlo > w) {
          if (q[s].x) atomicOr(&sup32[2 * wlo + 0], q[s].x);
          if (q[s].y) atomicOr(&sup32[2 * wlo + 1], q[s].y);
        }
        if (whi > w) {
          if (q[s].z) atomicOr(&sup32[2 * whi + 0], q[s].z);
          if (q[s].w) atomicOr(&sup32[2 * whi + 1], q[s].w);
        }
      }
      __syncthreads();
    }
  }
}

// ---------------- final outputs ----------------
__global__ void k_out(const float* __restrict__ ss, const uint32_t* __restrict__ sl,
                      const float* __restrict__ sb, const unsigned long long* __restrict__ keepw,
                      float* __restrict__ out) {
  int r = blockIdx.x * blockDim.x + threadIdx.x;
  if (r >= BN * KTOT) return;
  int b = r / KTOT;
  int e = r - b * KTOT;
  unsigned int kp = (unsigned int)((keepw[b * NWIN + (e >> 6)] >> (e & 63)) & 1ull);
  out[(size_t)r * 5 + 0] = sb[(size_t)r * 4 + 0];
  out[(size_t)r * 5 + 1] = sb[(size_t)r * 4 + 1];
  out[(size_t)r * 5 + 2] = sb[(size_t)r * 4 + 2];
  out[(size_t)r * 5 + 3] = sb[(size_t)r * 4 + 3];
  out[(size_t)r * 5 + 4] = ss[r];
  out[(size_t)BN * KTOT * 5 + r] = (float)sl[r];
  out[(size_t)BN * KTOT * 6 + r] = kp ? 1.0f : 0.0f;
}

extern "C" void kernel_launch(void* const* d_in, const int* in_sizes, int n_in,
                              void* d_out, int out_size, void* d_ws, size_t ws_size,
                              hipStream_t stream) {
  InPtrs ip;
  for (int l = 0; l < 5; l++) {
    ip.cls[l]  = (const float*)d_in[3 * l + 0];
    ip.bbox[l] = (const float*)d_in[3 * l + 1];
    ip.ctr[l]  = (const float*)d_in[3 * l + 2];
  }

  size_t off = 0;
  auto alloc = [&](size_t n) {
    char* p = (char*)d_ws + off;
    off = (off + n + 255) & ~(size_t)255;
    return p;
  };
  // region0: su + hist + small counters (phase A) overlaid with padded mask
  // (phase B). Small counters (selcnt/tiecnt/maxcb) are consumed before
  // k_mask writes the mask over them.
  const size_t SU_BYTES   = (size_t)BN * TOT * 4;                  // 2.73 MB
  const size_t HIST_BYTES = 20ull * 65536 * 4;                     // 5.24 MB
  const size_t EXTRA      = 256;                                   // selcnt/tiecnt/maxcb
  const size_t MASK_BYTES = (size_t)BN * (KTOT + 64) * NWORDS * 8; // 11.3 MB
  size_t region0 = ((SU_BYTES + 255) & ~(size_t)255) + HIST_BYTES + EXTRA;
  if (MASK_BYTES > region0) region0 = MASK_BYTES;
  char* r0p = (char*)alloc(region0);
  uint32_t* su   = (uint32_t*)r0p;
  uint32_t* hist = (uint32_t*)(r0p + ((SU_BYTES + 255) & ~(size_t)255));
  uint32_t* selcnt = hist + 20ull * 65536;
  uint32_t* tiecnt = selcnt + 20;
  uint32_t* maxcb  = tiecnt + 20;
  unsigned long long* mask = (unsigned long long*)r0p;

  uint32_t* mpfx   = (uint32_t*)alloc(20 * 4);
  uint32_t* mk     = (uint32_t*)alloc(20 * 4);
  uint32_t* selu   = (uint32_t*)alloc(20ull * 1024 * 4);
  uint32_t* seli   = (uint32_t*)alloc(20ull * 1024 * 4);
  uint32_t* tiei   = (uint32_t*)alloc(20ull * TIE_CAP * 4);
  float*    ccs    = (float*)   alloc((size_t)BN * KTOT * 4);
  uint32_t* ccl    = (uint32_t*)alloc((size_t)BN * KTOT * 4);
  uint32_t* ccv    = (uint32_t*)alloc((size_t)BN * KTOT * 4);
  float*    ccb    = (float*)   alloc((size_t)BN * KTOT * 16);
  float*    ss     = (float*)   alloc((size_t)BN * KTOT * 4);
  uint32_t* sl     = (uint32_t*)alloc((size_t)BN * KTOT * 4);
  uint32_t* sv     = (uint32_t*)alloc((size_t)BN * KTOT * 4);
  float*    sb     = (float*)   alloc((size_t)BN * KTOT * 16);
  float*    ob     = (float*)   alloc((size_t)BN * KTOT * 16);
  unsigned long long* tdiag = (unsigned long long*)alloc((size_t)BN * NWIN * 64 * 8); // 148 KB
  unsigned long long* vbits = (unsigned long long*)alloc((size_t)BN * NWIN * 8);
  unsigned long long* keepw = (unsigned long long*)alloc((size_t)BN * NWIN * 8);
  uint32_t* pairs   = (uint32_t*)alloc((size_t)BN * PAIR_CAP * 4);  // 2 MB
  uint32_t* paircnt = (uint32_t*)alloc(BN * 4);
  (void)ws_size; (void)in_sizes; (void)n_in; (void)out_size;

  dim3 gscan((TOT + 255) / 256, BN);
  hipMemsetAsync(hist, 0, HIST_BYTES + EXTRA, stream);   // hist + counters
  k_score<<<gscan, 256, 0, stream>>>(ip, su, hist);
  k_findp<<<20, 1024, 0, stream>>>(hist, mpfx, mk, 0);
  hipMemsetAsync(hist, 0, HIST_BYTES, stream);
  k_hist1<<<gscan, 256, 0, stream>>>(su, mpfx, hist);
  k_findp<<<20, 1024, 0, stream>>>(hist, mpfx, mk, 1);
  k_compact<<<gscan, 256, 0, stream>>>(su, mpfx, selcnt, tiecnt, selu, seli, tiei);
  k_ties<<<20, 256, 0, stream>>>(mpfx, mk, tiecnt, tiei, selu, seli);
  k_emit<<<dim3(20, 4), 256, 0, stream>>>(ip, selu, seli, ccs, ccl, ccv, ccb);
  k_sortimg<<<dim3(19, BN), 256, 0, stream>>>(ccs, ccl, ccv, ccb, ss, sl, sv, sb, maxcb);
  k_bits<<<dim3(NWIN, BN), 64, 0, stream>>>(sv, vbits);
  k_offset<<<(BN * KTOT + 255) / 256, 256, 0, stream>>>(sb, sl, maxcb, ob, paircnt);
  k_mask<<<dim3(19, 19, BN), 256, 0, stream>>>(ob, mask, tdiag, pairs, paircnt);
  k_nms<<<BN, 256, 0, stream>>>(mask, tdiag, vbits, keepw, pairs, paircnt);
  k_out<<<(BN * KTOT + 255) / 256, 256, 0, stream>>>(ss, sl, sb, keepw, (float*)d_out);
}

// Round 4
// 546.303 us; speedup vs baseline: 1.5904x; 1.1903x over previous
//
#include <hip/hip_runtime.h>
#include <stdint.h>

// FCOS bbox post-processing, B=4 images — bit-exact np/XLA-f32 replication
// (R7 semantics). R13: block-aggregated atomics. R14: k_mask 256x256 tiles.
// R15:
//  - k_score: c-major thread mapping -> coalesced cls reads (scattered su
//    writes are fire-and-forget, L2-merged). Constant-divisor decode.
//  - k_mask: tdiag now stores ROWS (dw directly); 64-ballot transpose deleted.
//  - k_nms: pairs bucketed by source window (count/prefix/scatter in LDS);
//    per-window scatter touches only its bucket. In-window closure is a
//    row-based sparse scalar scan (iterate set bits of ballot(row!=0)).

#define BN 4
#define NC 80
#define TOT 170720       // 128000+32000+8000+2000+720
#define KTOT 4720        // 1000*4+720
#define NWORDS 74        // ceil(4720/64)
#define NWIN 74
#define TIE_CAP 4096
#define IMGSZ 320.0f
#define WCH 2368         // uint4 chunks per 64-row window (64*74*8/16)
#define PAIR_CAP 131072  // pairs per image (global)
#define LDSP 12288       // pairs staged in LDS

struct InPtrs {
  const float* cls[5];
  const float* bbox[5];
  const float* ctr[5];
};

__device__ __forceinline__ uint32_t f2s(float f) {
  uint32_t x = __float_as_uint(f);
  return (x & 0x80000000u) ? ~x : (x | 0x80000000u);
}
__device__ __forceinline__ float s2f(uint32_t s) {
  uint32_t x = (s & 0x80000000u) ? (s & 0x7fffffffu) : ~s;
  return __uint_as_float(x);
}
// np/XLA logistic: 1/(1+exp(-x)) with per-op f32 rounding.
__device__ __forceinline__ float sigmoid32(float v) {
  float e = (float)exp(-(double)v);          // CR f32 exp(-v)
  return __fdiv_rn(1.0f, __fadd_rn(1.0f, e));
}
__device__ __forceinline__ void lvl_of(int e, int& l, int& le) {
  if (e < 128000)      { l = 0; le = e; }
  else if (e < 160000) { l = 1; le = e - 128000; }
  else if (e < 168000) { l = 2; le = e - 160000; }
  else if (e < 170000) { l = 3; le = e - 168000; }
  else                 { l = 4; le = e - 170000; }
}
__device__ __forceinline__ int kl_of(int l) {
  constexpr int KL[5] = {1000, 1000, 1000, 1000, 720};
  return KL[l];
}
__device__ __forceinline__ float clip32(float v) {
  return fminf(fmaxf(v, 0.0f), IMGSZ);
}
// IoU > 0.5 predicate, exact np f32 op chain (identical to R7-R11).
__device__ __forceinline__ int iou_gt(float bx1, float by1, float bx2, float by2,
                                      float bai, float4 o) {
  float ta_ = __fmul_rn(__fsub_rn(o.z, o.x), __fsub_rn(o.w, o.y));
  float ltx = fmaxf(bx1, o.x), lty = fmaxf(by1, o.y);
  float rbx = fminf(bx2, o.z), rby = fminf(by2, o.w);
  float wd = fmaxf(__fsub_rn(rbx, ltx), 0.0f);
  float hg = fmaxf(__fsub_rn(rby, lty), 0.0f);
  float inter = __fmul_rn(wd, hg);
  float asum = __fadd_rn(bai, ta_);
  float uni  = __fsub_rn(asum, inter);
  float iou  = (uni > 0.0f) ? __fdiv_rn(inter, uni) : 0.0f;
  return (iou > 0.5f) ? 1 : 0;
}

// ---------------- scores -> sortable u32 keys + pass-0 histogram ----------------
// R15: c-major mapping — lane-adjacent threads read adjacent spatial positions
// (coalesced). su write scattered (stride NC*4), L2-merged, no stall.
__global__ void k_score(InPtrs in, uint32_t* __restrict__ su, uint32_t* __restrict__ hist) {
  int b = blockIdx.y;
  int g = blockIdx.x * blockDim.x + threadIdx.x;
  if (g >= TOT) return;
  int l, le; lvl_of(g, l, le);
  int c, hw;
  switch (l) {
    case 0:  hw = 1600; c = le / 1600; break;
    case 1:  hw = 400;  c = le / 400;  break;
    case 2:  hw = 100;  c = le / 100;  break;
    case 3:  hw = 25;   c = le / 25;   break;
    default: hw = 9;    c = le / 9;    break;
  }
  int p = le - c * hw;
  float v = in.cls[l][((size_t)b * NC + c) * hw + p];
  float s = sigmoid32(v);
  float m = (s > 0.025f) ? s : -1.0f;
  uint32_t u = f2s(m);
  constexpr int LOFF[5] = {0, 128000, 160000, 168000, 170000};
  int e = LOFF[l] + p * NC + c;
  su[(size_t)b * TOT + e] = u;
  atomicAdd(&hist[(size_t)(b * 5 + l) * 65536u + (u >> 16)], 1u);
}

// ---------------- radix pass 1: low-16 histogram of matching keys ---------------
__global__ void k_hist1(const uint32_t* __restrict__ su, const uint32_t* __restrict__ mpfx,
                        uint32_t* __restrict__ hist) {
  int b = blockIdx.y;
  int e = blockIdx.x * blockDim.x + threadIdx.x;
  if (e >= TOT) return;
  int l, le; lvl_of(e, l, le);
  int bl = b * 5 + l;
  uint32_t key = su[(size_t)b * TOT + e];
  if ((key >> 16) == (mpfx[bl] >> 16))
    atomicAdd(&hist[(size_t)bl * 65536u + (key & 0xFFFFu)], 1u);
}

__global__ void k_findp(const uint32_t* __restrict__ hist, uint32_t* __restrict__ mpfx,
                        uint32_t* __restrict__ mk, int pass) {
  int bl = blockIdx.x;
  uint32_t k = (pass == 0) ? (uint32_t)kl_of(bl % 5) : mk[bl];
  uint32_t pfx = (pass == 0) ? 0u : mpfx[bl];
  const uint32_t* h = hist + (size_t)bl * 65536;
  __shared__ uint32_t sh[1024];
  int tid = threadIdx.x;
  int base = tid * 64;
  uint32_t s = 0;
  for (int i = 0; i < 64; i++) s += h[base + i];
  sh[tid] = s;
  __syncthreads();
  uint32_t above = 0;
  for (int t = tid + 1; t < 1024; t++) above += sh[t];
  if (above < k && above + s >= k) {
    uint32_t cum = above;
    for (int bin = base + 63; bin >= base; bin--) {
      uint32_t c = h[bin];
      if (cum < k && cum + c >= k) {
        if (pass == 0) mpfx[bl] = (uint32_t)bin << 16;
        else           mpfx[bl] = pfx | (uint32_t)bin;
        mk[bl] = k - cum;
        break;
      }
      cum += c;
    }
  }
}

// ---------------- compact selected (LDS-staged, block-aggregated atomics) -------
__global__ void k_compact(const uint32_t* __restrict__ su, const uint32_t* __restrict__ mpfx,
                          uint32_t* __restrict__ selcnt, uint32_t* __restrict__ tiecnt,
                          uint32_t* __restrict__ selu, uint32_t* __restrict__ seli,
                          uint32_t* __restrict__ tiei) {
  int b = blockIdx.y;
  int tid = threadIdx.x;
  int e0 = blockIdx.x * 256;
  int e = e0 + tid;
  int l0, le0; lvl_of(e0, l0, le0);
  __shared__ uint32_t cnt[2], tcnt[2], gbase[2], tgbase[2];
  __shared__ uint32_t su_s[2][256], si_s[2][256];   // staged selected (u, le)
  __shared__ uint32_t ti_s[2][256];                 // staged tie le
  if (tid < 2) { cnt[tid] = 0u; tcnt[tid] = 0u; }
  __syncthreads();
  if (e < TOT) {
    int l, le; lvl_of(e, l, le);
    int slot = l - l0;          // 0 or 1
    int bl = b * 5 + l;
    uint32_t u = su[(size_t)b * TOT + e];
    uint32_t C = mpfx[bl];
    if (u > C) {
      uint32_t p = atomicAdd(&cnt[slot], 1u);
      su_s[slot][p] = u;
      si_s[slot][p] = (uint32_t)le;
    } else if (u == C) {
      uint32_t p = atomicAdd(&tcnt[slot], 1u);
      ti_s[slot][p] = (uint32_t)le;
    }
  }
  __syncthreads();
  if (tid < 2) {
    int bl = b * 5 + l0 + tid;
    if (cnt[tid])  gbase[tid]  = atomicAdd(&selcnt[bl], cnt[tid]);
    if (tcnt[tid]) tgbase[tid] = atomicAdd(&tiecnt[bl], tcnt[tid]);
  }
  __syncthreads();
  for (int s = 0; s < 2; s++) {
    int bl = b * 5 + l0 + s;
    uint32_t n = cnt[s];
    for (uint32_t t = tid; t < n; t += 256) {
      uint32_t pos = gbase[s] + t;
      selu[(size_t)bl * 1024 + pos] = su_s[s][t];
      seli[(size_t)bl * 1024 + pos] = si_s[s][t];
    }
    uint32_t tn = tcnt[s];
    for (uint32_t t = tid; t < tn; t += 256) {
      uint32_t pos = tgbase[s] + t;
      if (pos < TIE_CAP) tiei[(size_t)bl * TIE_CAP + pos] = ti_s[s][t];
    }
  }
}

// Boundary ties: stable top_k -> smallest indices first.
__global__ void k_ties(const uint32_t* __restrict__ mpfx, const uint32_t* __restrict__ mk,
                       const uint32_t* __restrict__ tiecnt, const uint32_t* __restrict__ tiei,
                       uint32_t* __restrict__ selu, uint32_t* __restrict__ seli) {
  int bl = blockIdx.x;
  int l = bl % 5;
  uint32_t C = mpfx[bl];
  uint32_t T = mk[bl];
  uint32_t G = (uint32_t)kl_of(l) - T;
  uint32_t Tc = tiecnt[bl];
  if (Tc > TIE_CAP) Tc = TIE_CAP;
  __shared__ uint32_t sh[TIE_CAP];
  for (uint32_t t = threadIdx.x; t < Tc; t += blockDim.x) sh[t] = tiei[(size_t)bl * TIE_CAP + t];
  __syncthreads();
  for (uint32_t t = threadIdx.x; t < Tc; t += blockDim.x) {
    uint32_t my = sh[t];
    uint32_t rank = 0;
    for (uint32_t q = 0; q < Tc; q++) rank += (sh[q] < my) ? 1u : 0u;
    if (rank < T) {
      selu[(size_t)bl * 1024 + G + rank] = C;
      seli[(size_t)bl * 1024 + G + rank] = my;
    }
  }
}

// ---------------- exact rank within level + emit (packed u64 keys) --------------
__global__ void k_emit(InPtrs in, const uint32_t* __restrict__ selu, const uint32_t* __restrict__ seli,
                       float* __restrict__ ccs, uint32_t* __restrict__ ccl,
                       uint32_t* __restrict__ ccv, float* __restrict__ ccb) {
  int bl = blockIdx.x;
  int chunk = blockIdx.y;
  int b = bl / 5, l = bl % 5;
  int k = kl_of(l);
  __shared__ uint64_t z[1024];   // 8 KB
  int tid = threadIdx.x;
  for (int t = tid; t < 1024; t += 256) {
    if (t < k) {
      uint32_t u = selu[(size_t)bl * 1024 + t];
      uint32_t idx = seli[(size_t)bl * 1024 + t];
      z[t] = (((uint64_t)u) << 32) | (uint32_t)(~idx);
    } else z[t] = 0ull;
  }
  __syncthreads();
  int tg = chunk * 256 + tid;
  if (tg >= k) return;
  uint64_t zi = z[tg];
  uint32_t u = (uint32_t)(zi >> 32);
  uint32_t idx = ~(uint32_t)zi;
  int rank = 0;
  const uint4* z4 = (const uint4*)z;
  for (int j4 = 0; j4 < 512; j4++) {
    uint4 q = z4[j4];
    uint64_t za = (((uint64_t)q.y) << 32) | q.x;
    uint64_t zb = (((uint64_t)q.w) << 32) | q.z;
    rank += (za > zi) ? 1 : 0;
    rank += (zb > zi) ? 1 : 0;
  }
  constexpr int Wc[5]  = {40, 20, 10, 5, 3};
  constexpr int HWc[5] = {1600, 400, 100, 25, 9};
  constexpr float Sc[5] = {8.f, 16.f, 32.f, 64.f, 128.f};
  constexpr int COFF[5] = {0, 1000, 2000, 3000, 4000};
  int w = Wc[l], hw = HWc[l];
  float ms = s2f(u);
  int valid = (ms > 0.025f) ? 1 : 0;
  int p = (int)idx / NC, c = (int)idx % NC;
  int x = p % w, y = p / w;
  float sf = sigmoid32(in.ctr[l][(size_t)b * hw + p]);
  float score = valid ? __fmul_rn(ms, sf) : -1.0f;
  float px = __fmul_rn(__fadd_rn((float)x, 0.5f), Sc[l]);
  float py = __fmul_rn(__fadd_rn((float)y, 0.5f), Sc[l]);
  size_t bb = (size_t)b * 4 * hw;
  float d0 = in.bbox[l][bb + 0 * hw + p];
  float d1 = in.bbox[l][bb + 1 * hw + p];
  float d2 = in.bbox[l][bb + 2 * hw + p];
  float d3 = in.bbox[l][bb + 3 * hw + p];
  float x1 = clip32(__fsub_rn(px, d0)), y1 = clip32(__fsub_rn(py, d1));
  float x2 = clip32(__fadd_rn(px, d2)), y2 = clip32(__fadd_rn(py, d3));
  int o = b * KTOT + COFF[l] + rank;
  ccs[o] = score;
  ccl[o] = (uint32_t)c;
  ccv[o] = (uint32_t)valid;
  ccb[(size_t)o * 4 + 0] = x1; ccb[(size_t)o * 4 + 1] = y1;
  ccb[(size_t)o * 4 + 2] = x2; ccb[(size_t)o * 4 + 3] = y2;
}

// ---------------- per-image stable descending sort (rank method) ----------------
__global__ void k_sortimg(const float* __restrict__ ccs, const uint32_t* __restrict__ ccl,
                          const uint32_t* __restrict__ ccv, const float* __restrict__ ccb,
                          float* __restrict__ ss, uint32_t* __restrict__ sl,
                          uint32_t* __restrict__ sv, float* __restrict__ sb,
                          uint32_t* __restrict__ maxcb) {
  int b = blockIdx.y;
  __shared__ uint32_t key[KTOT];   // 18.9 KB
  __shared__ float red[4];
  int tid = threadIdx.x;
  for (int t = tid; t < KTOT; t += 256) key[t] = f2s(ccs[(size_t)b * KTOT + t]);
  __syncthreads();
  int e = blockIdx.x * 256 + tid;
  float mx = 0.0f;
  if (e < KTOT) {
    uint32_t ke = key[e];
    int rank = 0;
    const uint4* k4 = (const uint4*)key;
    for (int j4 = 0; j4 < KTOT / 4; j4++) {
      uint4 kk = k4[j4];
      int j = j4 * 4;
      rank += ((kk.x > ke) || (kk.x == ke && (j + 0) < e)) ? 1 : 0;
      rank += ((kk.y > ke) || (kk.y == ke && (j + 1) < e)) ? 1 : 0;
      rank += ((kk.z > ke) || (kk.z == ke && (j + 2) < e)) ? 1 : 0;
      rank += ((kk.w > ke) || (kk.w == ke && (j + 3) < e)) ? 1 : 0;
    }
    int sidx = b * KTOT + e;
    int d = b * KTOT + rank;
    ss[d] = ccs[sidx];
    sl[d] = ccl[sidx];
    sv[d] = ccv[sidx];
    float b0 = ccb[(size_t)sidx * 4 + 0], b1 = ccb[(size_t)sidx * 4 + 1];
    float b2 = ccb[(size_t)sidx * 4 + 2], b3 = ccb[(size_t)sidx * 4 + 3];
    sb[(size_t)d * 4 + 0] = b0; sb[(size_t)d * 4 + 1] = b1;
    sb[(size_t)d * 4 + 2] = b2; sb[(size_t)d * 4 + 3] = b3;
    mx = fmaxf(fmaxf(b0, b1), fmaxf(b2, b3));
  }
  for (int o = 32; o; o >>= 1) mx = fmaxf(mx, __shfl_xor(mx, o));
  if ((tid & 63) == 0) red[tid >> 6] = mx;
  __syncthreads();
  if (tid == 0)
    atomicMax(&maxcb[b], __float_as_uint(fmaxf(fmaxf(red[0], red[1]), fmaxf(red[2], red[3]))));
}

// ---------------- valid bits -> bitmask words ----------------
__global__ void k_bits(const uint32_t* __restrict__ sv, unsigned long long* __restrict__ vbits) {
  int w = blockIdx.x, b = blockIdx.y, lane = threadIdx.x;
  int e = w * 64 + lane;
  int pred = (e < KTOT) ? (sv[(size_t)b * KTOT + e] != 0u) : 0;
  unsigned long long m = __ballot(pred);
  if (lane == 0) vbits[b * NWIN + w] = m;
}

// ---------------- per-class offset boxes (f32); also zeroes paircnt -------------
__global__ void k_offset(const float* __restrict__ sb, const uint32_t* __restrict__ sl,
                         const uint32_t* __restrict__ maxcb, float* __restrict__ ob,
                         uint32_t* __restrict__ paircnt) {
  if (blockIdx.x == 0 && threadIdx.x < BN) paircnt[threadIdx.x] = 0u;
  int r = blockIdx.x * blockDim.x + threadIdx.x;
  if (r >= BN * KTOT) return;
  int b = r / KTOT;
  float scale = __fadd_rn(__uint_as_float(maxcb[b]), 1.0f);
  float offv = __fmul_rn((float)sl[r], scale);
  float x1 = __fadd_rn(sb[(size_t)r * 4 + 0], offv);
  float y1 = __fadd_rn(sb[(size_t)r * 4 + 1], offv);
  float x2 = __fadd_rn(sb[(size_t)r * 4 + 2], offv);
  float y2 = __fadd_rn(sb[(size_t)r * 4 + 3], offv);
  ob[(size_t)r * 4 + 0] = x1; ob[(size_t)r * 4 + 1] = y1;
  ob[(size_t)r * 4 + 2] = x2; ob[(size_t)r * 4 + 3] = y2;
}

// ---------------- IoU bitmask, 2D-tiled (256x256) + pair emission ---------------
// R15: tdiag stores ROWS (dw) directly — ballot transpose removed.
__global__ void k_mask(const float* __restrict__ ob, unsigned long long* __restrict__ mask,
                       unsigned long long* __restrict__ tdiag,
                       uint32_t* __restrict__ pairs, uint32_t* __restrict__ paircnt) {
  int b = blockIdx.z;
  int jt = blockIdx.y;
  int ib = blockIdx.x;
  int jbase = jt * 256;
  int cnt = min(256, KTOT - jbase);
  bool diagBlock = (jt == ib);
  if (!diagBlock && (jbase + cnt - 1 <= ib * 256)) return;   // jt < ib
  __shared__ float4 tb[256];   // 4 KB
  int tid = threadIdx.x;
  if (tid < cnt)
    tb[tid] = ((const float4*)ob)[(size_t)b * KTOT + jbase + tid];
  __syncthreads();
  int i = ib * 256 + tid;
  bool act = (i < KTOT);
  float bx1 = 0, by1 = 0, bx2 = 0, by2 = 0, bai = 0;
  if (act) {
    float4 v = ((const float4*)ob)[(size_t)b * KTOT + i];
    bx1 = v.x; by1 = v.y; bx2 = v.z; by2 = v.w;
    bai = __fmul_rn(__fsub_rn(bx2, bx1), __fsub_rn(by2, by1));
  }
  int myw = i >> 6;
  unsigned long long dw = 0ull;
  if (act) {
    unsigned long long* mrow = mask + ((size_t)b * (KTOT + 64) + i) * NWORDS;
    int nw = (cnt + 63) >> 6;
    for (int w = 0; w < nw; w++) {
      int gw = jt * 4 + w;
      if (gw < myw) continue;
      unsigned long long bits = 0ull;
      int j0 = w * 64;
      int jn = min(64, cnt - j0);
      if (gw == myw) {
        for (int jj = 0; jj < jn; jj++) {
          if (jbase + j0 + jj > i)
            bits |= ((unsigned long long)iou_gt(bx1, by1, bx2, by2, bai, tb[j0 + jj])) << jj;
        }
        dw = bits;
      } else {
        for (int jj = 0; jj < jn; jj++)
          bits |= ((unsigned long long)iou_gt(bx1, by1, bx2, by2, bai, tb[j0 + jj])) << jj;
        mrow[gw] = bits;
        if (bits) {   // emit sparse pairs (i<<13)|j; jword>iword by construction
          uint32_t pos = atomicAdd(&paircnt[b], (uint32_t)__popcll(bits));
          unsigned long long t = bits;
          while (t) {
            int jj = __ffsll((long long)t) - 1; t &= t - 1;
            if (pos < PAIR_CAP)
              pairs[(size_t)b * PAIR_CAP + pos] = ((uint32_t)i << 13) | (uint32_t)(jbase + j0 + jj);
            pos++;
          }
        }
      }
    }
  }
  if (diagBlock && myw < NWIN) {
    tdiag[((size_t)b * NWIN + (size_t)myw) * 64 + (tid & 63)] = dw;   // row store
  }
}

// ---------------- bucketed sparse-pair blocked greedy NMS, 256 thr/image --------
__global__ void k_nms(const unsigned long long* __restrict__ mask,
                      const unsigned long long* __restrict__ tdiag,
                      const unsigned long long* __restrict__ vbits,
                      unsigned long long* __restrict__ keepw,
                      const uint32_t* __restrict__ pairs,
                      const uint32_t* __restrict__ paircnt) {
  int b = blockIdx.x;
  int tid = threadIdx.x;
  int lane = tid & 63;
  int wv = tid >> 6;
  const unsigned long long* mb = mask + (size_t)b * (KTOT + 64) * NWORDS;
  __shared__ unsigned long long tdl[NWIN * 64];   // rows; 37888 B
  __shared__ unsigned long long svl[NWIN];
  __shared__ unsigned long long sup[NWIN];
  __shared__ unsigned long long kwsh;
  __shared__ uint32_t plp[LDSP];                  // window-sorted pairs; 49152 B
  __shared__ uint32_t wstart[NWIN + 1];
  __shared__ uint32_t wtmp[NWIN];
  {
    const uint4* src = (const uint4*)(tdiag + (size_t)b * NWIN * 64);
    uint4* dst = (uint4*)tdl;
#pragma unroll
    for (int s = 0; s < 10; s++) {
      int c = tid + 256 * s;
      if (c < WCH) dst[c] = src[c];
    }
  }
  if (tid < NWIN) { svl[tid] = vbits[b * NWIN + tid]; sup[tid] = 0ull; wtmp[tid] = 0u; }
  uint32_t npairs = paircnt[b];
  bool useP = (npairs <= (uint32_t)PAIR_CAP);
  bool useL = (npairs <= (uint32_t)LDSP);
  const uint32_t* gpl = pairs + (size_t)b * PAIR_CAP;
  __syncthreads();
  if (useL) {
    // bucket pairs by source window: count -> prefix -> scatter
    for (uint32_t t = tid; t < npairs; t += 256) atomicAdd(&wtmp[gpl[t] >> 19], 1u);
    __syncthreads();
    if (tid == 0) {
      uint32_t acc = 0;
      for (int w = 0; w < NWIN; w++) { wstart[w] = acc; acc += wtmp[w]; }
      wstart[NWIN] = acc;
    }
    __syncthreads();
    if (tid < NWIN) wtmp[tid] = 0u;
    __syncthreads();
    for (uint32_t t = tid; t < npairs; t += 256) {
      uint32_t p = gpl[t];
      uint32_t w = p >> 19;
      uint32_t pos = wstart[w] + atomicAdd(&wtmp[w], 1u);
      plp[pos] = p;
    }
  }
  __syncthreads();
  unsigned int* sup32 = (unsigned int*)sup;
  if (useP) {
    for (int w = 0; w < NWIN; w++) {
      if (wv == 0) {
        // row-based sparse closure; result uniform across wave 0.
        unsigned long long row = tdl[w * 64 + lane];
        unsigned long long m = __ballot(row != 0ull);
        unsigned long long sa = sup[w];
        unsigned long long sval = svl[w];
        unsigned int rlo = (unsigned int)row, rhi = (unsigned int)(row >> 32);
        while (m) {
          int i = __ffsll((long long)m) - 1;
          m &= m - 1;
          if (((sval >> i) & 1ull) && !((sa >> i) & 1ull)) {
            unsigned int lo = (unsigned int)__builtin_amdgcn_readlane((int)rlo, i);
            unsigned int hi = (unsigned int)__builtin_amdgcn_readlane((int)rhi, i);
            sa |= (((unsigned long long)hi) << 32) | (unsigned long long)lo;
          }
        }
        unsigned long long kw = sval & ~sa;
        if (lane == 0) { keepw[b * NWIN + w] = kw; kwsh = kw; }
      }
      __syncthreads();
      unsigned long long kw = kwsh;
      if (useL) {
        for (uint32_t t = wstart[w] + tid; t < wstart[w + 1]; t += 256) {
          uint32_t p = plp[t];
          int i = (int)(p >> 13);
          if (!((kw >> (i & 63)) & 1ull)) continue;
          int j = (int)(p & 8191u);
          atomicOr(&sup32[j >> 5], 1u << (j & 31));
        }
      } else {
        for (uint32_t t = tid; t < npairs; t += 256) {
          uint32_t p = gpl[t];
          int i = (int)(p >> 13);
          if ((i >> 6) != w) continue;
          if (!((kw >> (i & 63)) & 1ull)) continue;
          int j = (int)(p & 8191u);
          atomicOr(&sup32[j >> 5], 1u << (j & 31));
        }
      }
      __syncthreads();
    }
  } else {
    // -------- dense fallback (mask words), row-based scan --------
    for (int w = 0; w < NWIN; w++) {
      uint4 q[10];
      const uint4* src4 = (const uint4*)(mb + (size_t)w * 64 * NWORDS);
#pragma unroll
      for (int s = 0; s < 10; s++) {
        int c = tid + 256 * s;
        if (c < WCH && (2 * (c % 37) + 1 > w)) q[s] = src4[c];
      }
      if (wv == 0) {
        unsigned long long row = tdl[w * 64 + lane];
        unsigned long long m = __ballot(row != 0ull);
        unsigned long long sa = sup[w];
        unsigned long long sval = svl[w];
        unsigned int rlo = (unsigned int)row, rhi = (unsigned int)(row >> 32);
        while (m) {
          int i = __ffsll((long long)m) - 1;
          m &= m - 1;
          if (((sval >> i) & 1ull) && !((sa >> i) & 1ull)) {
            unsigned int lo = (unsigned int)__builtin_amdgcn_readlane((int)rlo, i);
            unsigned int hi = (unsigned int)__builtin_amdgcn_readlane((int)rhi, i);
            sa |= (((unsigned long long)hi) << 32) | (unsigned long long)lo;
          }
        }
        unsigned long long kw = sval & ~sa;
        if (lane == 0) { keepw[b * NWIN + w] = kw; kwsh = kw; }
      }
      __syncthreads();
      unsigned long long kw = kwsh;
#pragma unroll
      for (int s = 0; s < 10; s++) {
        int c = tid + 256 * s;
        if (c >= WCH) continue;
        int wp = c % 37;
        if (2 * wp + 1 <= w) continue;
        int r = c / 37;
        if (!((kw >> r) & 1ull)) continue;
        int wlo = 2 * wp, whi = 2 * wp + 1;
        if (wlo > w) {
          if (q[s].x) atomicOr(&sup32[2 * wlo + 0], q[s].x);
          if (q[s].y) atomicOr(&sup32[2 * wlo + 1], q[s].y);
        }
        if (whi > w) {
          if (q[s].z) atomicOr(&sup32[2 * whi + 0], q[s].z);
          if (q[s].w) atomicOr(&sup32[2 * whi + 1], q[s].w);
        }
      }
      __syncthreads();
    }
  }
}

// ---------------- final outputs ----------------
__global__ void k_out(const float* __restrict__ ss, const uint32_t* __restrict__ sl,
                      const float* __restrict__ sb, const unsigned long long* __restrict__ keepw,
                      float* __restrict__ out) {
  int r = blockIdx.x * blockDim.x + threadIdx.x;
  if (r >= BN * KTOT) return;
  int b = r / KTOT;
  int e = r - b * KTOT;
  unsigned int kp = (unsigned int)((keepw[b * NWIN + (e >> 6)] >> (e & 63)) & 1ull);
  out[(size_t)r * 5 + 0] = sb[(size_t)r * 4 + 0];
  out[(size_t)r * 5 + 1] = sb[(size_t)r * 4 + 1];
  out[(size_t)r * 5 + 2] = sb[(size_t)r * 4 + 2];
  out[(size_t)r * 5 + 3] = sb[(size_t)r * 4 + 3];
  out[(size_t)r * 5 + 4] = ss[r];
  out[(size_t)BN * KTOT * 5 + r] = (float)sl[r];
  out[(size_t)BN * KTOT * 6 + r] = kp ? 1.0f : 0.0f;
}

extern "C" void kernel_launch(void* const* d_in, const int* in_sizes, int n_in,
                              void* d_out, int out_size, void* d_ws, size_t ws_size,
                              hipStream_t stream) {
  InPtrs ip;
  for (int l = 0; l < 5; l++) {
    ip.cls[l]  = (const float*)d_in[3 * l + 0];
    ip.bbox[l] = (const float*)d_in[3 * l + 1];
    ip.ctr[l]  = (const float*)d_in[3 * l + 2];
  }

  size_t off = 0;
  auto alloc = [&](size_t n) {
    char* p = (char*)d_ws + off;
    off = (off + n + 255) & ~(size_t)255;
    return p;
  };
  // region0: su + hist + small counters (phase A) overlaid with padded mask
  // (phase B). Small counters (selcnt/tiecnt/maxcb) are consumed before
  // k_mask writes the mask over them.
  const size_t SU_BYTES   = (size_t)BN * TOT * 4;                  // 2.73 MB
  const size_t HIST_BYTES = 20ull * 65536 * 4;                     // 5.24 MB
  const size_t EXTRA      = 256;                                   // selcnt/tiecnt/maxcb
  const size_t MASK_BYTES = (size_t)BN * (KTOT + 64) * NWORDS * 8; // 11.3 MB
  size_t region0 = ((SU_BYTES + 255) & ~(size_t)255) + HIST_BYTES + EXTRA;
  if (MASK_BYTES > region0) region0 = MASK_BYTES;
  char* r0p = (char*)alloc(region0);
  uint32_t* su   = (uint32_t*)r0p;
  uint32_t* hist = (uint32_t*)(r0p + ((SU_BYTES + 255) & ~(size_t)255));
  uint32_t* selcnt = hist + 20ull * 65536;
  uint32_t* tiecnt = selcnt + 20;
  uint32_t* maxcb  = tiecnt + 20;
  unsigned long long* mask = (unsigned long long*)r0p;

  uint32_t* mpfx   = (uint32_t*)alloc(20 * 4);
  uint32_t* mk     = (uint32_t*)alloc(20 * 4);
  uint32_t* selu   = (uint32_t*)alloc(20ull * 1024 * 4);
  uint32_t* seli   = (uint32_t*)alloc(20ull * 1024 * 4);
  uint32_t* tiei   = (uint32_t*)alloc(20ull * TIE_CAP * 4);
  float*    ccs    = (float*)   alloc((size_t)BN * KTOT * 4);
  uint32_t* ccl    = (uint32_t*)alloc((size_t)BN * KTOT * 4);
  uint32_t* ccv    = (uint32_t*)alloc((size_t)BN * KTOT * 4);
  float*    ccb    = (float*)   alloc((size_t)BN * KTOT * 16);
  float*    ss     = (float*)   alloc((size_t)BN * KTOT * 4);
  uint32_t* sl     = (uint32_t*)alloc((size_t)BN * KTOT * 4);
  uint32_t* sv     = (uint32_t*)alloc((size_t)BN * KTOT * 4);
  float*    sb     = (float*)   alloc((size_t)BN * KTOT * 16);
  float*    ob     = (float*)   alloc((size_t)BN * KTOT * 16);
  unsigned long long* tdiag = (unsigned long long*)alloc((size_t)BN * NWIN * 64 * 8); // 148 KB
  unsigned long long* vbits = (unsigned long long*)alloc((size_t)BN * NWIN * 8);
  unsigned long long* keepw = (unsigned long long*)alloc((size_t)BN * NWIN * 8);
  uint32_t* pairs   = (uint32_t*)alloc((size_t)BN * PAIR_CAP * 4);  // 2 MB
  uint32_t* paircnt = (uint32_t*)alloc(BN * 4);
  (void)ws_size; (void)in_sizes; (void)n_in; (void)out_size;

  dim3 gscan((TOT + 255) / 256, BN);
  hipMemsetAsync(hist, 0, HIST_BYTES + EXTRA, stream);   // hist + counters
  k_score<<<gscan, 256, 0, stream>>>(ip, su, hist);
  k_findp<<<20, 1024, 0, stream>>>(hist, mpfx, mk, 0);
  hipMemsetAsync(hist, 0, HIST_BYTES, stream);
  k_hist1<<<gscan, 256, 0, stream>>>(su, mpfx, hist);
  k_findp<<<20, 1024, 0, stream>>>(hist, mpfx, mk, 1);
  k_compact<<<gscan, 256, 0, stream>>>(su, mpfx, selcnt, tiecnt, selu, seli, tiei);
  k_ties<<<20, 256, 0, stream>>>(mpfx, mk, tiecnt, tiei, selu, seli);
  k_emit<<<dim3(20, 4), 256, 0, stream>>>(ip, selu, seli, ccs, ccl, ccv, ccb);
  k_sortimg<<<dim3(19, BN), 256, 0, stream>>>(ccs, ccl, ccv, ccb, ss, sl, sv, sb, maxcb);
  k_bits<<<dim3(NWIN, BN), 64, 0, stream>>>(sv, vbits);
  k_offset<<<(BN * KTOT + 255) / 256, 256, 0, stream>>>(sb, sl, maxcb, ob, paircnt);
  k_mask<<<dim3(19, 19, BN), 256, 0, stream>>>(ob, mask, tdiag, pairs, paircnt);
  k_nms<<<BN, 256, 0, stream>>>(mask, tdiag, vbits, keepw, pairs, paircnt);
  k_out<<<(BN * KTOT + 255) / 256, 256, 0, stream>>>(ss, sl, sb, keepw, (float*)d_out);
}

// Round 5
// 400.356 us; speedup vs baseline: 2.1702x; 1.3645x over previous
//
#include <hip/hip_runtime.h>
#include <stdint.h>

// FCOS bbox post-processing, B=4 images — bit-exact np/XLA-f32 replication
// (R7 semantics). R13: block-aggregated atomics. R14: k_mask 256x256 tiles.
// R15: row tdiag + bucketed NMS. R16: selection via 3-digit radix (10/10/12)
// with LDS-aggregated histograms:
//  - k_score: (64p x 80c) tiles; coalesced cls reads, LDS transpose ->
//    contiguous su writes, LDS 1024-bin pass-0 hist (global atomics
//    683k -> ~2k). Kills the device-atomic + partial-line-write scatter
//    that pinned k_score at ~134us regardless of read layout (R14==R15).
//  - k_scan1: pass-1 hist (bits 21-12) of top-10 matches, LDS-aggregated.
//  - k_scan2: pass-2 hist (low 12) of top-20 matches, direct atomics (rare).
//  - generic k_findp; same boundary C / tie-count T as the old 16+16 radix.

#define BN 4
#define NC 80
#define TOT 170720       // 128000+32000+8000+2000+720
#define KTOT 4720        // 1000*4+720
#define NWORDS 74        // ceil(4720/64)
#define NWIN 74
#define TIE_CAP 4096
#define IMGSZ 320.0f
#define WCH 2368         // uint4 chunks per 64-row window (64*74*8/16)
#define PAIR_CAP 131072  // pairs per image (global)
#define LDSP 12288       // pairs staged in LDS

struct InPtrs {
  const float* cls[5];
  const float* bbox[5];
  const float* ctr[5];
};

__device__ __forceinline__ uint32_t f2s(float f) {
  uint32_t x = __float_as_uint(f);
  return (x & 0x80000000u) ? ~x : (x | 0x80000000u);
}
__device__ __forceinline__ float s2f(uint32_t s) {
  uint32_t x = (s & 0x80000000u) ? (s & 0x7fffffffu) : ~s;
  return __uint_as_float(x);
}
// np/XLA logistic: 1/(1+exp(-x)) with per-op f32 rounding.
__device__ __forceinline__ float sigmoid32(float v) {
  float e = (float)exp(-(double)v);          // CR f32 exp(-v)
  return __fdiv_rn(1.0f, __fadd_rn(1.0f, e));
}
__device__ __forceinline__ void lvl_of(int e, int& l, int& le) {
  if (e < 128000)      { l = 0; le = e; }
  else if (e < 160000) { l = 1; le = e - 128000; }
  else if (e < 168000) { l = 2; le = e - 160000; }
  else if (e < 170000) { l = 3; le = e - 168000; }
  else                 { l = 4; le = e - 170000; }
}
__device__ __forceinline__ int kl_of(int l) {
  constexpr int KL[5] = {1000, 1000, 1000, 1000, 720};
  return KL[l];
}
__device__ __forceinline__ float clip32(float v) {
  return fminf(fmaxf(v, 0.0f), IMGSZ);
}
// tile table for k_score: 36 tiles/image of (<=64 p) x (80 c)
__device__ __forceinline__ void tile_of(int t, int& l, int& p0) {
  if (t < 25)       { l = 0; p0 = t * 64; }
  else if (t < 32)  { l = 1; p0 = (t - 25) * 64; }
  else if (t < 34)  { l = 2; p0 = (t - 32) * 64; }
  else if (t == 34) { l = 3; p0 = 0; }
  else              { l = 4; p0 = 0; }
}
// IoU > 0.5 predicate, exact np f32 op chain (identical to R7-R11).
__device__ __forceinline__ int iou_gt(float bx1, float by1, float bx2, float by2,
                                      float bai, float4 o) {
  float ta_ = __fmul_rn(__fsub_rn(o.z, o.x), __fsub_rn(o.w, o.y));
  float ltx = fmaxf(bx1, o.x), lty = fmaxf(by1, o.y);
  float rbx = fminf(bx2, o.z), rby = fminf(by2, o.w);
  float wd = fmaxf(__fsub_rn(rbx, ltx), 0.0f);
  float hg = fmaxf(__fsub_rn(rby, lty), 0.0f);
  float inter = __fmul_rn(wd, hg);
  float asum = __fadd_rn(bai, ta_);
  float uni  = __fsub_rn(asum, inter);
  float iou  = (uni > 0.0f) ? __fdiv_rn(inter, uni) : 0.0f;
  return (iou > 0.5f) ? 1 : 0;
}

// ---------------- scores -> sortable u32 keys + pass-0 LDS histogram -----------
__global__ void k_score(InPtrs in, uint32_t* __restrict__ su, uint32_t* __restrict__ hist0) {
  int b = blockIdx.y;
  int tl, p0; tile_of(blockIdx.x, tl, p0);
  constexpr int HWc[5]  = {1600, 400, 100, 25, 9};
  constexpr int LOFF[5] = {0, 128000, 160000, 168000, 170000};
  int hw = HWc[tl];
  int tw = min(64, hw - p0);
  int tid = threadIdx.x;
  __shared__ uint32_t lu[64 * 81];   // padded transpose tile (20.7 KB)
  __shared__ uint32_t lh[1024];      // pass-0 hist (4 KB)
  for (int i = tid; i < 1024; i += 256) lh[i] = 0;
  __syncthreads();
  int pf = tid & 63;
  if (pf < tw) {
    const float* cp = in.cls[tl] + (size_t)b * NC * hw + p0 + pf;
    for (int c = tid >> 6; c < NC; c += 4) {
      float v = cp[(size_t)c * hw];                 // coalesced (64-lane run)
      float s = sigmoid32(v);
      float m = (s > 0.025f) ? s : -1.0f;
      uint32_t u = f2s(m);
      lu[pf * 81 + c] = u;
      atomicAdd(&lh[u >> 22], 1u);                  // LDS atomic
    }
  }
  __syncthreads();
  int bl = b * 5 + tl;
  for (int i = tid; i < 1024; i += 256)
    if (lh[i]) atomicAdd(&hist0[(size_t)bl * 1024 + i], lh[i]);
  int n = tw * NC;
  uint32_t* dst = su + (size_t)b * TOT + LOFF[tl] + p0 * NC;
  for (int idx = tid; idx < n; idx += 256)
    dst[idx] = lu[(idx / 80) * 81 + (idx % 80)];    // contiguous store
}

// ---------------- radix pass 1: bits 21-12 of top-10 matches (LDS) -------------
__global__ void k_scan1(const uint32_t* __restrict__ su, const uint32_t* __restrict__ mpfx,
                        uint32_t* __restrict__ hist1) {
  int b = blockIdx.y;
  int tid = threadIdx.x;
  int e0 = blockIdx.x * 256;
  int e = e0 + tid;
  int l0, le0; lvl_of(e0, l0, le0);
  __shared__ uint32_t lh[2][1024];   // two slots: block may span 2 levels
  for (int i = tid; i < 2048; i += 256) lh[i >> 10][i & 1023] = 0;
  __syncthreads();
  if (e < TOT) {
    int l, le; lvl_of(e, l, le);
    uint32_t C = mpfx[b * 5 + l];
    uint32_t u = su[(size_t)b * TOT + e];
    if ((u >> 22) == (C >> 22)) atomicAdd(&lh[l - l0][(u >> 12) & 1023u], 1u);
  }
  __syncthreads();
  for (int s = 0; s < 2; s++) {
    int l = l0 + s;
    if (l >= 5) break;
    int bl = b * 5 + l;
    for (int i = tid; i < 1024; i += 256)
      if (lh[s][i]) atomicAdd(&hist1[(size_t)bl * 1024 + i], lh[s][i]);
  }
}

// ---------------- radix pass 2: low 12 bits of top-20 matches (rare) -----------
__global__ void k_scan2(const uint32_t* __restrict__ su, const uint32_t* __restrict__ mpfx,
                        uint32_t* __restrict__ hist2) {
  int b = blockIdx.y;
  int e = blockIdx.x * blockDim.x + threadIdx.x;
  if (e >= TOT) return;
  int l, le; lvl_of(e, l, le);
  int bl = b * 5 + l;
  uint32_t C = mpfx[bl];
  uint32_t u = su[(size_t)b * TOT + e];
  if ((u >> 12) == (C >> 12))
    atomicAdd(&hist2[(size_t)bl * 4096 + (u & 4095u)], 1u);
}

// ---------------- generic digit select (suffix-count crossing) -----------------
__global__ void k_findp(const uint32_t* __restrict__ hist, uint32_t* __restrict__ mpfx,
                        uint32_t* __restrict__ mk, int nbins, int shift, int pass) {
  int bl = blockIdx.x;
  uint32_t k = (pass == 0) ? (uint32_t)kl_of(bl % 5) : mk[bl];
  const uint32_t* h = hist + (size_t)bl * nbins;
  __shared__ uint32_t gsum[256];
  int tid = threadIdx.x;
  int per = nbins / 256;             // 4 or 16
  int base = tid * per;
  uint32_t s = 0;
  for (int i = 0; i < per; i++) s += h[base + i];
  gsum[tid] = s;
  __syncthreads();
  uint32_t above = 0;
  for (int t = tid + 1; t < 256; t++) above += gsum[t];
  if (above < k && above + s >= k) {
    uint32_t cum = above;
    for (int bin = base + per - 1; bin >= base; bin--) {
      uint32_t c = h[bin];
      if (cum < k && cum + c >= k) {
        uint32_t pfx = (pass == 0) ? 0u : mpfx[bl];
        mpfx[bl] = pfx | ((uint32_t)bin << shift);
        mk[bl] = k - cum;
        break;
      }
      cum += c;
    }
  }
}

// ---------------- compact selected (LDS-staged, block-aggregated atomics) -------
__global__ void k_compact(const uint32_t* __restrict__ su, const uint32_t* __restrict__ mpfx,
                          uint32_t* __restrict__ selcnt, uint32_t* __restrict__ tiecnt,
                          uint32_t* __restrict__ selu, uint32_t* __restrict__ seli,
                          uint32_t* __restrict__ tiei) {
  int b = blockIdx.y;
  int tid = threadIdx.x;
  int e0 = blockIdx.x * 256;
  int e = e0 + tid;
  int l0, le0; lvl_of(e0, l0, le0);
  __shared__ uint32_t cnt[2], tcnt[2], gbase[2], tgbase[2];
  __shared__ uint32_t su_s[2][256], si_s[2][256];   // staged selected (u, le)
  __shared__ uint32_t ti_s[2][256];                 // staged tie le
  if (tid < 2) { cnt[tid] = 0u; tcnt[tid] = 0u; }
  __syncthreads();
  if (e < TOT) {
    int l, le; lvl_of(e, l, le);
    int slot = l - l0;          // 0 or 1
    int bl = b * 5 + l;
    uint32_t u = su[(size_t)b * TOT + e];
    uint32_t C = mpfx[bl];
    if (u > C) {
      uint32_t p = atomicAdd(&cnt[slot], 1u);
      su_s[slot][p] = u;
      si_s[slot][p] = (uint32_t)le;
    } else if (u == C) {
      uint32_t p = atomicAdd(&tcnt[slot], 1u);
      ti_s[slot][p] = (uint32_t)le;
    }
  }
  __syncthreads();
  if (tid < 2) {
    int bl = b * 5 + l0 + tid;
    if (cnt[tid])  gbase[tid]  = atomicAdd(&selcnt[bl], cnt[tid]);
    if (tcnt[tid]) tgbase[tid] = atomicAdd(&tiecnt[bl], tcnt[tid]);
  }
  __syncthreads();
  for (int s = 0; s < 2; s++) {
    int bl = b * 5 + l0 + s;
    uint32_t n = cnt[s];
    for (uint32_t t = tid; t < n; t += 256) {
      uint32_t pos = gbase[s] + t;
      selu[(size_t)bl * 1024 + pos] = su_s[s][t];
      seli[(size_t)bl * 1024 + pos] = si_s[s][t];
    }
    uint32_t tn = tcnt[s];
    for (uint32_t t = tid; t < tn; t += 256) {
      uint32_t pos = tgbase[s] + t;
      if (pos < TIE_CAP) tiei[(size_t)bl * TIE_CAP + pos] = ti_s[s][t];
    }
  }
}

// Boundary ties: stable top_k -> smallest indices first.
__global__ void k_ties(const uint32_t* __restrict__ mpfx, const uint32_t* __restrict__ mk,
                       const uint32_t* __restrict__ tiecnt, const uint32_t* __restrict__ tiei,
                       uint32_t* __restrict__ selu, uint32_t* __restrict__ seli) {
  int bl = blockIdx.x;
  int l = bl % 5;
  uint32_t C = mpfx[bl];
  uint32_t T = mk[bl];
  uint32_t G = (uint32_t)kl_of(l) - T;
  uint32_t Tc = tiecnt[bl];
  if (Tc > TIE_CAP) Tc = TIE_CAP;
  __shared__ uint32_t sh[TIE_CAP];
  for (uint32_t t = threadIdx.x; t < Tc; t += blockDim.x) sh[t] = tiei[(size_t)bl * TIE_CAP + t];
  __syncthreads();
  for (uint32_t t = threadIdx.x; t < Tc; t += blockDim.x) {
    uint32_t my = sh[t];
    uint32_t rank = 0;
    for (uint32_t q = 0; q < Tc; q++) rank += (sh[q] < my) ? 1u : 0u;
    if (rank < T) {
      selu[(size_t)bl * 1024 + G + rank] = C;
      seli[(size_t)bl * 1024 + G + rank] = my;
    }
  }
}

// ---------------- exact rank within level + emit (packed u64 keys) --------------
__global__ void k_emit(InPtrs in, const uint32_t* __restrict__ selu, const uint32_t* __restrict__ seli,
                       float* __restrict__ ccs, uint32_t* __restrict__ ccl,
                       uint32_t* __restrict__ ccv, float* __restrict__ ccb) {
  int bl = blockIdx.x;
  int chunk = blockIdx.y;
  int b = bl / 5, l = bl % 5;
  int k = kl_of(l);
  __shared__ uint64_t z[1024];   // 8 KB
  int tid = threadIdx.x;
  for (int t = tid; t < 1024; t += 256) {
    if (t < k) {
      uint32_t u = selu[(size_t)bl * 1024 + t];
      uint32_t idx = seli[(size_t)bl * 1024 + t];
      z[t] = (((uint64_t)u) << 32) | (uint32_t)(~idx);
    } else z[t] = 0ull;
  }
  __syncthreads();
  int tg = chunk * 256 + tid;
  if (tg >= k) return;
  uint64_t zi = z[tg];
  uint32_t u = (uint32_t)(zi >> 32);
  uint32_t idx = ~(uint32_t)zi;
  int rank = 0;
  const uint4* z4 = (const uint4*)z;
  for (int j4 = 0; j4 < 512; j4++) {
    uint4 q = z4[j4];
    uint64_t za = (((uint64_t)q.y) << 32) | q.x;
    uint64_t zb = (((uint64_t)q.w) << 32) | q.z;
    rank += (za > zi) ? 1 : 0;
    rank += (zb > zi) ? 1 : 0;
  }
  constexpr int Wc[5]  = {40, 20, 10, 5, 3};
  constexpr int HWc[5] = {1600, 400, 100, 25, 9};
  constexpr float Sc[5] = {8.f, 16.f, 32.f, 64.f, 128.f};
  constexpr int COFF[5] = {0, 1000, 2000, 3000, 4000};
  int w = Wc[l], hw = HWc[l];
  float ms = s2f(u);
  int valid = (ms > 0.025f) ? 1 : 0;
  int p = (int)idx / NC, c = (int)idx % NC;
  int x = p % w, y = p / w;
  float sf = sigmoid32(in.ctr[l][(size_t)b * hw + p]);
  float score = valid ? __fmul_rn(ms, sf) : -1.0f;
  float px = __fmul_rn(__fadd_rn((float)x, 0.5f), Sc[l]);
  float py = __fmul_rn(__fadd_rn((float)y, 0.5f), Sc[l]);
  size_t bb = (size_t)b * 4 * hw;
  float d0 = in.bbox[l][bb + 0 * hw + p];
  float d1 = in.bbox[l][bb + 1 * hw + p];
  float d2 = in.bbox[l][bb + 2 * hw + p];
  float d3 = in.bbox[l][bb + 3 * hw + p];
  float x1 = clip32(__fsub_rn(px, d0)), y1 = clip32(__fsub_rn(py, d1));
  float x2 = clip32(__fadd_rn(px, d2)), y2 = clip32(__fadd_rn(py, d3));
  int o = b * KTOT + COFF[l] + rank;
  ccs[o] = score;
  ccl[o] = (uint32_t)c;
  ccv[o] = (uint32_t)valid;
  ccb[(size_t)o * 4 + 0] = x1; ccb[(size_t)o * 4 + 1] = y1;
  ccb[(size_t)o * 4 + 2] = x2; ccb[(size_t)o * 4 + 3] = y2;
}

// ---------------- per-image stable descending sort (rank method) ----------------
__global__ void k_sortimg(const float* __restrict__ ccs, const uint32_t* __restrict__ ccl,
                          const uint32_t* __restrict__ ccv, const float* __restrict__ ccb,
                          float* __restrict__ ss, uint32_t* __restrict__ sl,
                          uint32_t* __restrict__ sv, float* __restrict__ sb,
                          uint32_t* __restrict__ maxcb) {
  int b = blockIdx.y;
  __shared__ uint32_t key[KTOT];   // 18.9 KB
  __shared__ float red[4];
  int tid = threadIdx.x;
  for (int t = tid; t < KTOT; t += 256) key[t] = f2s(ccs[(size_t)b * KTOT + t]);
  __syncthreads();
  int e = blockIdx.x * 256 + tid;
  float mx = 0.0f;
  if (e < KTOT) {
    uint32_t ke = key[e];
    int rank = 0;
    const uint4* k4 = (const uint4*)key;
    for (int j4 = 0; j4 < KTOT / 4; j4++) {
      uint4 kk = k4[j4];
      int j = j4 * 4;
      rank += ((kk.x > ke) || (kk.x == ke && (j + 0) < e)) ? 1 : 0;
      rank += ((kk.y > ke) || (kk.y == ke && (j + 1) < e)) ? 1 : 0;
      rank += ((kk.z > ke) || (kk.z == ke && (j + 2) < e)) ? 1 : 0;
      rank += ((kk.w > ke) || (kk.w == ke && (j + 3) < e)) ? 1 : 0;
    }
    int sidx = b * KTOT + e;
    int d = b * KTOT + rank;
    ss[d] = ccs[sidx];
    sl[d] = ccl[sidx];
    sv[d] = ccv[sidx];
    float b0 = ccb[(size_t)sidx * 4 + 0], b1 = ccb[(size_t)sidx * 4 + 1];
    float b2 = ccb[(size_t)sidx * 4 + 2], b3 = ccb[(size_t)sidx * 4 + 3];
    sb[(size_t)d * 4 + 0] = b0; sb[(size_t)d * 4 + 1] = b1;
    sb[(size_t)d * 4 + 2] = b2; sb[(size_t)d * 4 + 3] = b3;
    mx = fmaxf(fmaxf(b0, b1), fmaxf(b2, b3));
  }
  for (int o = 32; o; o >>= 1) mx = fmaxf(mx, __shfl_xor(mx, o));
  if ((tid & 63) == 0) red[tid >> 6] = mx;
  __syncthreads();
  if (tid == 0)
    atomicMax(&maxcb[b], __float_as_uint(fmaxf(fmaxf(red[0], red[1]), fmaxf(red[2], red[3]))));
}

// ---------------- valid bits -> bitmask words ----------------
__global__ void k_bits(const uint32_t* __restrict__ sv, unsigned long long* __restrict__ vbits) {
  int w = blockIdx.x, b = blockIdx.y, lane = threadIdx.x;
  int e = w * 64 + lane;
  int pred = (e < KTOT) ? (sv[(size_t)b * KTOT + e] != 0u) : 0;
  unsigned long long m = __ballot(pred);
  if (lane == 0) vbits[b * NWIN + w] = m;
}

// ---------------- per-class offset boxes (f32); also zeroes paircnt -------------
__global__ void k_offset(const float* __restrict__ sb, const uint32_t* __restrict__ sl,
                         const uint32_t* __restrict__ maxcb, float* __restrict__ ob,
                         uint32_t* __restrict__ paircnt) {
  if (blockIdx.x == 0 && threadIdx.x < BN) paircnt[threadIdx.x] = 0u;
  int r = blockIdx.x * blockDim.x + threadIdx.x;
  if (r >= BN * KTOT) return;
  int b = r / KTOT;
  float scale = __fadd_rn(__uint_as_float(maxcb[b]), 1.0f);
  float offv = __fmul_rn((float)sl[r], scale);
  float x1 = __fadd_rn(sb[(size_t)r * 4 + 0], offv);
  float y1 = __fadd_rn(sb[(size_t)r * 4 + 1], offv);
  float x2 = __fadd_rn(sb[(size_t)r * 4 + 2], offv);
  float y2 = __fadd_rn(sb[(size_t)r * 4 + 3], offv);
  ob[(size_t)r * 4 + 0] = x1; ob[(size_t)r * 4 + 1] = y1;
  ob[(size_t)r * 4 + 2] = x2; ob[(size_t)r * 4 + 3] = y2;
}

// ---------------- IoU bitmask, 2D-tiled (256x256) + pair emission ---------------
__global__ void k_mask(const float* __restrict__ ob, unsigned long long* __restrict__ mask,
                       unsigned long long* __restrict__ tdiag,
                       uint32_t* __restrict__ pairs, uint32_t* __restrict__ paircnt) {
  int b = blockIdx.z;
  int jt = blockIdx.y;
  int ib = blockIdx.x;
  int jbase = jt * 256;
  int cnt = min(256, KTOT - jbase);
  bool diagBlock = (jt == ib);
  if (!diagBlock && (jbase + cnt - 1 <= ib * 256)) return;   // jt < ib
  __shared__ float4 tb[256];   // 4 KB
  int tid = threadIdx.x;
  if (tid < cnt)
    tb[tid] = ((const float4*)ob)[(size_t)b * KTOT + jbase + tid];
  __syncthreads();
  int i = ib * 256 + tid;
  bool act = (i < KTOT);
  float bx1 = 0, by1 = 0, bx2 = 0, by2 = 0, bai = 0;
  if (act) {
    float4 v = ((const float4*)ob)[(size_t)b * KTOT + i];
    bx1 = v.x; by1 = v.y; bx2 = v.z; by2 = v.w;
    bai = __fmul_rn(__fsub_rn(bx2, bx1), __fsub_rn(by2, by1));
  }
  int myw = i >> 6;
  unsigned long long dw = 0ull;
  if (act) {
    unsigned long long* mrow = mask + ((size_t)b * (KTOT + 64) + i) * NWORDS;
    int nw = (cnt + 63) >> 6;
    for (int w = 0; w < nw; w++) {
      int gw = jt * 4 + w;
      if (gw < myw) continue;
      unsigned long long bits = 0ull;
      int j0 = w * 64;
      int jn = min(64, cnt - j0);
      if (gw == myw) {
        for (int jj = 0; jj < jn; jj++) {
          if (jbase + j0 + jj > i)
            bits |= ((unsigned long long)iou_gt(bx1, by1, bx2, by2, bai, tb[j0 + jj])) << jj;
        }
        dw = bits;
      } else {
        for (int jj = 0; jj < jn; jj++)
          bits |= ((unsigned long long)iou_gt(bx1, by1, bx2, by2, bai, tb[j0 + jj])) << jj;
        mrow[gw] = bits;
        if (bits) {   // emit sparse pairs (i<<13)|j; jword>iword by construction
          uint32_t pos = atomicAdd(&paircnt[b], (uint32_t)__popcll(bits));
          unsigned long long t = bits;
          while (t) {
            int jj = __ffsll((long long)t) - 1; t &= t - 1;
            if (pos < PAIR_CAP)
              pairs[(size_t)b * PAIR_CAP + pos] = ((uint32_t)i << 13) | (uint32_t)(jbase + j0 + jj);
            pos++;
          }
        }
      }
    }
  }
  if (diagBlock && myw < NWIN) {
    tdiag[((size_t)b * NWIN + (size_t)myw) * 64 + (tid & 63)] = dw;   // row store
  }
}

// ---------------- bucketed sparse-pair blocked greedy NMS, 256 thr/image --------
__global__ void k_nms(const unsigned long long* __restrict__ mask,
                      const unsigned long long* __restrict__ tdiag,
                      const unsigned long long* __restrict__ vbits,
                      unsigned long long* __restrict__ keepw,
                      const uint32_t* __restrict__ pairs,
                      const uint32_t* __restrict__ paircnt) {
  int b = blockIdx.x;
  int tid = threadIdx.x;
  int lane = tid & 63;
  int wv = tid >> 6;
  const unsigned long long* mb = mask + (size_t)b * (KTOT + 64) * NWORDS;
  __shared__ unsigned long long tdl[NWIN * 64];   // rows; 37888 B
  __shared__ unsigned long long svl[NWIN];
  __shared__ unsigned long long sup[NWIN];
  __shared__ unsigned long long kwsh;
  __shared__ uint32_t plp[LDSP];                  // window-sorted pairs; 49152 B
  __shared__ uint32_t wstart[NWIN + 1];
  __shared__ uint32_t wtmp[NWIN];
  {
    const uint4* src = (const uint4*)(tdiag + (size_t)b * NWIN * 64);
    uint4* dst = (uint4*)tdl;
#pragma unroll
    for (int s = 0; s < 10; s++) {
      int c = tid + 256 * s;
      if (c < WCH) dst[c] = src[c];
    }
  }
  if (tid < NWIN) { svl[tid] = vbits[b * NWIN + tid]; sup[tid] = 0ull; wtmp[tid] = 0u; }
  uint32_t npairs = paircnt[b];
  bool useP = (npairs <= (uint32_t)PAIR_CAP);
  bool useL = (npairs <= (uint32_t)LDSP);
  const uint32_t* gpl = pairs + (size_t)b * PAIR_CAP;
  __syncthreads();
  if (useL) {
    for (uint32_t t = tid; t < npairs; t += 256) atomicAdd(&wtmp[gpl[t] >> 19], 1u);
    __syncthreads();
    if (tid == 0) {
      uint32_t acc = 0;
      for (int w = 0; w < NWIN; w++) { wstart[w] = acc; acc += wtmp[w]; }
      wstart[NWIN] = acc;
    }
    __syncthreads();
    if (tid < NWIN) wtmp[tid] = 0u;
    __syncthreads();
    for (uint32_t t = tid; t < npairs; t += 256) {
      uint32_t p = gpl[t];
      uint32_t w = p >> 19;
      uint32_t pos = wstart[w] + atomicAdd(&wtmp[w], 1u);
      plp[pos] = p;
    }
  }
  __syncthreads();
  unsigned int* sup32 = (unsigned int*)sup;
  if (useP) {
    for (int w = 0; w < NWIN; w++) {
      if (wv == 0) {
        unsigned long long row = tdl[w * 64 + lane];
        unsigned long long m = __ballot(row != 0ull);
        unsigned long long sa = sup[w];
        unsigned long long sval = svl[w];
        unsigned int rlo = (unsigned int)row, rhi = (unsigned int)(row >> 32);
        while (m) {
          int i = __ffsll((long long)m) - 1;
          m &= m - 1;
          if (((sval >> i) & 1ull) && !((sa >> i) & 1ull)) {
            unsigned int lo = (unsigned int)__builtin_amdgcn_readlane((int)rlo, i);
            unsigned int hi = (unsigned int)__builtin_amdgcn_readlane((int)rhi, i);
            sa |= (((unsigned long long)hi) << 32) | (unsigned long long)lo;
          }
        }
        unsigned long long kw = sval & ~sa;
        if (lane == 0) { keepw[b * NWIN + w] = kw; kwsh = kw; }
      }
      __syncthreads();
      unsigned long long kw = kwsh;
      if (useL) {
        for (uint32_t t = wstart[w] + tid; t < wstart[w + 1]; t += 256) {
          uint32_t p = plp[t];
          int i = (int)(p >> 13);
          if (!((kw >> (i & 63)) & 1ull)) continue;
          int j = (int)(p & 8191u);
          atomicOr(&sup32[j >> 5], 1u << (j & 31));
        }
      } else {
        for (uint32_t t = tid; t < npairs; t += 256) {
          uint32_t p = gpl[t];
          int i = (int)(p >> 13);
          if ((i >> 6) != w) continue;
          if (!((kw >> (i & 63)) & 1ull)) continue;
          int j = (int)(p & 8191u);
          atomicOr(&sup32[j >> 5], 1u << (j & 31));
        }
      }
      __syncthreads();
    }
  } else {
    // -------- dense fallback (mask words), row-based scan --------
    for (int w = 0; w < NWIN; w++) {
      uint4 q[10];
      const uint4* src4 = (const uint4*)(mb + (size_t)w * 64 * NWORDS);
#pragma unroll
      for (int s = 0; s < 10; s++) {
        int c = tid + 256 * s;
        if (c < WCH && (2 * (c % 37) + 1 > w)) q[s] = src4[c];
      }
      if (wv == 0) {
        unsigned long long row = tdl[w * 64 + lane];
        unsigned long long m = __ballot(row != 0ull);
        unsigned long long sa = sup[w];
        unsigned long long sval = svl[w];
        unsigned int rlo = (unsigned int)row, rhi = (unsigned int)(row >> 32);
        while (m) {
          int i = __ffsll((long long)m) - 1;
          m &= m - 1;
          if (((sval >> i) & 1ull) && !((sa >> i) & 1ull)) {
            unsigned int lo = (unsigned int)__builtin_amdgcn_readlane((int)rlo, i);
            unsigned int hi = (unsigned int)__builtin_amdgcn_readlane((int)rhi, i);
            sa |= (((unsigned long long)hi) << 32) | (unsigned long long)lo;
          }
        }
        unsigned long long kw = sval & ~sa;
        if (lane == 0) { keepw[b * NWIN + w] = kw; kwsh = kw; }
      }
      __syncthreads();
      unsigned long long kw = kwsh;
#pragma unroll
      for (int s = 0; s < 10; s++) {
        int c = tid + 256 * s;
        if (c >= WCH) continue;
        int wp = c % 37;
        if (2 * wp + 1 <= w) continue;
        int r = c / 37;
        if (!((kw >> r) & 1ull)) continue;
        int wlo = 2 * wp, whi = 2 * wp + 1;
        if (wlo > w) {
          if (q[s].x) atomicOr(&sup32[2 * wlo + 0], q[s].x);
          if (q[s].y) atomicOr(&sup32[2 * wlo + 1], q[s].y);
        }
        if (whi > w) {
          if (q[s].z) atomicOr(&sup32[2 * whi + 0], q[s].z);
          if (q[s].w) atomicOr(&sup32[2 * whi + 1], q[s].w);
        }
      }
      __syncthreads();
    }
  }
}

// ---------------- final outputs ----------------
__global__ void k_out(const float* __restrict__ ss, const uint32_t* __restrict__ sl,
                      const float* __restrict__ sb, const unsigned long long* __restrict__ keepw,
                      float* __restrict__ out) {
  int r = blockIdx.x * blockDim.x + threadIdx.x;
  if (r >= BN * KTOT) return;
  int b = r / KTOT;
  int e = r - b * KTOT;
  unsigned int kp = (unsigned int)((keepw[b * NWIN + (e >> 6)] >> (e & 63)) & 1ull);
  out[(size_t)r * 5 + 0] = sb[(size_t)r * 4 + 0];
  out[(size_t)r * 5 + 1] = sb[(size_t)r * 4 + 1];
  out[(size_t)r * 5 + 2] = sb[(size_t)r * 4 + 2];
  out[(size_t)r * 5 + 3] = sb[(size_t)r * 4 + 3];
  out[(size_t)r * 5 + 4] = ss[r];
  out[(size_t)BN * KTOT * 5 + r] = (float)sl[r];
  out[(size_t)BN * KTOT * 6 + r] = kp ? 1.0f : 0.0f;
}

extern "C" void kernel_launch(void* const* d_in, const int* in_sizes, int n_in,
                              void* d_out, int out_size, void* d_ws, size_t ws_size,
                              hipStream_t stream) {
  InPtrs ip;
  for (int l = 0; l < 5; l++) {
    ip.cls[l]  = (const float*)d_in[3 * l + 0];
    ip.bbox[l] = (const float*)d_in[3 * l + 1];
    ip.ctr[l]  = (const float*)d_in[3 * l + 2];
  }

  size_t off = 0;
  auto alloc = [&](size_t n) {
    char* p = (char*)d_ws + off;
    off = (off + n + 255) & ~(size_t)255;
    return p;
  };
  // region0: su + hists + small counters (phase A) overlaid with padded mask
  // (phase B). Counters are consumed before k_mask writes the mask over them.
  const size_t SU_BYTES   = (size_t)BN * TOT * 4;                  // 2.73 MB
  const size_t HIST_BYTES = (20ull * 1024 + 20ull * 1024 + 20ull * 4096) * 4; // 480 KB
  const size_t EXTRA      = 256;                                   // selcnt/tiecnt/maxcb
  const size_t MASK_BYTES = (size_t)BN * (KTOT + 64) * NWORDS * 8; // 11.3 MB
  size_t region0 = ((SU_BYTES + 255) & ~(size_t)255) + HIST_BYTES + EXTRA;
  if (MASK_BYTES > region0) region0 = MASK_BYTES;
  char* r0p = (char*)alloc(region0);
  uint32_t* su    = (uint32_t*)r0p;
  uint32_t* hist0 = (uint32_t*)(r0p + ((SU_BYTES + 255) & ~(size_t)255));
  uint32_t* hist1 = hist0 + 20ull * 1024;
  uint32_t* hist2 = hist1 + 20ull * 1024;
  uint32_t* selcnt = hist2 + 20ull * 4096;
  uint32_t* tiecnt = selcnt + 20;
  uint32_t* maxcb  = tiecnt + 20;
  unsigned long long* mask = (unsigned long long*)r0p;

  uint32_t* mpfx   = (uint32_t*)alloc(20 * 4);
  uint32_t* mk     = (uint32_t*)alloc(20 * 4);
  uint32_t* selu   = (uint32_t*)alloc(20ull * 1024 * 4);
  uint32_t* seli   = (uint32_t*)alloc(20ull * 1024 * 4);
  uint32_t* tiei   = (uint32_t*)alloc(20ull * TIE_CAP * 4);
  float*    ccs    = (float*)   alloc((size_t)BN * KTOT * 4);
  uint32_t* ccl    = (uint32_t*)alloc((size_t)BN * KTOT * 4);
  uint32_t* ccv    = (uint32_t*)alloc((size_t)BN * KTOT * 4);
  float*    ccb    = (float*)   alloc((size_t)BN * KTOT * 16);
  float*    ss     = (float*)   alloc((size_t)BN * KTOT * 4);
  uint32_t* sl     = (uint32_t*)alloc((size_t)BN * KTOT * 4);
  uint32_t* sv     = (uint32_t*)alloc((size_t)BN * KTOT * 4);
  float*    sb     = (float*)   alloc((size_t)BN * KTOT * 16);
  float*    ob     = (float*)   alloc((size_t)BN * KTOT * 16);
  unsigned long long* tdiag = (unsigned long long*)alloc((size_t)BN * NWIN * 64 * 8); // 148 KB
  unsigned long long* vbits = (unsigned long long*)alloc((size_t)BN * NWIN * 8);
  unsigned long long* keepw = (unsigned long long*)alloc((size_t)BN * NWIN * 8);
  uint32_t* pairs   = (uint32_t*)alloc((size_t)BN * PAIR_CAP * 4);  // 2 MB
  uint32_t* paircnt = (uint32_t*)alloc(BN * 4);
  (void)ws_size; (void)in_sizes; (void)n_in; (void)out_size;

  dim3 gscan((TOT + 255) / 256, BN);
  hipMemsetAsync(hist0, 0, HIST_BYTES + EXTRA, stream);   // all hists + counters
  k_score<<<dim3(36, BN), 256, 0, stream>>>(ip, su, hist0);
  k_findp<<<20, 256, 0, stream>>>(hist0, mpfx, mk, 1024, 22, 0);
  k_scan1<<<gscan, 256, 0, stream>>>(su, mpfx, hist1);
  k_findp<<<20, 256, 0, stream>>>(hist1, mpfx, mk, 1024, 12, 1);
  k_scan2<<<gscan, 256, 0, stream>>>(su, mpfx, hist2);
  k_findp<<<20, 256, 0, stream>>>(hist2, mpfx, mk, 4096, 0, 2);
  k_compact<<<gscan, 256, 0, stream>>>(su, mpfx, selcnt, tiecnt, selu, seli, tiei);
  k_ties<<<20, 256, 0, stream>>>(mpfx, mk, tiecnt, tiei, selu, seli);
  k_emit<<<dim3(20, 4), 256, 0, stream>>>(ip, selu, seli, ccs, ccl, ccv, ccb);
  k_sortimg<<<dim3(19, BN), 256, 0, stream>>>(ccs, ccl, ccv, ccb, ss, sl, sv, sb, maxcb);
  k_bits<<<dim3(NWIN, BN), 64, 0, stream>>>(sv, vbits);
  k_offset<<<(BN * KTOT + 255) / 256, 256, 0, stream>>>(sb, sl, maxcb, ob, paircnt);
  k_mask<<<dim3(19, 19, BN), 256, 0, stream>>>(ob, mask, tdiag, pairs, paircnt);
  k_nms<<<BN, 256, 0, stream>>>(mask, tdiag, vbits, keepw, pairs, paircnt);
  k_out<<<(BN * KTOT + 255) / 256, 256, 0, stream>>>(ss, sl, sb, keepw, (float*)d_out);
}

// Round 6
// 302.118 us; speedup vs baseline: 2.8759x; 1.3252x over previous
//
#include <hip/hip_runtime.h>
#include <stdint.h>

// FCOS bbox post-processing, B=4 images — bit-exact np/XLA-f32 replication
// (R7 semantics). R13: block-aggregated atomics. R14: k_mask 256x256 tiles.
// R15: row tdiag + bucketed NMS. R16: 3-digit radix selection with LDS hists.
// R17: k_sortimg 2D decomposition —
//  - k_rank (19x19xB): partial ranks vs 256-key j-tiles in LDS; contiguous
//    stores to rankp, no atomics. Per-thread serial scan 1180 -> 64 uint4.
//  - k_scatter (19xB): sum 19 partials (coalesced), permuted write, block
//    max-reduce -> 1 atomicMax/block. Replaces the 0.3-waves/SIMD k_sortimg.

#define BN 4
#define NC 80
#define TOT 170720       // 128000+32000+8000+2000+720
#define KTOT 4720        // 1000*4+720
#define NWORDS 74        // ceil(4720/64)
#define NWIN 74
#define NJT 19           // rank j-tiles
#define TIE_CAP 4096
#define IMGSZ 320.0f
#define WCH 2368         // uint4 chunks per 64-row window (64*74*8/16)
#define PAIR_CAP 131072  // pairs per image (global)
#define LDSP 12288       // pairs staged in LDS

struct InPtrs {
  const float* cls[5];
  const float* bbox[5];
  const float* ctr[5];
};

__device__ __forceinline__ uint32_t f2s(float f) {
  uint32_t x = __float_as_uint(f);
  return (x & 0x80000000u) ? ~x : (x | 0x80000000u);
}
__device__ __forceinline__ float s2f(uint32_t s) {
  uint32_t x = (s & 0x80000000u) ? (s & 0x7fffffffu) : ~s;
  return __uint_as_float(x);
}
// np/XLA logistic: 1/(1+exp(-x)) with per-op f32 rounding.
__device__ __forceinline__ float sigmoid32(float v) {
  float e = (float)exp(-(double)v);          // CR f32 exp(-v)
  return __fdiv_rn(1.0f, __fadd_rn(1.0f, e));
}
__device__ __forceinline__ void lvl_of(int e, int& l, int& le) {
  if (e < 128000)      { l = 0; le = e; }
  else if (e < 160000) { l = 1; le = e - 128000; }
  else if (e < 168000) { l = 2; le = e - 160000; }
  else if (e < 170000) { l = 3; le = e - 168000; }
  else                 { l = 4; le = e - 170000; }
}
__device__ __forceinline__ int kl_of(int l) {
  constexpr int KL[5] = {1000, 1000, 1000, 1000, 720};
  return KL[l];
}
__device__ __forceinline__ float clip32(float v) {
  return fminf(fmaxf(v, 0.0f), IMGSZ);
}
// tile table for k_score: 36 tiles/image of (<=64 p) x (80 c)
__device__ __forceinline__ void tile_of(int t, int& l, int& p0) {
  if (t < 25)       { l = 0; p0 = t * 64; }
  else if (t < 32)  { l = 1; p0 = (t - 25) * 64; }
  else if (t < 34)  { l = 2; p0 = (t - 32) * 64; }
  else if (t == 34) { l = 3; p0 = 0; }
  else              { l = 4; p0 = 0; }
}
// IoU > 0.5 predicate, exact np f32 op chain (identical to R7-R11).
__device__ __forceinline__ int iou_gt(float bx1, float by1, float bx2, float by2,
                                      float bai, float4 o) {
  float ta_ = __fmul_rn(__fsub_rn(o.z, o.x), __fsub_rn(o.w, o.y));
  float ltx = fmaxf(bx1, o.x), lty = fmaxf(by1, o.y);
  float rbx = fminf(bx2, o.z), rby = fminf(by2, o.w);
  float wd = fmaxf(__fsub_rn(rbx, ltx), 0.0f);
  float hg = fmaxf(__fsub_rn(rby, lty), 0.0f);
  float inter = __fmul_rn(wd, hg);
  float asum = __fadd_rn(bai, ta_);
  float uni  = __fsub_rn(asum, inter);
  float iou  = (uni > 0.0f) ? __fdiv_rn(inter, uni) : 0.0f;
  return (iou > 0.5f) ? 1 : 0;
}

// ---------------- scores -> sortable u32 keys + pass-0 LDS histogram -----------
__global__ void k_score(InPtrs in, uint32_t* __restrict__ su, uint32_t* __restrict__ hist0) {
  int b = blockIdx.y;
  int tl, p0; tile_of(blockIdx.x, tl, p0);
  constexpr int HWc[5]  = {1600, 400, 100, 25, 9};
  constexpr int LOFF[5] = {0, 128000, 160000, 168000, 170000};
  int hw = HWc[tl];
  int tw = min(64, hw - p0);
  int tid = threadIdx.x;
  __shared__ uint32_t lu[64 * 81];   // padded transpose tile (20.7 KB)
  __shared__ uint32_t lh[1024];      // pass-0 hist (4 KB)
  for (int i = tid; i < 1024; i += 256) lh[i] = 0;
  __syncthreads();
  int pf = tid & 63;
  if (pf < tw) {
    const float* cp = in.cls[tl] + (size_t)b * NC * hw + p0 + pf;
    for (int c = tid >> 6; c < NC; c += 4) {
      float v = cp[(size_t)c * hw];                 // coalesced (64-lane run)
      float s = sigmoid32(v);
      float m = (s > 0.025f) ? s : -1.0f;
      uint32_t u = f2s(m);
      lu[pf * 81 + c] = u;
      atomicAdd(&lh[u >> 22], 1u);                  // LDS atomic
    }
  }
  __syncthreads();
  int bl = b * 5 + tl;
  for (int i = tid; i < 1024; i += 256)
    if (lh[i]) atomicAdd(&hist0[(size_t)bl * 1024 + i], lh[i]);
  int n = tw * NC;
  uint32_t* dst = su + (size_t)b * TOT + LOFF[tl] + p0 * NC;
  for (int idx = tid; idx < n; idx += 256)
    dst[idx] = lu[(idx / 80) * 81 + (idx % 80)];    // contiguous store
}

// ---------------- radix pass 1: bits 21-12 of top-10 matches (LDS) -------------
__global__ void k_scan1(const uint32_t* __restrict__ su, const uint32_t* __restrict__ mpfx,
                        uint32_t* __restrict__ hist1) {
  int b = blockIdx.y;
  int tid = threadIdx.x;
  int e0 = blockIdx.x * 256;
  int e = e0 + tid;
  int l0, le0; lvl_of(e0, l0, le0);
  __shared__ uint32_t lh[2][1024];   // two slots: block may span 2 levels
  for (int i = tid; i < 2048; i += 256) lh[i >> 10][i & 1023] = 0;
  __syncthreads();
  if (e < TOT) {
    int l, le; lvl_of(e, l, le);
    uint32_t C = mpfx[b * 5 + l];
    uint32_t u = su[(size_t)b * TOT + e];
    if ((u >> 22) == (C >> 22)) atomicAdd(&lh[l - l0][(u >> 12) & 1023u], 1u);
  }
  __syncthreads();
  for (int s = 0; s < 2; s++) {
    int l = l0 + s;
    if (l >= 5) break;
    int bl = b * 5 + l;
    for (int i = tid; i < 1024; i += 256)
      if (lh[s][i]) atomicAdd(&hist1[(size_t)bl * 1024 + i], lh[s][i]);
  }
}

// ---------------- radix pass 2: low 12 bits of top-20 matches (rare) -----------
__global__ void k_scan2(const uint32_t* __restrict__ su, const uint32_t* __restrict__ mpfx,
                        uint32_t* __restrict__ hist2) {
  int b = blockIdx.y;
  int e = blockIdx.x * blockDim.x + threadIdx.x;
  if (e >= TOT) return;
  int l, le; lvl_of(e, l, le);
  int bl = b * 5 + l;
  uint32_t C = mpfx[bl];
  uint32_t u = su[(size_t)b * TOT + e];
  if ((u >> 12) == (C >> 12))
    atomicAdd(&hist2[(size_t)bl * 4096 + (u & 4095u)], 1u);
}

// ---------------- generic digit select (suffix-count crossing) -----------------
__global__ void k_findp(const uint32_t* __restrict__ hist, uint32_t* __restrict__ mpfx,
                        uint32_t* __restrict__ mk, int nbins, int shift, int pass) {
  int bl = blockIdx.x;
  uint32_t k = (pass == 0) ? (uint32_t)kl_of(bl % 5) : mk[bl];
  const uint32_t* h = hist + (size_t)bl * nbins;
  __shared__ uint32_t gsum[256];
  int tid = threadIdx.x;
  int per = nbins / 256;             // 4 or 16
  int base = tid * per;
  uint32_t s = 0;
  for (int i = 0; i < per; i++) s += h[base + i];
  gsum[tid] = s;
  __syncthreads();
  uint32_t above = 0;
  for (int t = tid + 1; t < 256; t++) above += gsum[t];
  if (above < k && above + s >= k) {
    uint32_t cum = above;
    for (int bin = base + per - 1; bin >= base; bin--) {
      uint32_t c = h[bin];
      if (cum < k && cum + c >= k) {
        uint32_t pfx = (pass == 0) ? 0u : mpfx[bl];
        mpfx[bl] = pfx | ((uint32_t)bin << shift);
        mk[bl] = k - cum;
        break;
      }
      cum += c;
    }
  }
}

// ---------------- compact selected (LDS-staged, block-aggregated atomics) -------
__global__ void k_compact(const uint32_t* __restrict__ su, const uint32_t* __restrict__ mpfx,
                          uint32_t* __restrict__ selcnt, uint32_t* __restrict__ tiecnt,
                          uint32_t* __restrict__ selu, uint32_t* __restrict__ seli,
                          uint32_t* __restrict__ tiei) {
  int b = blockIdx.y;
  int tid = threadIdx.x;
  int e0 = blockIdx.x * 256;
  int e = e0 + tid;
  int l0, le0; lvl_of(e0, l0, le0);
  __shared__ uint32_t cnt[2], tcnt[2], gbase[2], tgbase[2];
  __shared__ uint32_t su_s[2][256], si_s[2][256];   // staged selected (u, le)
  __shared__ uint32_t ti_s[2][256];                 // staged tie le
  if (tid < 2) { cnt[tid] = 0u; tcnt[tid] = 0u; }
  __syncthreads();
  if (e < TOT) {
    int l, le; lvl_of(e, l, le);
    int slot = l - l0;          // 0 or 1
    int bl = b * 5 + l;
    uint32_t u = su[(size_t)b * TOT + e];
    uint32_t C = mpfx[bl];
    if (u > C) {
      uint32_t p = atomicAdd(&cnt[slot], 1u);
      su_s[slot][p] = u;
      si_s[slot][p] = (uint32_t)le;
    } else if (u == C) {
      uint32_t p = atomicAdd(&tcnt[slot], 1u);
      ti_s[slot][p] = (uint32_t)le;
    }
  }
  __syncthreads();
  if (tid < 2) {
    int bl = b * 5 + l0 + tid;
    if (cnt[tid])  gbase[tid]  = atomicAdd(&selcnt[bl], cnt[tid]);
    if (tcnt[tid]) tgbase[tid] = atomicAdd(&tiecnt[bl], tcnt[tid]);
  }
  __syncthreads();
  for (int s = 0; s < 2; s++) {
    int bl = b * 5 + l0 + s;
    uint32_t n = cnt[s];
    for (uint32_t t = tid; t < n; t += 256) {
      uint32_t pos = gbase[s] + t;
      selu[(size_t)bl * 1024 + pos] = su_s[s][t];
      seli[(size_t)bl * 1024 + pos] = si_s[s][t];
    }
    uint32_t tn = tcnt[s];
    for (uint32_t t = tid; t < tn; t += 256) {
      uint32_t pos = tgbase[s] + t;
      if (pos < TIE_CAP) tiei[(size_t)bl * TIE_CAP + pos] = ti_s[s][t];
    }
  }
}

// Boundary ties: stable top_k -> smallest indices first.
__global__ void k_ties(const uint32_t* __restrict__ mpfx, const uint32_t* __restrict__ mk,
                       const uint32_t* __restrict__ tiecnt, const uint32_t* __restrict__ tiei,
                       uint32_t* __restrict__ selu, uint32_t* __restrict__ seli) {
  int bl = blockIdx.x;
  int l = bl % 5;
  uint32_t C = mpfx[bl];
  uint32_t T = mk[bl];
  uint32_t G = (uint32_t)kl_of(l) - T;
  uint32_t Tc = tiecnt[bl];
  if (Tc > TIE_CAP) Tc = TIE_CAP;
  __shared__ uint32_t sh[TIE_CAP];
  for (uint32_t t = threadIdx.x; t < Tc; t += blockDim.x) sh[t] = tiei[(size_t)bl * TIE_CAP + t];
  __syncthreads();
  for (uint32_t t = threadIdx.x; t < Tc; t += blockDim.x) {
    uint32_t my = sh[t];
    uint32_t rank = 0;
    for (uint32_t q = 0; q < Tc; q++) rank += (sh[q] < my) ? 1u : 0u;
    if (rank < T) {
      selu[(size_t)bl * 1024 + G + rank] = C;
      seli[(size_t)bl * 1024 + G + rank] = my;
    }
  }
}

// ---------------- exact rank within level + emit (packed u64 keys) --------------
__global__ void k_emit(InPtrs in, const uint32_t* __restrict__ selu, const uint32_t* __restrict__ seli,
                       float* __restrict__ ccs, uint32_t* __restrict__ ccl,
                       uint32_t* __restrict__ ccv, float* __restrict__ ccb) {
  int bl = blockIdx.x;
  int chunk = blockIdx.y;
  int b = bl / 5, l = bl % 5;
  int k = kl_of(l);
  __shared__ uint64_t z[1024];   // 8 KB
  int tid = threadIdx.x;
  for (int t = tid; t < 1024; t += 256) {
    if (t < k) {
      uint32_t u = selu[(size_t)bl * 1024 + t];
      uint32_t idx = seli[(size_t)bl * 1024 + t];
      z[t] = (((uint64_t)u) << 32) | (uint32_t)(~idx);
    } else z[t] = 0ull;
  }
  __syncthreads();
  int tg = chunk * 256 + tid;
  if (tg >= k) return;
  uint64_t zi = z[tg];
  uint32_t u = (uint32_t)(zi >> 32);
  uint32_t idx = ~(uint32_t)zi;
  int rank = 0;
  const uint4* z4 = (const uint4*)z;
  for (int j4 = 0; j4 < 512; j4++) {
    uint4 q = z4[j4];
    uint64_t za = (((uint64_t)q.y) << 32) | q.x;
    uint64_t zb = (((uint64_t)q.w) << 32) | q.z;
    rank += (za > zi) ? 1 : 0;
    rank += (zb > zi) ? 1 : 0;
  }
  constexpr int Wc[5]  = {40, 20, 10, 5, 3};
  constexpr int HWc[5] = {1600, 400, 100, 25, 9};
  constexpr float Sc[5] = {8.f, 16.f, 32.f, 64.f, 128.f};
  constexpr int COFF[5] = {0, 1000, 2000, 3000, 4000};
  int w = Wc[l], hw = HWc[l];
  float ms = s2f(u);
  int valid = (ms > 0.025f) ? 1 : 0;
  int p = (int)idx / NC, c = (int)idx % NC;
  int x = p % w, y = p / w;
  float sf = sigmoid32(in.ctr[l][(size_t)b * hw + p]);
  float score = valid ? __fmul_rn(ms, sf) : -1.0f;
  float px = __fmul_rn(__fadd_rn((float)x, 0.5f), Sc[l]);
  float py = __fmul_rn(__fadd_rn((float)y, 0.5f), Sc[l]);
  size_t bb = (size_t)b * 4 * hw;
  float d0 = in.bbox[l][bb + 0 * hw + p];
  float d1 = in.bbox[l][bb + 1 * hw + p];
  float d2 = in.bbox[l][bb + 2 * hw + p];
  float d3 = in.bbox[l][bb + 3 * hw + p];
  float x1 = clip32(__fsub_rn(px, d0)), y1 = clip32(__fsub_rn(py, d1));
  float x2 = clip32(__fadd_rn(px, d2)), y2 = clip32(__fadd_rn(py, d3));
  int o = b * KTOT + COFF[l] + rank;
  ccs[o] = score;
  ccl[o] = (uint32_t)c;
  ccv[o] = (uint32_t)valid;
  ccb[(size_t)o * 4 + 0] = x1; ccb[(size_t)o * 4 + 1] = y1;
  ccb[(size_t)o * 4 + 2] = x2; ccb[(size_t)o * 4 + 3] = y2;
}

// ---------------- partial ranks vs 256-key j-tiles (R17) ----------------
// rankp[b][jt][e] = #{ j in tile jt : key_j > key_e || (== && j < e) }.
// Pad key 0 is inert: all real keys >= f2s(-1.0) = 0x407FFFFF > 0.
__global__ void k_rank(const float* __restrict__ ccs, uint32_t* __restrict__ rankp) {
  int b = blockIdx.z;
  int jt = blockIdx.y;
  int ib = blockIdx.x;
  int tid = threadIdx.x;
  __shared__ uint32_t jk[256];   // 1 KB
  int j0 = jt * 256;
  int jn = min(256, KTOT - j0);
  jk[tid] = (tid < jn) ? f2s(ccs[(size_t)b * KTOT + j0 + tid]) : 0u;
  __syncthreads();
  int e = ib * 256 + tid;
  if (e >= KTOT) return;
  uint32_t ke = f2s(ccs[(size_t)b * KTOT + e]);
  int rank = 0;
  const uint4* k4 = (const uint4*)jk;
#pragma unroll 8
  for (int q = 0; q < 64; q++) {
    uint4 kk = k4[q];
    int j = j0 + q * 4;
    rank += ((kk.x > ke) || (kk.x == ke && (j + 0) < e)) ? 1 : 0;
    rank += ((kk.y > ke) || (kk.y == ke && (j + 1) < e)) ? 1 : 0;
    rank += ((kk.z > ke) || (kk.z == ke && (j + 2) < e)) ? 1 : 0;
    rank += ((kk.w > ke) || (kk.w == ke && (j + 3) < e)) ? 1 : 0;
  }
  rankp[((size_t)b * NJT + jt) * KTOT + e] = (uint32_t)rank;   // contiguous
}

// ---------------- sum partials + permuted scatter + maxcb ----------------
__global__ void k_scatter(const float* __restrict__ ccs, const uint32_t* __restrict__ ccl,
                          const uint32_t* __restrict__ ccv, const float* __restrict__ ccb,
                          const uint32_t* __restrict__ rankp,
                          float* __restrict__ ss, uint32_t* __restrict__ sl,
                          uint32_t* __restrict__ sv, float* __restrict__ sb,
                          uint32_t* __restrict__ maxcb) {
  int b = blockIdx.y;
  __shared__ float red[4];
  int tid = threadIdx.x;
  int e = blockIdx.x * 256 + tid;
  float mx = 0.0f;
  if (e < KTOT) {
    uint32_t rank = 0;
    for (int jt = 0; jt < NJT; jt++)
      rank += rankp[((size_t)b * NJT + jt) * KTOT + e];   // coalesced
    int sidx = b * KTOT + e;
    int d = b * KTOT + (int)rank;
    ss[d] = ccs[sidx];
    sl[d] = ccl[sidx];
    sv[d] = ccv[sidx];
    float b0 = ccb[(size_t)sidx * 4 + 0], b1 = ccb[(size_t)sidx * 4 + 1];
    float b2 = ccb[(size_t)sidx * 4 + 2], b3 = ccb[(size_t)sidx * 4 + 3];
    sb[(size_t)d * 4 + 0] = b0; sb[(size_t)d * 4 + 1] = b1;
    sb[(size_t)d * 4 + 2] = b2; sb[(size_t)d * 4 + 3] = b3;
    mx = fmaxf(fmaxf(b0, b1), fmaxf(b2, b3));
  }
  for (int o = 32; o; o >>= 1) mx = fmaxf(mx, __shfl_xor(mx, o));
  if ((tid & 63) == 0) red[tid >> 6] = mx;
  __syncthreads();
  if (tid == 0)
    atomicMax(&maxcb[b], __float_as_uint(fmaxf(fmaxf(red[0], red[1]), fmaxf(red[2], red[3]))));
}

// ---------------- valid bits -> bitmask words ----------------
__global__ void k_bits(const uint32_t* __restrict__ sv, unsigned long long* __restrict__ vbits) {
  int w = blockIdx.x, b = blockIdx.y, lane = threadIdx.x;
  int e = w * 64 + lane;
  int pred = (e < KTOT) ? (sv[(size_t)b * KTOT + e] != 0u) : 0;
  unsigned long long m = __ballot(pred);
  if (lane == 0) vbits[b * NWIN + w] = m;
}

// ---------------- per-class offset boxes (f32); also zeroes paircnt -------------
__global__ void k_offset(const float* __restrict__ sb, const uint32_t* __restrict__ sl,
                         const uint32_t* __restrict__ maxcb, float* __restrict__ ob,
                         uint32_t* __restrict__ paircnt) {
  if (blockIdx.x == 0 && threadIdx.x < BN) paircnt[threadIdx.x] = 0u;
  int r = blockIdx.x * blockDim.x + threadIdx.x;
  if (r >= BN * KTOT) return;
  int b = r / KTOT;
  float scale = __fadd_rn(__uint_as_float(maxcb[b]), 1.0f);
  float offv = __fmul_rn((float)sl[r], scale);
  float x1 = __fadd_rn(sb[(size_t)r * 4 + 0], offv);
  float y1 = __fadd_rn(sb[(size_t)r * 4 + 1], offv);
  float x2 = __fadd_rn(sb[(size_t)r * 4 + 2], offv);
  float y2 = __fadd_rn(sb[(size_t)r * 4 + 3], offv);
  ob[(size_t)r * 4 + 0] = x1; ob[(size_t)r * 4 + 1] = y1;
  ob[(size_t)r * 4 + 2] = x2; ob[(size_t)r * 4 + 3] = y2;
}

// ---------------- IoU bitmask, 2D-tiled (256x256) + pair emission ---------------
__global__ void k_mask(const float* __restrict__ ob, unsigned long long* __restrict__ mask,
                       unsigned long long* __restrict__ tdiag,
                       uint32_t* __restrict__ pairs, uint32_t* __restrict__ paircnt) {
  int b = blockIdx.z;
  int jt = blockIdx.y;
  int ib = blockIdx.x;
  int jbase = jt * 256;
  int cnt = min(256, KTOT - jbase);
  bool diagBlock = (jt == ib);
  if (!diagBlock && (jbase + cnt - 1 <= ib * 256)) return;   // jt < ib
  __shared__ float4 tb[256];   // 4 KB
  int tid = threadIdx.x;
  if (tid < cnt)
    tb[tid] = ((const float4*)ob)[(size_t)b * KTOT + jbase + tid];
  __syncthreads();
  int i = ib * 256 + tid;
  bool act = (i < KTOT);
  float bx1 = 0, by1 = 0, bx2 = 0, by2 = 0, bai = 0;
  if (act) {
    float4 v = ((const float4*)ob)[(size_t)b * KTOT + i];
    bx1 = v.x; by1 = v.y; bx2 = v.z; by2 = v.w;
    bai = __fmul_rn(__fsub_rn(bx2, bx1), __fsub_rn(by2, by1));
  }
  int myw = i >> 6;
  unsigned long long dw = 0ull;
  if (act) {
    unsigned long long* mrow = mask + ((size_t)b * (KTOT + 64) + i) * NWORDS;
    int nw = (cnt + 63) >> 6;
    for (int w = 0; w < nw; w++) {
      int gw = jt * 4 + w;
      if (gw < myw) continue;
      unsigned long long bits = 0ull;
      int j0 = w * 64;
      int jn = min(64, cnt - j0);
      if (gw == myw) {
        for (int jj = 0; jj < jn; jj++) {
          if (jbase + j0 + jj > i)
            bits |= ((unsigned long long)iou_gt(bx1, by1, bx2, by2, bai, tb[j0 + jj])) << jj;
        }
        dw = bits;
      } else {
        for (int jj = 0; jj < jn; jj++)
          bits |= ((unsigned long long)iou_gt(bx1, by1, bx2, by2, bai, tb[j0 + jj])) << jj;
        mrow[gw] = bits;
        if (bits) {   // emit sparse pairs (i<<13)|j; jword>iword by construction
          uint32_t pos = atomicAdd(&paircnt[b], (uint32_t)__popcll(bits));
          unsigned long long t = bits;
          while (t) {
            int jj = __ffsll((long long)t) - 1; t &= t - 1;
            if (pos < PAIR_CAP)
              pairs[(size_t)b * PAIR_CAP + pos] = ((uint32_t)i << 13) | (uint32_t)(jbase + j0 + jj);
            pos++;
          }
        }
      }
    }
  }
  if (diagBlock && myw < NWIN) {
    tdiag[((size_t)b * NWIN + (size_t)myw) * 64 + (tid & 63)] = dw;   // row store
  }
}

// ---------------- bucketed sparse-pair blocked greedy NMS, 256 thr/image --------
__global__ void k_nms(const unsigned long long* __restrict__ mask,
                      const unsigned long long* __restrict__ tdiag,
                      const unsigned long long* __restrict__ vbits,
                      unsigned long long* __restrict__ keepw,
                      const uint32_t* __restrict__ pairs,
                      const uint32_t* __restrict__ paircnt) {
  int b = blockIdx.x;
  int tid = threadIdx.x;
  int lane = tid & 63;
  int wv = tid >> 6;
  const unsigned long long* mb = mask + (size_t)b * (KTOT + 64) * NWORDS;
  __shared__ unsigned long long tdl[NWIN * 64];   // rows; 37888 B
  __shared__ unsigned long long svl[NWIN];
  __shared__ unsigned long long sup[NWIN];
  __shared__ unsigned long long kwsh;
  __shared__ uint32_t plp[LDSP];                  // window-sorted pairs; 49152 B
  __shared__ uint32_t wstart[NWIN + 1];
  __shared__ uint32_t wtmp[NWIN];
  {
    const uint4* src = (const uint4*)(tdiag + (size_t)b * NWIN * 64);
    uint4* dst = (uint4*)tdl;
#pragma unroll
    for (int s = 0; s < 10; s++) {
      int c = tid + 256 * s;
      if (c < WCH) dst[c] = src[c];
    }
  }
  if (tid < NWIN) { svl[tid] = vbits[b * NWIN + tid]; sup[tid] = 0ull; wtmp[tid] = 0u; }
  uint32_t npairs = paircnt[b];
  bool useP = (npairs <= (uint32_t)PAIR_CAP);
  bool useL = (npairs <= (uint32_t)LDSP);
  const uint32_t* gpl = pairs + (size_t)b * PAIR_CAP;
  __syncthreads();
  if (useL) {
    for (uint32_t t = tid; t < npairs; t += 256) atomicAdd(&wtmp[gpl[t] >> 19], 1u);
    __syncthreads();
    if (tid == 0) {
      uint32_t acc = 0;
      for (int w = 0; w < NWIN; w++) { wstart[w] = acc; acc += wtmp[w]; }
      wstart[NWIN] = acc;
    }
    __syncthreads();
    if (tid < NWIN) wtmp[tid] = 0u;
    __syncthreads();
    for (uint32_t t = tid; t < npairs; t += 256) {
      uint32_t p = gpl[t];
      uint32_t w = p >> 19;
      uint32_t pos = wstart[w] + atomicAdd(&wtmp[w], 1u);
      plp[pos] = p;
    }
  }
  __syncthreads();
  unsigned int* sup32 = (unsigned int*)sup;
  if (useP) {
    for (int w = 0; w < NWIN; w++) {
      if (wv == 0) {
        unsigned long long row = tdl[w * 64 + lane];
        unsigned long long m = __ballot(row != 0ull);
        unsigned long long sa = sup[w];
        unsigned long long sval = svl[w];
        unsigned int rlo = (unsigned int)row, rhi = (unsigned int)(row >> 32);
        while (m) {
          int i = __ffsll((long long)m) - 1;
          m &= m - 1;
          if (((sval >> i) & 1ull) && !((sa >> i) & 1ull)) {
            unsigned int lo = (unsigned int)__builtin_amdgcn_readlane((int)rlo, i);
            unsigned int hi = (unsigned int)__builtin_amdgcn_readlane((int)rhi, i);
            sa |= (((unsigned long long)hi) << 32) | (unsigned long long)lo;
          }
        }
        unsigned long long kw = sval & ~sa;
        if (lane == 0) { keepw[b * NWIN + w] = kw; kwsh = kw; }
      }
      __syncthreads();
      unsigned long long kw = kwsh;
      if (useL) {
        for (uint32_t t = wstart[w] + tid; t < wstart[w + 1]; t += 256) {
          uint32_t p = plp[t];
          int i = (int)(p >> 13);
          if (!((kw >> (i & 63)) & 1ull)) continue;
          int j = (int)(p & 8191u);
          atomicOr(&sup32[j >> 5], 1u << (j & 31));
        }
      } else {
        for (uint32_t t = tid; t < npairs; t += 256) {
          uint32_t p = gpl[t];
          int i = (int)(p >> 13);
          if ((i >> 6) != w) continue;
          if (!((kw >> (i & 63)) & 1ull)) continue;
          int j = (int)(p & 8191u);
          atomicOr(&sup32[j >> 5], 1u << (j & 31));
        }
      }
      __syncthreads();
    }
  } else {
    // -------- dense fallback (mask words), row-based scan --------
    for (int w = 0; w < NWIN; w++) {
      uint4 q[10];
      const uint4* src4 = (const uint4*)(mb + (size_t)w * 64 * NWORDS);
#pragma unroll
      for (int s = 0; s < 10; s++) {
        int c = tid + 256 * s;
        if (c < WCH && (2 * (c % 37) + 1 > w)) q[s] = src4[c];
      }
      if (wv == 0) {
        unsigned long long row = tdl[w * 64 + lane];
        unsigned long long m = __ballot(row != 0ull);
        unsigned long long sa = sup[w];
        unsigned long long sval = svl[w];
        unsigned int rlo = (unsigned int)row, rhi = (unsigned int)(row >> 32);
        while (m) {
          int i = __ffsll((long long)m) - 1;
          m &= m - 1;
          if (((sval >> i) & 1ull) && !((sa >> i) & 1ull)) {
            unsigned int lo = (unsigned int)__builtin_amdgcn_readlane((int)rlo, i);
            unsigned int hi = (unsigned int)__builtin_amdgcn_readlane((int)rhi, i);
            sa |= (((unsigned long long)hi) << 32) | (unsigned long long)lo;
          }
        }
        unsigned long long kw = sval & ~sa;
        if (lane == 0) { keepw[b * NWIN + w] = kw; kwsh = kw; }
      }
      __syncthreads();
      unsigned long long kw = kwsh;
#pragma unroll
      for (int s = 0; s < 10; s++) {
        int c = tid + 256 * s;
        if (c >= WCH) continue;
        int wp = c % 37;
        if (2 * wp + 1 <= w) continue;
        int r = c / 37;
        if (!((kw >> r) & 1ull)) continue;
        int wlo = 2 * wp, whi = 2 * wp + 1;
        if (wlo > w) {
          if (q[s].x) atomicOr(&sup32[2 * wlo + 0], q[s].x);
          if (q[s].y) atomicOr(&sup32[2 * wlo + 1], q[s].y);
        }
        if (whi > w) {
          if (q[s].z) atomicOr(&sup32[2 * whi + 0], q[s].z);
          if (q[s].w) atomicOr(&sup32[2 * whi + 1], q[s].w);
        }
      }
      __syncthreads();
    }
  }
}

// ---------------- final outputs ----------------
__global__ void k_out(const float* __restrict__ ss, const uint32_t* __restrict__ sl,
                      const float* __restrict__ sb, const unsigned long long* __restrict__ keepw,
                      float* __restrict__ out) {
  int r = blockIdx.x * blockDim.x + threadIdx.x;
  if (r >= BN * KTOT) return;
  int b = r / KTOT;
  int e = r - b * KTOT;
  unsigned int kp = (unsigned int)((keepw[b * NWIN + (e >> 6)] >> (e & 63)) & 1ull);
  out[(size_t)r * 5 + 0] = sb[(size_t)r * 4 + 0];
  out[(size_t)r * 5 + 1] = sb[(size_t)r * 4 + 1];
  out[(size_t)r * 5 + 2] = sb[(size_t)r * 4 + 2];
  out[(size_t)r * 5 + 3] = sb[(size_t)r * 4 + 3];
  out[(size_t)r * 5 + 4] = ss[r];
  out[(size_t)BN * KTOT * 5 + r] = (float)sl[r];
  out[(size_t)BN * KTOT * 6 + r] = kp ? 1.0f : 0.0f;
}

extern "C" void kernel_launch(void* const* d_in, const int* in_sizes, int n_in,
                              void* d_out, int out_size, void* d_ws, size_t ws_size,
                              hipStream_t stream) {
  InPtrs ip;
  for (int l = 0; l < 5; l++) {
    ip.cls[l]  = (const float*)d_in[3 * l + 0];
    ip.bbox[l] = (const float*)d_in[3 * l + 1];
    ip.ctr[l]  = (const float*)d_in[3 * l + 2];
  }

  size_t off = 0;
  auto alloc = [&](size_t n) {
    char* p = (char*)d_ws + off;
    off = (off + n + 255) & ~(size_t)255;
    return p;
  };
  // region0: su + hists + small counters (phase A) overlaid with padded mask
  // (phase B). Counters are consumed before k_mask writes the mask over them.
  const size_t SU_BYTES   = (size_t)BN * TOT * 4;                  // 2.73 MB
  const size_t HIST_BYTES = (20ull * 1024 + 20ull * 1024 + 20ull * 4096) * 4; // 480 KB
  const size_t EXTRA      = 256;                                   // selcnt/tiecnt/maxcb
  const size_t MASK_BYTES = (size_t)BN * (KTOT + 64) * NWORDS * 8; // 11.3 MB
  size_t region0 = ((SU_BYTES + 255) & ~(size_t)255) + HIST_BYTES + EXTRA;
  if (MASK_BYTES > region0) region0 = MASK_BYTES;
  char* r0p = (char*)alloc(region0);
  uint32_t* su    = (uint32_t*)r0p;
  uint32_t* hist0 = (uint32_t*)(r0p + ((SU_BYTES + 255) & ~(size_t)255));
  uint32_t* hist1 = hist0 + 20ull * 1024;
  uint32_t* hist2 = hist1 + 20ull * 1024;
  uint32_t* selcnt = hist2 + 20ull * 4096;
  uint32_t* tiecnt = selcnt + 20;
  uint32_t* maxcb  = tiecnt + 20;
  unsigned long long* mask = (unsigned long long*)r0p;

  uint32_t* mpfx   = (uint32_t*)alloc(20 * 4);
  uint32_t* mk     = (uint32_t*)alloc(20 * 4);
  uint32_t* selu   = (uint32_t*)alloc(20ull * 1024 * 4);
  uint32_t* seli   = (uint32_t*)alloc(20ull * 1024 * 4);
  uint32_t* tiei   = (uint32_t*)alloc(20ull * TIE_CAP * 4);
  float*    ccs    = (float*)   alloc((size_t)BN * KTOT * 4);
  uint32_t* ccl    = (uint32_t*)alloc((size_t)BN * KTOT * 4);
  uint32_t* ccv    = (uint32_t*)alloc((size_t)BN * KTOT * 4);
  float*    ccb    = (float*)   alloc((size_t)BN * KTOT * 16);
  float*    ss     = (float*)   alloc((size_t)BN * KTOT * 4);
  uint32_t* sl     = (uint32_t*)alloc((size_t)BN * KTOT * 4);
  uint32_t* sv     = (uint32_t*)alloc((size_t)BN * KTOT * 4);
  float*    sb     = (float*)   alloc((size_t)BN * KTOT * 16);
  float*    ob     = (float*)   alloc((size_t)BN * KTOT * 16);
  uint32_t* rankp  = (uint32_t*)alloc((size_t)BN * NJT * KTOT * 4); // 1.43 MB
  unsigned long long* tdiag = (unsigned long long*)alloc((size_t)BN * NWIN * 64 * 8); // 148 KB
  unsigned long long* vbits = (unsigned long long*)alloc((size_t)BN * NWIN * 8);
  unsigned long long* keepw = (unsigned long long*)alloc((size_t)BN * NWIN * 8);
  uint32_t* pairs   = (uint32_t*)alloc((size_t)BN * PAIR_CAP * 4);  // 2 MB
  uint32_t* paircnt = (uint32_t*)alloc(BN * 4);
  (void)ws_size; (void)in_sizes; (void)n_in; (void)out_size;

  dim3 gscan((TOT + 255) / 256, BN);
  hipMemsetAsync(hist0, 0, HIST_BYTES + EXTRA, stream);   // all hists + counters
  k_score<<<dim3(36, BN), 256, 0, stream>>>(ip, su, hist0);
  k_findp<<<20, 256, 0, stream>>>(hist0, mpfx, mk, 1024, 22, 0);
  k_scan1<<<gscan, 256, 0, stream>>>(su, mpfx, hist1);
  k_findp<<<20, 256, 0, stream>>>(hist1, mpfx, mk, 1024, 12, 1);
  k_scan2<<<gscan, 256, 0, stream>>>(su, mpfx, hist2);
  k_findp<<<20, 256, 0, stream>>>(hist2, mpfx, mk, 4096, 0, 2);
  k_compact<<<gscan, 256, 0, stream>>>(su, mpfx, selcnt, tiecnt, selu, seli, tiei);
  k_ties<<<20, 256, 0, stream>>>(mpfx, mk, tiecnt, tiei, selu, seli);
  k_emit<<<dim3(20, 4), 256, 0, stream>>>(ip, selu, seli, ccs, ccl, ccv, ccb);
  k_rank<<<dim3(19, NJT, BN), 256, 0, stream>>>(ccs, rankp);
  k_scatter<<<dim3(19, BN), 256, 0, stream>>>(ccs, ccl, ccv, ccb, rankp, ss, sl, sv, sb, maxcb);
  k_bits<<<dim3(NWIN, BN), 64, 0, stream>>>(sv, vbits);
  k_offset<<<(BN * KTOT + 255) / 256, 256, 0, stream>>>(sb, sl, maxcb, ob, paircnt);
  k_mask<<<dim3(19, 19, BN), 256, 0, stream>>>(ob, mask, tdiag, pairs, paircnt);
  k_nms<<<BN, 256, 0, stream>>>(mask, tdiag, vbits, keepw, pairs, paircnt);
  k_out<<<(BN * KTOT + 255) / 256, 256, 0, stream>>>(ss, sl, sb, keepw, (float*)d_out);
}

// Round 7
// 267.745 us; speedup vs baseline: 3.2451x; 1.1284x over previous
//
#include <hip/hip_runtime.h>
#include <stdint.h>

// FCOS bbox post-processing, B=4 images — bit-exact np/XLA-f32 replication
// (R7 semantics). R13: block-aggregated atomics. R15: bucketed NMS.
// R16: 3-digit radix selection. R17: 2D rank decomposition.
// R18: class-bucketed IoU — dense mask DELETED.
//  - Cross-class IoU is exactly 0 by construction (offset = label*(maxc+1),
//    maxc+1 > 320 >= any coord -> separation >= 1.0 >> f32 rounding at that
//    magnitude -> intersection width exactly 0). Only same-class pairs matter:
//    137k IoU/image instead of 11.7M, and no 15.7MB of scattered mask writes.
//  - k_class: order-preserving per-class member compaction (ballot/prefix).
//  - k_mask2: per-class pairwise IoU, two-phase count->emit, one global
//    atomicAdd per block. Identical pair set, exact same f32 op chain on ob.
//  - k_nms: tdl rows built from same-window pairs (LDS atomicOr); cross-window
//    pairs bucketed as before. PAIR_CAP overflow -> on-the-fly IoU recompute.

#define BN 4
#define NC 80
#define TOT 170720       // 128000+32000+8000+2000+720
#define KTOT 4720        // 1000*4+720
#define NWIN 74          // ceil(4720/64)
#define NJT 19           // rank j-tiles
#define TIE_CAP 4096
#define IMGSZ 320.0f
#define PAIR_CAP 131072  // pairs per image (global)
#define LDSP 12288       // pairs staged in LDS

struct InPtrs {
  const float* cls[5];
  const float* bbox[5];
  const float* ctr[5];
};

__device__ __forceinline__ uint32_t f2s(float f) {
  uint32_t x = __float_as_uint(f);
  return (x & 0x80000000u) ? ~x : (x | 0x80000000u);
}
__device__ __forceinline__ float s2f(uint32_t s) {
  uint32_t x = (s & 0x80000000u) ? (s & 0x7fffffffu) : ~s;
  return __uint_as_float(x);
}
// np/XLA logistic: 1/(1+exp(-x)) with per-op f32 rounding.
__device__ __forceinline__ float sigmoid32(float v) {
  float e = (float)exp(-(double)v);          // CR f32 exp(-v)
  return __fdiv_rn(1.0f, __fadd_rn(1.0f, e));
}
__device__ __forceinline__ void lvl_of(int e, int& l, int& le) {
  if (e < 128000)      { l = 0; le = e; }
  else if (e < 160000) { l = 1; le = e - 128000; }
  else if (e < 168000) { l = 2; le = e - 160000; }
  else if (e < 170000) { l = 3; le = e - 168000; }
  else                 { l = 4; le = e - 170000; }
}
__device__ __forceinline__ int kl_of(int l) {
  constexpr int KL[5] = {1000, 1000, 1000, 1000, 720};
  return KL[l];
}
__device__ __forceinline__ float clip32(float v) {
  return fminf(fmaxf(v, 0.0f), IMGSZ);
}
// tile table for k_score: 36 tiles/image of (<=64 p) x (80 c)
__device__ __forceinline__ void tile_of(int t, int& l, int& p0) {
  if (t < 25)       { l = 0; p0 = t * 64; }
  else if (t < 32)  { l = 1; p0 = (t - 25) * 64; }
  else if (t < 34)  { l = 2; p0 = (t - 32) * 64; }
  else if (t == 34) { l = 3; p0 = 0; }
  else              { l = 4; p0 = 0; }
}
// IoU > 0.5 predicate, exact np f32 op chain (identical to R7-R17).
__device__ __forceinline__ int iou_gt(float bx1, float by1, float bx2, float by2,
                                      float bai, float4 o) {
  float ta_ = __fmul_rn(__fsub_rn(o.z, o.x), __fsub_rn(o.w, o.y));
  float ltx = fmaxf(bx1, o.x), lty = fmaxf(by1, o.y);
  float rbx = fminf(bx2, o.z), rby = fminf(by2, o.w);
  float wd = fmaxf(__fsub_rn(rbx, ltx), 0.0f);
  float hg = fmaxf(__fsub_rn(rby, lty), 0.0f);
  float inter = __fmul_rn(wd, hg);
  float asum = __fadd_rn(bai, ta_);
  float uni  = __fsub_rn(asum, inter);
  float iou  = (uni > 0.0f) ? __fdiv_rn(inter, uni) : 0.0f;
  return (iou > 0.5f) ? 1 : 0;
}

// ---------------- scores -> sortable u32 keys + pass-0 LDS histogram -----------
__global__ void k_score(InPtrs in, uint32_t* __restrict__ su, uint32_t* __restrict__ hist0) {
  int b = blockIdx.y;
  int tl, p0; tile_of(blockIdx.x, tl, p0);
  constexpr int HWc[5]  = {1600, 400, 100, 25, 9};
  constexpr int LOFF[5] = {0, 128000, 160000, 168000, 170000};
  int hw = HWc[tl];
  int tw = min(64, hw - p0);
  int tid = threadIdx.x;
  __shared__ uint32_t lu[64 * 81];   // padded transpose tile (20.7 KB)
  __shared__ uint32_t lh[1024];      // pass-0 hist (4 KB)
  for (int i = tid; i < 1024; i += 256) lh[i] = 0;
  __syncthreads();
  int pf = tid & 63;
  if (pf < tw) {
    const float* cp = in.cls[tl] + (size_t)b * NC * hw + p0 + pf;
    for (int c = tid >> 6; c < NC; c += 4) {
      float v = cp[(size_t)c * hw];                 // coalesced (64-lane run)
      float s = sigmoid32(v);
      float m = (s > 0.025f) ? s : -1.0f;
      uint32_t u = f2s(m);
      lu[pf * 81 + c] = u;
      atomicAdd(&lh[u >> 22], 1u);                  // LDS atomic
    }
  }
  __syncthreads();
  int bl = b * 5 + tl;
  for (int i = tid; i < 1024; i += 256)
    if (lh[i]) atomicAdd(&hist0[(size_t)bl * 1024 + i], lh[i]);
  int n = tw * NC;
  uint32_t* dst = su + (size_t)b * TOT + LOFF[tl] + p0 * NC;
  for (int idx = tid; idx < n; idx += 256)
    dst[idx] = lu[(idx / 80) * 81 + (idx % 80)];    // contiguous store
}

// ---------------- radix pass 1: bits 21-12 of top-10 matches (LDS) -------------
__global__ void k_scan1(const uint32_t* __restrict__ su, const uint32_t* __restrict__ mpfx,
                        uint32_t* __restrict__ hist1) {
  int b = blockIdx.y;
  int tid = threadIdx.x;
  int e0 = blockIdx.x * 256;
  int e = e0 + tid;
  int l0, le0; lvl_of(e0, l0, le0);
  __shared__ uint32_t lh[2][1024];   // two slots: block may span 2 levels
  for (int i = tid; i < 2048; i += 256) lh[i >> 10][i & 1023] = 0;
  __syncthreads();
  if (e < TOT) {
    int l, le; lvl_of(e, l, le);
    uint32_t C = mpfx[b * 5 + l];
    uint32_t u = su[(size_t)b * TOT + e];
    if ((u >> 22) == (C >> 22)) atomicAdd(&lh[l - l0][(u >> 12) & 1023u], 1u);
  }
  __syncthreads();
  for (int s = 0; s < 2; s++) {
    int l = l0 + s;
    if (l >= 5) break;
    int bl = b * 5 + l;
    for (int i = tid; i < 1024; i += 256)
      if (lh[s][i]) atomicAdd(&hist1[(size_t)bl * 1024 + i], lh[s][i]);
  }
}

// ---------------- radix pass 2: low 12 bits of top-20 matches (rare) -----------
__global__ void k_scan2(const uint32_t* __restrict__ su, const uint32_t* __restrict__ mpfx,
                        uint32_t* __restrict__ hist2) {
  int b = blockIdx.y;
  int e = blockIdx.x * blockDim.x + threadIdx.x;
  if (e >= TOT) return;
  int l, le; lvl_of(e, l, le);
  int bl = b * 5 + l;
  uint32_t C = mpfx[bl];
  uint32_t u = su[(size_t)b * TOT + e];
  if ((u >> 12) == (C >> 12))
    atomicAdd(&hist2[(size_t)bl * 4096 + (u & 4095u)], 1u);
}

// ---------------- generic digit select (suffix-count crossing) -----------------
__global__ void k_findp(const uint32_t* __restrict__ hist, uint32_t* __restrict__ mpfx,
                        uint32_t* __restrict__ mk, int nbins, int shift, int pass) {
  int bl = blockIdx.x;
  uint32_t k = (pass == 0) ? (uint32_t)kl_of(bl % 5) : mk[bl];
  const uint32_t* h = hist + (size_t)bl * nbins;
  __shared__ uint32_t gsum[256];
  int tid = threadIdx.x;
  int per = nbins / 256;             // 4 or 16
  int base = tid * per;
  uint32_t s = 0;
  for (int i = 0; i < per; i++) s += h[base + i];
  gsum[tid] = s;
  __syncthreads();
  uint32_t above = 0;
  for (int t = tid + 1; t < 256; t++) above += gsum[t];
  if (above < k && above + s >= k) {
    uint32_t cum = above;
    for (int bin = base + per - 1; bin >= base; bin--) {
      uint32_t c = h[bin];
      if (cum < k && cum + c >= k) {
        uint32_t pfx = (pass == 0) ? 0u : mpfx[bl];
        mpfx[bl] = pfx | ((uint32_t)bin << shift);
        mk[bl] = k - cum;
        break;
      }
      cum += c;
    }
  }
}

// ---------------- compact selected (LDS-staged, block-aggregated atomics) -------
__global__ void k_compact(const uint32_t* __restrict__ su, const uint32_t* __restrict__ mpfx,
                          uint32_t* __restrict__ selcnt, uint32_t* __restrict__ tiecnt,
                          uint32_t* __restrict__ selu, uint32_t* __restrict__ seli,
                          uint32_t* __restrict__ tiei) {
  int b = blockIdx.y;
  int tid = threadIdx.x;
  int e0 = blockIdx.x * 256;
  int e = e0 + tid;
  int l0, le0; lvl_of(e0, l0, le0);
  __shared__ uint32_t cnt[2], tcnt[2], gbase[2], tgbase[2];
  __shared__ uint32_t su_s[2][256], si_s[2][256];   // staged selected (u, le)
  __shared__ uint32_t ti_s[2][256];                 // staged tie le
  if (tid < 2) { cnt[tid] = 0u; tcnt[tid] = 0u; }
  __syncthreads();
  if (e < TOT) {
    int l, le; lvl_of(e, l, le);
    int slot = l - l0;          // 0 or 1
    int bl = b * 5 + l;
    uint32_t u = su[(size_t)b * TOT + e];
    uint32_t C = mpfx[bl];
    if (u > C) {
      uint32_t p = atomicAdd(&cnt[slot], 1u);
      su_s[slot][p] = u;
      si_s[slot][p] = (uint32_t)le;
    } else if (u == C) {
      uint32_t p = atomicAdd(&tcnt[slot], 1u);
      ti_s[slot][p] = (uint32_t)le;
    }
  }
  __syncthreads();
  if (tid < 2) {
    int bl = b * 5 + l0 + tid;
    if (cnt[tid])  gbase[tid]  = atomicAdd(&selcnt[bl], cnt[tid]);
    if (tcnt[tid]) tgbase[tid] = atomicAdd(&tiecnt[bl], tcnt[tid]);
  }
  __syncthreads();
  for (int s = 0; s < 2; s++) {
    int bl = b * 5 + l0 + s;
    uint32_t n = cnt[s];
    for (uint32_t t = tid; t < n; t += 256) {
      uint32_t pos = gbase[s] + t;
      selu[(size_t)bl * 1024 + pos] = su_s[s][t];
      seli[(size_t)bl * 1024 + pos] = si_s[s][t];
    }
    uint32_t tn = tcnt[s];
    for (uint32_t t = tid; t < tn; t += 256) {
      uint32_t pos = tgbase[s] + t;
      if (pos < TIE_CAP) tiei[(size_t)bl * TIE_CAP + pos] = ti_s[s][t];
    }
  }
}

// Boundary ties: stable top_k -> smallest indices first.
__global__ void k_ties(const uint32_t* __restrict__ mpfx, const uint32_t* __restrict__ mk,
                       const uint32_t* __restrict__ tiecnt, const uint32_t* __restrict__ tiei,
                       uint32_t* __restrict__ selu, uint32_t* __restrict__ seli) {
  int bl = blockIdx.x;
  int l = bl % 5;
  uint32_t C = mpfx[bl];
  uint32_t T = mk[bl];
  uint32_t G = (uint32_t)kl_of(l) - T;
  uint32_t Tc = tiecnt[bl];
  if (Tc > TIE_CAP) Tc = TIE_CAP;
  __shared__ uint32_t sh[TIE_CAP];
  for (uint32_t t = threadIdx.x; t < Tc; t += blockDim.x) sh[t] = tiei[(size_t)bl * TIE_CAP + t];
  __syncthreads();
  for (uint32_t t = threadIdx.x; t < Tc; t += blockDim.x) {
    uint32_t my = sh[t];
    uint32_t rank = 0;
    for (uint32_t q = 0; q < Tc; q++) rank += (sh[q] < my) ? 1u : 0u;
    if (rank < T) {
      selu[(size_t)bl * 1024 + G + rank] = C;
      seli[(size_t)bl * 1024 + G + rank] = my;
    }
  }
}

// ---------------- exact rank within level + emit (packed u64 keys) --------------
__global__ void k_emit(InPtrs in, const uint32_t* __restrict__ selu, const uint32_t* __restrict__ seli,
                       float* __restrict__ ccs, uint32_t* __restrict__ ccl,
                       uint32_t* __restrict__ ccv, float* __restrict__ ccb) {
  int bl = blockIdx.x;
  int chunk = blockIdx.y;
  int b = bl / 5, l = bl % 5;
  int k = kl_of(l);
  __shared__ uint64_t z[1024];   // 8 KB
  int tid = threadIdx.x;
  for (int t = tid; t < 1024; t += 256) {
    if (t < k) {
      uint32_t u = selu[(size_t)bl * 1024 + t];
      uint32_t idx = seli[(size_t)bl * 1024 + t];
      z[t] = (((uint64_t)u) << 32) | (uint32_t)(~idx);
    } else z[t] = 0ull;
  }
  __syncthreads();
  int tg = chunk * 256 + tid;
  if (tg >= k) return;
  uint64_t zi = z[tg];
  uint32_t u = (uint32_t)(zi >> 32);
  uint32_t idx = ~(uint32_t)zi;
  int rank = 0;
  const uint4* z4 = (const uint4*)z;
  for (int j4 = 0; j4 < 512; j4++) {
    uint4 q = z4[j4];
    uint64_t za = (((uint64_t)q.y) << 32) | q.x;
    uint64_t zb = (((uint64_t)q.w) << 32) | q.z;
    rank += (za > zi) ? 1 : 0;
    rank += (zb > zi) ? 1 : 0;
  }
  constexpr int Wc[5]  = {40, 20, 10, 5, 3};
  constexpr int HWc[5] = {1600, 400, 100, 25, 9};
  constexpr float Sc[5] = {8.f, 16.f, 32.f, 64.f, 128.f};
  constexpr int COFF[5] = {0, 1000, 2000, 3000, 4000};
  int w = Wc[l], hw = HWc[l];
  float ms = s2f(u);
  int valid = (ms > 0.025f) ? 1 : 0;
  int p = (int)idx / NC, c = (int)idx % NC;
  int x = p % w, y = p / w;
  float sf = sigmoid32(in.ctr[l][(size_t)b * hw + p]);
  float score = valid ? __fmul_rn(ms, sf) : -1.0f;
  float px = __fmul_rn(__fadd_rn((float)x, 0.5f), Sc[l]);
  float py = __fmul_rn(__fadd_rn((float)y, 0.5f), Sc[l]);
  size_t bb = (size_t)b * 4 * hw;
  float d0 = in.bbox[l][bb + 0 * hw + p];
  float d1 = in.bbox[l][bb + 1 * hw + p];
  float d2 = in.bbox[l][bb + 2 * hw + p];
  float d3 = in.bbox[l][bb + 3 * hw + p];
  float x1 = clip32(__fsub_rn(px, d0)), y1 = clip32(__fsub_rn(py, d1));
  float x2 = clip32(__fadd_rn(px, d2)), y2 = clip32(__fadd_rn(py, d3));
  int o = b * KTOT + COFF[l] + rank;
  ccs[o] = score;
  ccl[o] = (uint32_t)c;
  ccv[o] = (uint32_t)valid;
  ccb[(size_t)o * 4 + 0] = x1; ccb[(size_t)o * 4 + 1] = y1;
  ccb[(size_t)o * 4 + 2] = x2; ccb[(size_t)o * 4 + 3] = y2;
}

// ---------------- partial ranks vs 256-key j-tiles ----------------
__global__ void k_rank(const float* __restrict__ ccs, uint32_t* __restrict__ rankp) {
  int b = blockIdx.z;
  int jt = blockIdx.y;
  int ib = blockIdx.x;
  int tid = threadIdx.x;
  __shared__ uint32_t jk[256];   // 1 KB
  int j0 = jt * 256;
  int jn = min(256, KTOT - j0);
  jk[tid] = (tid < jn) ? f2s(ccs[(size_t)b * KTOT + j0 + tid]) : 0u;
  __syncthreads();
  int e = ib * 256 + tid;
  if (e >= KTOT) return;
  uint32_t ke = f2s(ccs[(size_t)b * KTOT + e]);
  int rank = 0;
  const uint4* k4 = (const uint4*)jk;
#pragma unroll 8
  for (int q = 0; q < 64; q++) {
    uint4 kk = k4[q];
    int j = j0 + q * 4;
    rank += ((kk.x > ke) || (kk.x == ke && (j + 0) < e)) ? 1 : 0;
    rank += ((kk.y > ke) || (kk.y == ke && (j + 1) < e)) ? 1 : 0;
    rank += ((kk.z > ke) || (kk.z == ke && (j + 2) < e)) ? 1 : 0;
    rank += ((kk.w > ke) || (kk.w == ke && (j + 3) < e)) ? 1 : 0;
  }
  rankp[((size_t)b * NJT + jt) * KTOT + e] = (uint32_t)rank;   // contiguous
}

// ---------------- sum partials + permuted scatter + maxcb ----------------
__global__ void k_scatter(const float* __restrict__ ccs, const uint32_t* __restrict__ ccl,
                          const uint32_t* __restrict__ ccv, const float* __restrict__ ccb,
                          const uint32_t* __restrict__ rankp,
                          float* __restrict__ ss, uint32_t* __restrict__ sl,
                          uint32_t* __restrict__ sv, float* __restrict__ sb,
                          uint32_t* __restrict__ maxcb) {
  int b = blockIdx.y;
  __shared__ float red[4];
  int tid = threadIdx.x;
  int e = blockIdx.x * 256 + tid;
  float mx = 0.0f;
  if (e < KTOT) {
    uint32_t rank = 0;
    for (int jt = 0; jt < NJT; jt++)
      rank += rankp[((size_t)b * NJT + jt) * KTOT + e];   // coalesced
    int sidx = b * KTOT + e;
    int d = b * KTOT + (int)rank;
    ss[d] = ccs[sidx];
    sl[d] = ccl[sidx];
    sv[d] = ccv[sidx];
    float b0 = ccb[(size_t)sidx * 4 + 0], b1 = ccb[(size_t)sidx * 4 + 1];
    float b2 = ccb[(size_t)sidx * 4 + 2], b3 = ccb[(size_t)sidx * 4 + 3];
    sb[(size_t)d * 4 + 0] = b0; sb[(size_t)d * 4 + 1] = b1;
    sb[(size_t)d * 4 + 2] = b2; sb[(size_t)d * 4 + 3] = b3;
    mx = fmaxf(fmaxf(b0, b1), fmaxf(b2, b3));
  }
  for (int o = 32; o; o >>= 1) mx = fmaxf(mx, __shfl_xor(mx, o));
  if ((tid & 63) == 0) red[tid >> 6] = mx;
  __syncthreads();
  if (tid == 0)
    atomicMax(&maxcb[b], __float_as_uint(fmaxf(fmaxf(red[0], red[1]), fmaxf(red[2], red[3]))));
}

// ---------------- valid bits -> bitmask words ----------------
__global__ void k_bits(const uint32_t* __restrict__ sv, unsigned long long* __restrict__ vbits) {
  int w = blockIdx.x, b = blockIdx.y, lane = threadIdx.x;
  int e = w * 64 + lane;
  int pred = (e < KTOT) ? (sv[(size_t)b * KTOT + e] != 0u) : 0;
  unsigned long long m = __ballot(pred);
  if (lane == 0) vbits[b * NWIN + w] = m;
}

// ---------------- per-class offset boxes (f32); also zeroes paircnt -------------
__global__ void k_offset(const float* __restrict__ sb, const uint32_t* __restrict__ sl,
                         const uint32_t* __restrict__ maxcb, float* __restrict__ ob,
                         uint32_t* __restrict__ paircnt) {
  if (blockIdx.x == 0 && threadIdx.x < BN) paircnt[threadIdx.x] = 0u;
  int r = blockIdx.x * blockDim.x + threadIdx.x;
  if (r >= BN * KTOT) return;
  int b = r / KTOT;
  float scale = __fadd_rn(__uint_as_float(maxcb[b]), 1.0f);
  float offv = __fmul_rn((float)sl[r], scale);
  float x1 = __fadd_rn(sb[(size_t)r * 4 + 0], offv);
  float y1 = __fadd_rn(sb[(size_t)r * 4 + 1], offv);
  float x2 = __fadd_rn(sb[(size_t)r * 4 + 2], offv);
  float y2 = __fadd_rn(sb[(size_t)r * 4 + 3], offv);
  ob[(size_t)r * 4 + 0] = x1; ob[(size_t)r * 4 + 1] = y1;
  ob[(size_t)r * 4 + 2] = x2; ob[(size_t)r * 4 + 3] = y2;
}

// ---------------- order-preserving per-class member lists (R18) ----------------
__global__ void k_class(const uint32_t* __restrict__ sl, uint32_t* __restrict__ clist,
                        uint32_t* __restrict__ ccount) {
  int b = blockIdx.y;
  int c = blockIdx.x;
  int tid = threadIdx.x;
  int lane = tid & 63, wv = tid >> 6;
  __shared__ uint32_t woff[4];
  uint32_t* out = clist + ((size_t)b * NC + c) * KTOT;
  uint32_t base = 0;
  for (int chunk = 0; chunk < KTOT; chunk += 256) {
    int e = chunk + tid;
    int pred = (e < KTOT) && (sl[(size_t)b * KTOT + e] == (uint32_t)c);
    unsigned long long bal = __ballot(pred);
    if (lane == 0) woff[wv] = (uint32_t)__popcll(bal);
    __syncthreads();
    uint32_t myoff = base;
    for (int v = 0; v < wv; v++) myoff += woff[v];
    uint32_t tot = woff[0] + woff[1] + woff[2] + woff[3];
    if (pred) {
      uint32_t pos = myoff + (uint32_t)__popcll(bal & ((1ull << lane) - 1ull));
      out[pos] = (uint32_t)e;
    }
    base += tot;
    __syncthreads();
  }
  if (tid == 0) ccount[b * NC + c] = base;
}

// ---------------- per-class pairwise IoU -> suppression pairs (R18) ------------
// Two-phase (count -> prefix -> emit); one global atomicAdd per block.
__global__ void k_mask2(const float* __restrict__ ob, const uint32_t* __restrict__ clist,
                        const uint32_t* __restrict__ ccount,
                        uint32_t* __restrict__ pairs, uint32_t* __restrict__ paircnt) {
  int b = blockIdx.y;
  int c = blockIdx.x;
  int m = (int)ccount[b * NC + c];
  if (m < 2) return;
  const uint32_t* cl = clist + ((size_t)b * NC + c) * KTOT;
  const float4* ob4 = (const float4*)ob + (size_t)b * KTOT;
  int tid = threadIdx.x;
  __shared__ float4 tb[256];     // 4 KB
  __shared__ uint32_t jidx[256];
  __shared__ uint32_t pcnt[256];
  __shared__ uint32_t sbase;
  // phase 1: count
  uint32_t mycnt = 0;
  for (int jt = 0; jt < m; jt += 256) {
    int jn = min(256, m - jt);
    __syncthreads();
    if (tid < jn) { uint32_t gj = cl[jt + tid]; jidx[tid] = gj; tb[tid] = ob4[gj]; }
    __syncthreads();
    for (int i = tid; i < m; i += 256) {
      uint32_t gi = cl[i];
      float4 v = ob4[gi];
      float bai = __fmul_rn(__fsub_rn(v.z, v.x), __fsub_rn(v.w, v.y));
      for (int jj = 0; jj < jn; jj++)
        if (jidx[jj] > gi && iou_gt(v.x, v.y, v.z, v.w, bai, tb[jj])) mycnt++;
    }
  }
  __syncthreads();
  pcnt[tid] = mycnt;
  __syncthreads();
  uint32_t myoff = 0, total = 0;
  for (int t = 0; t < 256; t++) { uint32_t v = pcnt[t]; if (t < tid) myoff += v; total += v; }
  if (total == 0) return;            // uniform (every thread computed full sum)
  if (tid == 0) sbase = atomicAdd(&paircnt[b], total);
  __syncthreads();
  uint32_t base = sbase;
  uint32_t* gp = pairs + (size_t)b * PAIR_CAP;
  // phase 2: emit (identical iteration order)
  uint32_t k = 0;
  for (int jt = 0; jt < m; jt += 256) {
    int jn = min(256, m - jt);
    __syncthreads();
    if (tid < jn) { uint32_t gj = cl[jt + tid]; jidx[tid] = gj; tb[tid] = ob4[gj]; }
    __syncthreads();
    for (int i = tid; i < m; i += 256) {
      uint32_t gi = cl[i];
      float4 v = ob4[gi];
      float bai = __fmul_rn(__fsub_rn(v.z, v.x), __fsub_rn(v.w, v.y));
      for (int jj = 0; jj < jn; jj++) {
        uint32_t gj = jidx[jj];
        if (gj > gi && iou_gt(v.x, v.y, v.z, v.w, bai, tb[jj])) {
          uint32_t pos = base + myoff + k; k++;
          if (pos < PAIR_CAP) gp[pos] = (gi << 13) | gj;
        }
      }
    }
  }
}

// ---------------- bucketed sparse-pair blocked greedy NMS, 256 thr/image --------
__global__ void k_nms(const float* __restrict__ ob,
                      const unsigned long long* __restrict__ vbits,
                      unsigned long long* __restrict__ keepw,
                      const uint32_t* __restrict__ pairs,
                      const uint32_t* __restrict__ paircnt) {
  int b = blockIdx.x;
  int tid = threadIdx.x;
  int lane = tid & 63;
  int wv = tid >> 6;
  __shared__ unsigned long long tdl[NWIN * 64];   // within-window rows; 37888 B
  __shared__ unsigned long long svl[NWIN];
  __shared__ unsigned long long sup[NWIN];
  __shared__ unsigned long long kwsh;
  __shared__ uint32_t plp[LDSP];                  // window-sorted pairs; 49152 B
  __shared__ uint32_t wstart[NWIN + 1];
  __shared__ uint32_t wtmp[NWIN];
  for (int i = tid; i < NWIN * 64; i += 256) tdl[i] = 0ull;
  if (tid < NWIN) { svl[tid] = vbits[b * NWIN + tid]; sup[tid] = 0ull; wtmp[tid] = 0u; }
  uint32_t npairs = paircnt[b];
  bool useP = (npairs <= (uint32_t)PAIR_CAP);
  bool useL = (npairs <= (uint32_t)LDSP);
  const uint32_t* gpl = pairs + (size_t)b * PAIR_CAP;
  __syncthreads();
  unsigned int* sup32 = (unsigned int*)sup;
  unsigned int* tdl32 = (unsigned int*)tdl;
  if (useP) {
    // build tdl rows from same-window pairs; count cross-window buckets
    for (uint32_t t = tid; t < npairs; t += 256) {
      uint32_t p = gpl[t];
      int i = (int)(p >> 13), j = (int)(p & 8191u);
      if ((i >> 6) == (j >> 6)) {
        int r = ((i >> 6) * 64 + (i & 63)) * 2 + ((j & 63) >> 5);
        atomicOr(&tdl32[r], 1u << (j & 31));
      } else {
        atomicAdd(&wtmp[i >> 6], 1u);
      }
    }
    __syncthreads();
    if (tid == 0) {
      uint32_t acc = 0;
      for (int w = 0; w < NWIN; w++) { wstart[w] = acc; acc += wtmp[w]; }
      wstart[NWIN] = acc;
    }
    __syncthreads();
    if (tid < NWIN) wtmp[tid] = 0u;
    __syncthreads();
    if (useL) {
      for (uint32_t t = tid; t < npairs; t += 256) {
        uint32_t p = gpl[t];
        int i = (int)(p >> 13), j = (int)(p & 8191u);
        if ((i >> 6) == (j >> 6)) continue;
        uint32_t w = (uint32_t)(i >> 6);
        uint32_t pos = wstart[w] + atomicAdd(&wtmp[w], 1u);
        plp[pos] = p;
      }
    }
    __syncthreads();
    for (int w = 0; w < NWIN; w++) {
      if (wv == 0) {
        unsigned long long row = tdl[w * 64 + lane];
        unsigned long long m = __ballot(row != 0ull);
        unsigned long long sa = sup[w];
        unsigned long long sval = svl[w];
        unsigned int rlo = (unsigned int)row, rhi = (unsigned int)(row >> 32);
        while (m) {
          int i = __ffsll((long long)m) - 1;
          m &= m - 1;
          if (((sval >> i) & 1ull) && !((sa >> i) & 1ull)) {
            unsigned int lo = (unsigned int)__builtin_amdgcn_readlane((int)rlo, i);
            unsigned int hi = (unsigned int)__builtin_amdgcn_readlane((int)rhi, i);
            sa |= (((unsigned long long)hi) << 32) | (unsigned long long)lo;
          }
        }
        unsigned long long kw = sval & ~sa;
        if (lane == 0) { keepw[b * NWIN + w] = kw; kwsh = kw; }
      }
      __syncthreads();
      unsigned long long kw = kwsh;
      if (useL) {
        for (uint32_t t = wstart[w] + tid; t < wstart[w + 1]; t += 256) {
          uint32_t p = plp[t];
          int i = (int)(p >> 13);
          if (!((kw >> (i & 63)) & 1ull)) continue;
          int j = (int)(p & 8191u);
          atomicOr(&sup32[j >> 5], 1u << (j & 31));
        }
      } else {
        for (uint32_t t = tid; t < npairs; t += 256) {
          uint32_t p = gpl[t];
          int i = (int)(p >> 13);
          if ((i >> 6) != w) continue;
          int j = (int)(p & 8191u);
          if ((j >> 6) == w) continue;   // same-window handled via tdl
          if (!((kw >> (i & 63)) & 1ull)) continue;
          atomicOr(&sup32[j >> 5], 1u << (j & 31));
        }
      }
      __syncthreads();
    }
  } else {
    // -------- overflow fallback: recompute IoU from ob (rare/never) --------
    const float4* ob4 = (const float4*)ob + (size_t)b * KTOT;
    for (int w = 0; w < NWIN; w++) {
      if (wv == 0) {
        int i = w * 64 + lane;
        unsigned long long row = 0ull;
        if (i < KTOT) {
          float4 v = ob4[i];
          float bai = __fmul_rn(__fsub_rn(v.z, v.x), __fsub_rn(v.w, v.y));
          for (int jj = 0; jj < 64; jj++) {
            int j = w * 64 + jj;
            if (j > i && j < KTOT)
              row |= ((unsigned long long)iou_gt(v.x, v.y, v.z, v.w, bai, ob4[j])) << jj;
          }
        }
        unsigned long long m = __ballot(row != 0ull);
        unsigned long long sa = sup[w];
        unsigned long long sval = svl[w];
        unsigned int rlo = (unsigned int)row, rhi = (unsigned int)(row >> 32);
        while (m) {
          int i2 = __ffsll((long long)m) - 1;
          m &= m - 1;
          if (((sval >> i2) & 1ull) && !((sa >> i2) & 1ull)) {
            unsigned int lo = (unsigned int)__builtin_amdgcn_readlane((int)rlo, i2);
            unsigned int hi = (unsigned int)__builtin_amdgcn_readlane((int)rhi, i2);
            sa |= (((unsigned long long)hi) << 32) | (unsigned long long)lo;
          }
        }
        unsigned long long kw = sval & ~sa;
        if (lane == 0) { keepw[b * NWIN + w] = kw; kwsh = kw; }
      }
      __syncthreads();
      unsigned long long kw = kwsh;
      for (int ii = 0; ii < 64; ii++) {
        if (!((kw >> ii) & 1ull)) continue;
        int i = w * 64 + ii;
        if (i >= KTOT) break;
        float4 v = ob4[i];
        float bai = __fmul_rn(__fsub_rn(v.z, v.x), __fsub_rn(v.w, v.y));
        for (int j = (w + 1) * 64 + tid; j < KTOT; j += 256)
          if (iou_gt(v.x, v.y, v.z, v.w, bai, ob4[j]))
            atomicOr(&sup32[j >> 5], 1u << (j & 31));
      }
      __syncthreads();
    }
  }
}

// ---------------- final outputs ----------------
__global__ void k_out(const float* __restrict__ ss, const uint32_t* __restrict__ sl,
                      const float* __restrict__ sb, const unsigned long long* __restrict__ keepw,
                      float* __restrict__ out) {
  int r = blockIdx.x * blockDim.x + threadIdx.x;
  if (r >= BN * KTOT) return;
  int b = r / KTOT;
  int e = r - b * KTOT;
  unsigned int kp = (unsigned int)((keepw[b * NWIN + (e >> 6)] >> (e & 63)) & 1ull);
  out[(size_t)r * 5 + 0] = sb[(size_t)r * 4 + 0];
  out[(size_t)r * 5 + 1] = sb[(size_t)r * 4 + 1];
  out[(size_t)r * 5 + 2] = sb[(size_t)r * 4 + 2];
  out[(size_t)r * 5 + 3] = sb[(size_t)r * 4 + 3];
  out[(size_t)r * 5 + 4] = ss[r];
  out[(size_t)BN * KTOT * 5 + r] = (float)sl[r];
  out[(size_t)BN * KTOT * 6 + r] = kp ? 1.0f : 0.0f;
}

extern "C" void kernel_launch(void* const* d_in, const int* in_sizes, int n_in,
                              void* d_out, int out_size, void* d_ws, size_t ws_size,
                              hipStream_t stream) {
  InPtrs ip;
  for (int l = 0; l < 5; l++) {
    ip.cls[l]  = (const float*)d_in[3 * l + 0];
    ip.bbox[l] = (const float*)d_in[3 * l + 1];
    ip.ctr[l]  = (const float*)d_in[3 * l + 2];
  }

  size_t off = 0;
  auto alloc = [&](size_t n) {
    char* p = (char*)d_ws + off;
    off = (off + n + 255) & ~(size_t)255;
    return p;
  };
  const size_t SU_BYTES   = (size_t)BN * TOT * 4;                  // 2.73 MB
  const size_t HIST_BYTES = (20ull * 1024 + 20ull * 1024 + 20ull * 4096) * 4; // 480 KB
  const size_t EXTRA      = 256;                                   // selcnt/tiecnt/maxcb
  char* r0p = (char*)alloc(((SU_BYTES + 255) & ~(size_t)255) + HIST_BYTES + EXTRA);
  uint32_t* su    = (uint32_t*)r0p;
  uint32_t* hist0 = (uint32_t*)(r0p + ((SU_BYTES + 255) & ~(size_t)255));
  uint32_t* hist1 = hist0 + 20ull * 1024;
  uint32_t* hist2 = hist1 + 20ull * 1024;
  uint32_t* selcnt = hist2 + 20ull * 4096;
  uint32_t* tiecnt = selcnt + 20;
  uint32_t* maxcb  = tiecnt + 20;

  uint32_t* mpfx   = (uint32_t*)alloc(20 * 4);
  uint32_t* mk     = (uint32_t*)alloc(20 * 4);
  uint32_t* selu   = (uint32_t*)alloc(20ull * 1024 * 4);
  uint32_t* seli   = (uint32_t*)alloc(20ull * 1024 * 4);
  uint32_t* tiei   = (uint32_t*)alloc(20ull * TIE_CAP * 4);
  float*    ccs    = (float*)   alloc((size_t)BN * KTOT * 4);
  uint32_t* ccl    = (uint32_t*)alloc((size_t)BN * KTOT * 4);
  uint32_t* ccv    = (uint32_t*)alloc((size_t)BN * KTOT * 4);
  float*    ccb    = (float*)   alloc((size_t)BN * KTOT * 16);
  float*    ss     = (float*)   alloc((size_t)BN * KTOT * 4);
  uint32_t* sl     = (uint32_t*)alloc((size_t)BN * KTOT * 4);
  uint32_t* sv     = (uint32_t*)alloc((size_t)BN * KTOT * 4);
  float*    sb     = (float*)   alloc((size_t)BN * KTOT * 16);
  float*    ob     = (float*)   alloc((size_t)BN * KTOT * 16);
  uint32_t* rankp  = (uint32_t*)alloc((size_t)BN * NJT * KTOT * 4); // 1.43 MB
  uint32_t* clist  = (uint32_t*)alloc((size_t)BN * NC * KTOT * 4);  // 6.04 MB
  uint32_t* ccount = (uint32_t*)alloc((size_t)BN * NC * 4);
  unsigned long long* vbits = (unsigned long long*)alloc((size_t)BN * NWIN * 8);
  unsigned long long* keepw = (unsigned long long*)alloc((size_t)BN * NWIN * 8);
  uint32_t* pairs   = (uint32_t*)alloc((size_t)BN * PAIR_CAP * 4);  // 2 MB
  uint32_t* paircnt = (uint32_t*)alloc(BN * 4);
  (void)ws_size; (void)in_sizes; (void)n_in; (void)out_size;

  dim3 gscan((TOT + 255) / 256, BN);
  hipMemsetAsync(hist0, 0, HIST_BYTES + EXTRA, stream);   // all hists + counters
  k_score<<<dim3(36, BN), 256, 0, stream>>>(ip, su, hist0);
  k_findp<<<20, 256, 0, stream>>>(hist0, mpfx, mk, 1024, 22, 0);
  k_scan1<<<gscan, 256, 0, stream>>>(su, mpfx, hist1);
  k_findp<<<20, 256, 0, stream>>>(hist1, mpfx, mk, 1024, 12, 1);
  k_scan2<<<gscan, 256, 0, stream>>>(su, mpfx, hist2);
  k_findp<<<20, 256, 0, stream>>>(hist2, mpfx, mk, 4096, 0, 2);
  k_compact<<<gscan, 256, 0, stream>>>(su, mpfx, selcnt, tiecnt, selu, seli, tiei);
  k_ties<<<20, 256, 0, stream>>>(mpfx, mk, tiecnt, tiei, selu, seli);
  k_emit<<<dim3(20, 4), 256, 0, stream>>>(ip, selu, seli, ccs, ccl, ccv, ccb);
  k_rank<<<dim3(19, NJT, BN), 256, 0, stream>>>(ccs, rankp);
  k_scatter<<<dim3(19, BN), 256, 0, stream>>>(ccs, ccl, ccv, ccb, rankp, ss, sl, sv, sb, maxcb);
  k_class<<<dim3(NC, BN), 256, 0, stream>>>(sl, clist, ccount);
  k_bits<<<dim3(NWIN, BN), 64, 0, stream>>>(sv, vbits);
  k_offset<<<(BN * KTOT + 255) / 256, 256, 0, stream>>>(sb, sl, maxcb, ob, paircnt);
  k_mask2<<<dim3(NC, BN), 256, 0, stream>>>(ob, clist, ccount, pairs, paircnt);
  k_nms<<<BN, 256, 0, stream>>>(ob, vbits, keepw, pairs, paircnt);
  k_out<<<(BN * KTOT + 255) / 256, 256, 0, stream>>>(ss, sl, sb, keepw, (float*)d_out);
}

// Round 8
// 260.030 us; speedup vs baseline: 3.3414x; 1.0297x over previous
//
#include <hip/hip_runtime.h>
#include <stdint.h>

// FCOS bbox post-processing, B=4 images — bit-exact np/XLA-f32 replication
// (R7 semantics). R13: block-aggregated atomics. R16: 3-digit radix selection.
// R17: 2D rank decomposition. R18: class-bucketed IoU (dense mask deleted).
// R19:
//  - k_nms: main loop runs in ONE wave, barrier-free (was 148 block barriers).
//    DS ops from a single wave complete in order; fence per window for safety.
//  - k_pairs = k_class + k_mask2 fused; member list lives in LDS (18.9 KB),
//    clist global buffer deleted.
//  - k_offbits = k_offset + k_bits fused (wave-per-window ballot).

#define BN 4
#define NC 80
#define TOT 170720       // 128000+32000+8000+2000+720
#define KTOT 4720        // 1000*4+720
#define NWIN 74          // ceil(4720/64)
#define NJT 19           // rank j-tiles
#define TIE_CAP 4096
#define IMGSZ 320.0f
#define PAIR_CAP 131072  // pairs per image (global)
#define LDSP 12288       // pairs staged in LDS

struct InPtrs {
  const float* cls[5];
  const float* bbox[5];
  const float* ctr[5];
};

__device__ __forceinline__ uint32_t f2s(float f) {
  uint32_t x = __float_as_uint(f);
  return (x & 0x80000000u) ? ~x : (x | 0x80000000u);
}
__device__ __forceinline__ float s2f(uint32_t s) {
  uint32_t x = (s & 0x80000000u) ? (s & 0x7fffffffu) : ~s;
  return __uint_as_float(x);
}
// np/XLA logistic: 1/(1+exp(-x)) with per-op f32 rounding.
__device__ __forceinline__ float sigmoid32(float v) {
  float e = (float)exp(-(double)v);          // CR f32 exp(-v)
  return __fdiv_rn(1.0f, __fadd_rn(1.0f, e));
}
__device__ __forceinline__ void lvl_of(int e, int& l, int& le) {
  if (e < 128000)      { l = 0; le = e; }
  else if (e < 160000) { l = 1; le = e - 128000; }
  else if (e < 168000) { l = 2; le = e - 160000; }
  else if (e < 170000) { l = 3; le = e - 168000; }
  else                 { l = 4; le = e - 170000; }
}
__device__ __forceinline__ int kl_of(int l) {
  constexpr int KL[5] = {1000, 1000, 1000, 1000, 720};
  return KL[l];
}
__device__ __forceinline__ float clip32(float v) {
  return fminf(fmaxf(v, 0.0f), IMGSZ);
}
// tile table for k_score: 36 tiles/image of (<=64 p) x (80 c)
__device__ __forceinline__ void tile_of(int t, int& l, int& p0) {
  if (t < 25)       { l = 0; p0 = t * 64; }
  else if (t < 32)  { l = 1; p0 = (t - 25) * 64; }
  else if (t < 34)  { l = 2; p0 = (t - 32) * 64; }
  else if (t == 34) { l = 3; p0 = 0; }
  else              { l = 4; p0 = 0; }
}
// IoU > 0.5 predicate, exact np f32 op chain (identical to R7-R18).
__device__ __forceinline__ int iou_gt(float bx1, float by1, float bx2, float by2,
                                      float bai, float4 o) {
  float ta_ = __fmul_rn(__fsub_rn(o.z, o.x), __fsub_rn(o.w, o.y));
  float ltx = fmaxf(bx1, o.x), lty = fmaxf(by1, o.y);
  float rbx = fminf(bx2, o.z), rby = fminf(by2, o.w);
  float wd = fmaxf(__fsub_rn(rbx, ltx), 0.0f);
  float hg = fmaxf(__fsub_rn(rby, lty), 0.0f);
  float inter = __fmul_rn(wd, hg);
  float asum = __fadd_rn(bai, ta_);
  float uni  = __fsub_rn(asum, inter);
  float iou  = (uni > 0.0f) ? __fdiv_rn(inter, uni) : 0.0f;
  return (iou > 0.5f) ? 1 : 0;
}

// ---------------- scores -> sortable u32 keys + pass-0 LDS histogram -----------
__global__ void k_score(InPtrs in, uint32_t* __restrict__ su, uint32_t* __restrict__ hist0) {
  int b = blockIdx.y;
  int tl, p0; tile_of(blockIdx.x, tl, p0);
  constexpr int HWc[5]  = {1600, 400, 100, 25, 9};
  constexpr int LOFF[5] = {0, 128000, 160000, 168000, 170000};
  int hw = HWc[tl];
  int tw = min(64, hw - p0);
  int tid = threadIdx.x;
  __shared__ uint32_t lu[64 * 81];   // padded transpose tile (20.7 KB)
  __shared__ uint32_t lh[1024];      // pass-0 hist (4 KB)
  for (int i = tid; i < 1024; i += 256) lh[i] = 0;
  __syncthreads();
  int pf = tid & 63;
  if (pf < tw) {
    const float* cp = in.cls[tl] + (size_t)b * NC * hw + p0 + pf;
    for (int c = tid >> 6; c < NC; c += 4) {
      float v = cp[(size_t)c * hw];                 // coalesced (64-lane run)
      float s = sigmoid32(v);
      float m = (s > 0.025f) ? s : -1.0f;
      uint32_t u = f2s(m);
      lu[pf * 81 + c] = u;
      atomicAdd(&lh[u >> 22], 1u);                  // LDS atomic
    }
  }
  __syncthreads();
  int bl = b * 5 + tl;
  for (int i = tid; i < 1024; i += 256)
    if (lh[i]) atomicAdd(&hist0[(size_t)bl * 1024 + i], lh[i]);
  int n = tw * NC;
  uint32_t* dst = su + (size_t)b * TOT + LOFF[tl] + p0 * NC;
  for (int idx = tid; idx < n; idx += 256)
    dst[idx] = lu[(idx / 80) * 81 + (idx % 80)];    // contiguous store
}

// ---------------- radix pass 1: bits 21-12 of top-10 matches (LDS) -------------
__global__ void k_scan1(const uint32_t* __restrict__ su, const uint32_t* __restrict__ mpfx,
                        uint32_t* __restrict__ hist1) {
  int b = blockIdx.y;
  int tid = threadIdx.x;
  int e0 = blockIdx.x * 256;
  int e = e0 + tid;
  int l0, le0; lvl_of(e0, l0, le0);
  __shared__ uint32_t lh[2][1024];   // two slots: block may span 2 levels
  for (int i = tid; i < 2048; i += 256) lh[i >> 10][i & 1023] = 0;
  __syncthreads();
  if (e < TOT) {
    int l, le; lvl_of(e, l, le);
    uint32_t C = mpfx[b * 5 + l];
    uint32_t u = su[(size_t)b * TOT + e];
    if ((u >> 22) == (C >> 22)) atomicAdd(&lh[l - l0][(u >> 12) & 1023u], 1u);
  }
  __syncthreads();
  for (int s = 0; s < 2; s++) {
    int l = l0 + s;
    if (l >= 5) break;
    int bl = b * 5 + l;
    for (int i = tid; i < 1024; i += 256)
      if (lh[s][i]) atomicAdd(&hist1[(size_t)bl * 1024 + i], lh[s][i]);
  }
}

// ---------------- radix pass 2: low 12 bits of top-20 matches (rare) -----------
__global__ void k_scan2(const uint32_t* __restrict__ su, const uint32_t* __restrict__ mpfx,
                        uint32_t* __restrict__ hist2) {
  int b = blockIdx.y;
  int e = blockIdx.x * blockDim.x + threadIdx.x;
  if (e >= TOT) return;
  int l, le; lvl_of(e, l, le);
  int bl = b * 5 + l;
  uint32_t C = mpfx[bl];
  uint32_t u = su[(size_t)b * TOT + e];
  if ((u >> 12) == (C >> 12))
    atomicAdd(&hist2[(size_t)bl * 4096 + (u & 4095u)], 1u);
}

// ---------------- generic digit select (suffix-count crossing) -----------------
__global__ void k_findp(const uint32_t* __restrict__ hist, uint32_t* __restrict__ mpfx,
                        uint32_t* __restrict__ mk, int nbins, int shift, int pass) {
  int bl = blockIdx.x;
  uint32_t k = (pass == 0) ? (uint32_t)kl_of(bl % 5) : mk[bl];
  const uint32_t* h = hist + (size_t)bl * nbins;
  __shared__ uint32_t gsum[256];
  int tid = threadIdx.x;
  int per = nbins / 256;             // 4 or 16
  int base = tid * per;
  uint32_t s = 0;
  for (int i = 0; i < per; i++) s += h[base + i];
  gsum[tid] = s;
  __syncthreads();
  uint32_t above = 0;
  for (int t = tid + 1; t < 256; t++) above += gsum[t];
  if (above < k && above + s >= k) {
    uint32_t cum = above;
    for (int bin = base + per - 1; bin >= base; bin--) {
      uint32_t c = h[bin];
      if (cum < k && cum + c >= k) {
        uint32_t pfx = (pass == 0) ? 0u : mpfx[bl];
        mpfx[bl] = pfx | ((uint32_t)bin << shift);
        mk[bl] = k - cum;
        break;
      }
      cum += c;
    }
  }
}

// ---------------- compact selected (LDS-staged, block-aggregated atomics) -------
__global__ void k_compact(const uint32_t* __restrict__ su, const uint32_t* __restrict__ mpfx,
                          uint32_t* __restrict__ selcnt, uint32_t* __restrict__ tiecnt,
                          uint32_t* __restrict__ selu, uint32_t* __restrict__ seli,
                          uint32_t* __restrict__ tiei) {
  int b = blockIdx.y;
  int tid = threadIdx.x;
  int e0 = blockIdx.x * 256;
  int e = e0 + tid;
  int l0, le0; lvl_of(e0, l0, le0);
  __shared__ uint32_t cnt[2], tcnt[2], gbase[2], tgbase[2];
  __shared__ uint32_t su_s[2][256], si_s[2][256];   // staged selected (u, le)
  __shared__ uint32_t ti_s[2][256];                 // staged tie le
  if (tid < 2) { cnt[tid] = 0u; tcnt[tid] = 0u; }
  __syncthreads();
  if (e < TOT) {
    int l, le; lvl_of(e, l, le);
    int slot = l - l0;          // 0 or 1
    int bl = b * 5 + l;
    uint32_t u = su[(size_t)b * TOT + e];
    uint32_t C = mpfx[bl];
    if (u > C) {
      uint32_t p = atomicAdd(&cnt[slot], 1u);
      su_s[slot][p] = u;
      si_s[slot][p] = (uint32_t)le;
    } else if (u == C) {
      uint32_t p = atomicAdd(&tcnt[slot], 1u);
      ti_s[slot][p] = (uint32_t)le;
    }
  }
  __syncthreads();
  if (tid < 2) {
    int bl = b * 5 + l0 + tid;
    if (cnt[tid])  gbase[tid]  = atomicAdd(&selcnt[bl], cnt[tid]);
    if (tcnt[tid]) tgbase[tid] = atomicAdd(&tiecnt[bl], tcnt[tid]);
  }
  __syncthreads();
  for (int s = 0; s < 2; s++) {
    int bl = b * 5 + l0 + s;
    uint32_t n = cnt[s];
    for (uint32_t t = tid; t < n; t += 256) {
      uint32_t pos = gbase[s] + t;
      selu[(size_t)bl * 1024 + pos] = su_s[s][t];
      seli[(size_t)bl * 1024 + pos] = si_s[s][t];
    }
    uint32_t tn = tcnt[s];
    for (uint32_t t = tid; t < tn; t += 256) {
      uint32_t pos = tgbase[s] + t;
      if (pos < TIE_CAP) tiei[(size_t)bl * TIE_CAP + pos] = ti_s[s][t];
    }
  }
}

// Boundary ties: stable top_k -> smallest indices first.
__global__ void k_ties(const uint32_t* __restrict__ mpfx, const uint32_t* __restrict__ mk,
                       const uint32_t* __restrict__ tiecnt, const uint32_t* __restrict__ tiei,
                       uint32_t* __restrict__ selu, uint32_t* __restrict__ seli) {
  int bl = blockIdx.x;
  int l = bl % 5;
  uint32_t C = mpfx[bl];
  uint32_t T = mk[bl];
  uint32_t G = (uint32_t)kl_of(l) - T;
  uint32_t Tc = tiecnt[bl];
  if (Tc > TIE_CAP) Tc = TIE_CAP;
  __shared__ uint32_t sh[TIE_CAP];
  for (uint32_t t = threadIdx.x; t < Tc; t += blockDim.x) sh[t] = tiei[(size_t)bl * TIE_CAP + t];
  __syncthreads();
  for (uint32_t t = threadIdx.x; t < Tc; t += blockDim.x) {
    uint32_t my = sh[t];
    uint32_t rank = 0;
    for (uint32_t q = 0; q < Tc; q++) rank += (sh[q] < my) ? 1u : 0u;
    if (rank < T) {
      selu[(size_t)bl * 1024 + G + rank] = C;
      seli[(size_t)bl * 1024 + G + rank] = my;
    }
  }
}

// ---------------- exact rank within level + emit (packed u64 keys) --------------
__global__ void k_emit(InPtrs in, const uint32_t* __restrict__ selu, const uint32_t* __restrict__ seli,
                       float* __restrict__ ccs, uint32_t* __restrict__ ccl,
                       uint32_t* __restrict__ ccv, float* __restrict__ ccb) {
  int bl = blockIdx.x;
  int chunk = blockIdx.y;
  int b = bl / 5, l = bl % 5;
  int k = kl_of(l);
  __shared__ uint64_t z[1024];   // 8 KB
  int tid = threadIdx.x;
  for (int t = tid; t < 1024; t += 256) {
    if (t < k) {
      uint32_t u = selu[(size_t)bl * 1024 + t];
      uint32_t idx = seli[(size_t)bl * 1024 + t];
      z[t] = (((uint64_t)u) << 32) | (uint32_t)(~idx);
    } else z[t] = 0ull;
  }
  __syncthreads();
  int tg = chunk * 256 + tid;
  if (tg >= k) return;
  uint64_t zi = z[tg];
  uint32_t u = (uint32_t)(zi >> 32);
  uint32_t idx = ~(uint32_t)zi;
  int rank = 0;
  const uint4* z4 = (const uint4*)z;
  for (int j4 = 0; j4 < 512; j4++) {
    uint4 q = z4[j4];
    uint64_t za = (((uint64_t)q.y) << 32) | q.x;
    uint64_t zb = (((uint64_t)q.w) << 32) | q.z;
    rank += (za > zi) ? 1 : 0;
    rank += (zb > zi) ? 1 : 0;
  }
  constexpr int Wc[5]  = {40, 20, 10, 5, 3};
  constexpr int HWc[5] = {1600, 400, 100, 25, 9};
  constexpr float Sc[5] = {8.f, 16.f, 32.f, 64.f, 128.f};
  constexpr int COFF[5] = {0, 1000, 2000, 3000, 4000};
  int w = Wc[l], hw = HWc[l];
  float ms = s2f(u);
  int valid = (ms > 0.025f) ? 1 : 0;
  int p = (int)idx / NC, c = (int)idx % NC;
  int x = p % w, y = p / w;
  float sf = sigmoid32(in.ctr[l][(size_t)b * hw + p]);
  float score = valid ? __fmul_rn(ms, sf) : -1.0f;
  float px = __fmul_rn(__fadd_rn((float)x, 0.5f), Sc[l]);
  float py = __fmul_rn(__fadd_rn((float)y, 0.5f), Sc[l]);
  size_t bb = (size_t)b * 4 * hw;
  float d0 = in.bbox[l][bb + 0 * hw + p];
  float d1 = in.bbox[l][bb + 1 * hw + p];
  float d2 = in.bbox[l][bb + 2 * hw + p];
  float d3 = in.bbox[l][bb + 3 * hw + p];
  float x1 = clip32(__fsub_rn(px, d0)), y1 = clip32(__fsub_rn(py, d1));
  float x2 = clip32(__fadd_rn(px, d2)), y2 = clip32(__fadd_rn(py, d3));
  int o = b * KTOT + COFF[l] + rank;
  ccs[o] = score;
  ccl[o] = (uint32_t)c;
  ccv[o] = (uint32_t)valid;
  ccb[(size_t)o * 4 + 0] = x1; ccb[(size_t)o * 4 + 1] = y1;
  ccb[(size_t)o * 4 + 2] = x2; ccb[(size_t)o * 4 + 3] = y2;
}

// ---------------- partial ranks vs 256-key j-tiles ----------------
__global__ void k_rank(const float* __restrict__ ccs, uint32_t* __restrict__ rankp) {
  int b = blockIdx.z;
  int jt = blockIdx.y;
  int ib = blockIdx.x;
  int tid = threadIdx.x;
  __shared__ uint32_t jk[256];   // 1 KB
  int j0 = jt * 256;
  int jn = min(256, KTOT - j0);
  jk[tid] = (tid < jn) ? f2s(ccs[(size_t)b * KTOT + j0 + tid]) : 0u;
  __syncthreads();
  int e = ib * 256 + tid;
  if (e >= KTOT) return;
  uint32_t ke = f2s(ccs[(size_t)b * KTOT + e]);
  int rank = 0;
  const uint4* k4 = (const uint4*)jk;
#pragma unroll 8
  for (int q = 0; q < 64; q++) {
    uint4 kk = k4[q];
    int j = j0 + q * 4;
    rank += ((kk.x > ke) || (kk.x == ke && (j + 0) < e)) ? 1 : 0;
    rank += ((kk.y > ke) || (kk.y == ke && (j + 1) < e)) ? 1 : 0;
    rank += ((kk.z > ke) || (kk.z == ke && (j + 2) < e)) ? 1 : 0;
    rank += ((kk.w > ke) || (kk.w == ke && (j + 3) < e)) ? 1 : 0;
  }
  rankp[((size_t)b * NJT + jt) * KTOT + e] = (uint32_t)rank;   // contiguous
}

// ---------------- sum partials + permuted scatter + maxcb ----------------
__global__ void k_scatter(const float* __restrict__ ccs, const uint32_t* __restrict__ ccl,
                          const uint32_t* __restrict__ ccv, const float* __restrict__ ccb,
                          const uint32_t* __restrict__ rankp,
                          float* __restrict__ ss, uint32_t* __restrict__ sl,
                          uint32_t* __restrict__ sv, float* __restrict__ sb,
                          uint32_t* __restrict__ maxcb) {
  int b = blockIdx.y;
  __shared__ float red[4];
  int tid = threadIdx.x;
  int e = blockIdx.x * 256 + tid;
  float mx = 0.0f;
  if (e < KTOT) {
    uint32_t rank = 0;
    for (int jt = 0; jt < NJT; jt++)
      rank += rankp[((size_t)b * NJT + jt) * KTOT + e];   // coalesced
    int sidx = b * KTOT + e;
    int d = b * KTOT + (int)rank;
    ss[d] = ccs[sidx];
    sl[d] = ccl[sidx];
    sv[d] = ccv[sidx];
    float b0 = ccb[(size_t)sidx * 4 + 0], b1 = ccb[(size_t)sidx * 4 + 1];
    float b2 = ccb[(size_t)sidx * 4 + 2], b3 = ccb[(size_t)sidx * 4 + 3];
    sb[(size_t)d * 4 + 0] = b0; sb[(size_t)d * 4 + 1] = b1;
    sb[(size_t)d * 4 + 2] = b2; sb[(size_t)d * 4 + 3] = b3;
    mx = fmaxf(fmaxf(b0, b1), fmaxf(b2, b3));
  }
  for (int o = 32; o; o >>= 1) mx = fmaxf(mx, __shfl_xor(mx, o));
  if ((tid & 63) == 0) red[tid >> 6] = mx;
  __syncthreads();
  if (tid == 0)
    atomicMax(&maxcb[b], __float_as_uint(fmaxf(fmaxf(red[0], red[1]), fmaxf(red[2], red[3]))));
}

// -------- fused per-class offset + valid-bit ballot + paircnt zero (R19) -------
// grid (19, BN) x 256: wave v of block x covers elements [x*256+v*64, +64)
// = exactly window x*4+v of image b.
__global__ void k_offbits(const float* __restrict__ sb, const uint32_t* __restrict__ sl,
                          const uint32_t* __restrict__ maxcb, const uint32_t* __restrict__ sv,
                          float* __restrict__ ob, unsigned long long* __restrict__ vbits,
                          uint32_t* __restrict__ paircnt) {
  int b = blockIdx.y;
  int tid = threadIdx.x;
  if (blockIdx.x == 0 && b == 0 && tid < BN) paircnt[tid] = 0u;
  int e = blockIdx.x * 256 + tid;
  int pred = 0;
  if (e < KTOT) {
    int r = b * KTOT + e;
    float scale = __fadd_rn(__uint_as_float(maxcb[b]), 1.0f);
    float offv = __fmul_rn((float)sl[r], scale);
    float x1 = __fadd_rn(sb[(size_t)r * 4 + 0], offv);
    float y1 = __fadd_rn(sb[(size_t)r * 4 + 1], offv);
    float x2 = __fadd_rn(sb[(size_t)r * 4 + 2], offv);
    float y2 = __fadd_rn(sb[(size_t)r * 4 + 3], offv);
    ob[(size_t)r * 4 + 0] = x1; ob[(size_t)r * 4 + 1] = y1;
    ob[(size_t)r * 4 + 2] = x2; ob[(size_t)r * 4 + 3] = y2;
    pred = (sv[r] != 0u);
  }
  unsigned long long m = __ballot(pred);
  int w = blockIdx.x * 4 + (tid >> 6);
  if ((tid & 63) == 0 && w < NWIN) vbits[b * NWIN + w] = m;
}

// -------- fused per-class member list (LDS) + pairwise IoU -> pairs (R19) ------
__global__ void k_pairs(const uint32_t* __restrict__ sl, const float* __restrict__ ob,
                        uint32_t* __restrict__ pairs, uint32_t* __restrict__ paircnt) {
  int b = blockIdx.y;
  int c = blockIdx.x;
  int tid = threadIdx.x;
  int lane = tid & 63, wv = tid >> 6;
  __shared__ uint32_t lst[KTOT];   // 18.9 KB — member indices, ascending
  __shared__ uint32_t woff[4];
  __shared__ float4 tb[256];       // 4 KB
  __shared__ uint32_t jidx[256];
  __shared__ uint32_t pcnt[256];
  __shared__ uint32_t sbase;
  // order-preserving compaction of this class's members into LDS
  uint32_t base = 0;
  for (int chunk = 0; chunk < KTOT; chunk += 256) {
    int e = chunk + tid;
    int pred = (e < KTOT) && (sl[(size_t)b * KTOT + e] == (uint32_t)c);
    unsigned long long bal = __ballot(pred);
    if (lane == 0) woff[wv] = (uint32_t)__popcll(bal);
    __syncthreads();
    uint32_t myoff = base;
    for (int v = 0; v < wv; v++) myoff += woff[v];
    uint32_t tot = woff[0] + woff[1] + woff[2] + woff[3];
    if (pred) lst[myoff + (uint32_t)__popcll(bal & ((1ull << lane) - 1ull))] = (uint32_t)e;
    base += tot;
    __syncthreads();
  }
  int m = (int)base;
  if (m < 2) return;
  const float4* ob4 = (const float4*)ob + (size_t)b * KTOT;
  // phase 1: count
  uint32_t mycnt = 0;
  for (int jt = 0; jt < m; jt += 256) {
    int jn = min(256, m - jt);
    __syncthreads();
    if (tid < jn) { uint32_t gj = lst[jt + tid]; jidx[tid] = gj; tb[tid] = ob4[gj]; }
    __syncthreads();
    for (int i = tid; i < m; i += 256) {
      uint32_t gi = lst[i];
      float4 v = ob4[gi];
      float bai = __fmul_rn(__fsub_rn(v.z, v.x), __fsub_rn(v.w, v.y));
      for (int jj = 0; jj < jn; jj++)
        if (jidx[jj] > gi && iou_gt(v.x, v.y, v.z, v.w, bai, tb[jj])) mycnt++;
    }
  }
  __syncthreads();
  pcnt[tid] = mycnt;
  __syncthreads();
  uint32_t myoff = 0, total = 0;
  for (int t = 0; t < 256; t++) { uint32_t v = pcnt[t]; if (t < tid) myoff += v; total += v; }
  if (total == 0) return;            // uniform
  if (tid == 0) sbase = atomicAdd(&paircnt[b], total);
  __syncthreads();
  uint32_t gb = sbase;
  uint32_t* gp = pairs + (size_t)b * PAIR_CAP;
  // phase 2: emit (identical iteration order)
  uint32_t k = 0;
  for (int jt = 0; jt < m; jt += 256) {
    int jn = min(256, m - jt);
    __syncthreads();
    if (tid < jn) { uint32_t gj = lst[jt + tid]; jidx[tid] = gj; tb[tid] = ob4[gj]; }
    __syncthreads();
    for (int i = tid; i < m; i += 256) {
      uint32_t gi = lst[i];
      float4 v = ob4[gi];
      float bai = __fmul_rn(__fsub_rn(v.z, v.x), __fsub_rn(v.w, v.y));
      for (int jj = 0; jj < jn; jj++) {
        uint32_t gj = jidx[jj];
        if (gj > gi && iou_gt(v.x, v.y, v.z, v.w, bai, tb[jj])) {
          uint32_t pos = gb + myoff + k; k++;
          if (pos < PAIR_CAP) gp[pos] = (gi << 13) | gj;
        }
      }
    }
  }
}

// ---------- single-wave barrier-free sparse-pair greedy NMS (R19) --------------
__global__ void k_nms(const float* __restrict__ ob,
                      const unsigned long long* __restrict__ vbits,
                      unsigned long long* __restrict__ keepw,
                      const uint32_t* __restrict__ pairs,
                      const uint32_t* __restrict__ paircnt) {
  int b = blockIdx.x;
  int tid = threadIdx.x;
  int lane = tid & 63;
  __shared__ unsigned long long tdl[NWIN * 64];   // within-window rows; 37888 B
  __shared__ unsigned long long svl[NWIN];
  __shared__ unsigned long long sup[NWIN];
  __shared__ unsigned long long kwsh;
  __shared__ uint32_t plp[LDSP];                  // window-sorted pairs; 49152 B
  __shared__ uint32_t wstart[NWIN + 1];
  __shared__ uint32_t wtmp[NWIN];
  for (int i = tid; i < NWIN * 64; i += 256) tdl[i] = 0ull;
  if (tid < NWIN) { svl[tid] = vbits[b * NWIN + tid]; sup[tid] = 0ull; wtmp[tid] = 0u; }
  uint32_t npairs = paircnt[b];
  bool useP = (npairs <= (uint32_t)PAIR_CAP);
  bool useL = (npairs <= (uint32_t)LDSP);
  const uint32_t* gpl = pairs + (size_t)b * PAIR_CAP;
  __syncthreads();
  unsigned int* sup32 = (unsigned int*)sup;
  unsigned int* tdl32 = (unsigned int*)tdl;
  if (useP) {
    // setup with all 256 threads: tdl rows + cross-window bucket counts
    for (uint32_t t = tid; t < npairs; t += 256) {
      uint32_t p = gpl[t];
      int i = (int)(p >> 13), j = (int)(p & 8191u);
      if ((i >> 6) == (j >> 6)) {
        int r = ((i >> 6) * 64 + (i & 63)) * 2 + ((j & 63) >> 5);
        atomicOr(&tdl32[r], 1u << (j & 31));
      } else {
        atomicAdd(&wtmp[i >> 6], 1u);
      }
    }
    __syncthreads();
    if (tid == 0) {
      uint32_t acc = 0;
      for (int w = 0; w < NWIN; w++) { wstart[w] = acc; acc += wtmp[w]; }
      wstart[NWIN] = acc;
    }
    __syncthreads();
    if (tid < NWIN) wtmp[tid] = 0u;
    __syncthreads();
    if (useL) {
      for (uint32_t t = tid; t < npairs; t += 256) {
        uint32_t p = gpl[t];
        int i = (int)(p >> 13), j = (int)(p & 8191u);
        if ((i >> 6) == (j >> 6)) continue;
        uint32_t w = (uint32_t)(i >> 6);
        uint32_t pos = wstart[w] + atomicAdd(&wtmp[w], 1u);
        plp[pos] = p;
      }
    }
    __syncthreads();
    // main loop: single wave, no block barriers. DS ops from one wave
    // complete in program order; fence per window as belt-and-braces.
    if (tid < 64) {
      for (int w = 0; w < NWIN; w++) {
        unsigned long long row = tdl[w * 64 + lane];
        unsigned long long m = __ballot(row != 0ull);
        unsigned long long sa = sup[w];
        unsigned long long sval = svl[w];
        unsigned int rlo = (unsigned int)row, rhi = (unsigned int)(row >> 32);
        while (m) {
          int i = __ffsll((long long)m) - 1;
          m &= m - 1;
          if (((sval >> i) & 1ull) && !((sa >> i) & 1ull)) {
            unsigned int lo = (unsigned int)__builtin_amdgcn_readlane((int)rlo, i);
            unsigned int hi = (unsigned int)__builtin_amdgcn_readlane((int)rhi, i);
            sa |= (((unsigned long long)hi) << 32) | (unsigned long long)lo;
          }
        }
        unsigned long long kw = sval & ~sa;     // identical in all 64 lanes
        if (lane == 0) keepw[b * NWIN + w] = kw;
        if (useL) {
          for (uint32_t t = wstart[w] + lane; t < wstart[w + 1]; t += 64) {
            uint32_t p = plp[t];
            int i = (int)(p >> 13);
            if (!((kw >> (i & 63)) & 1ull)) continue;
            int j = (int)(p & 8191u);
            atomicOr(&sup32[j >> 5], 1u << (j & 31));
          }
        } else {
          for (uint32_t t = lane; t < npairs; t += 64) {
            uint32_t p = gpl[t];
            int i = (int)(p >> 13);
            if ((i >> 6) != w) continue;
            int j = (int)(p & 8191u);
            if ((j >> 6) == w) continue;   // same-window handled via tdl
            if (!((kw >> (i & 63)) & 1ull)) continue;
            atomicOr(&sup32[j >> 5], 1u << (j & 31));
          }
        }
        __threadfence_block();
      }
    }
  } else {
    // -------- overflow fallback: recompute IoU from ob (rare/never) --------
    int wv = tid >> 6;
    const float4* ob4 = (const float4*)ob + (size_t)b * KTOT;
    for (int w = 0; w < NWIN; w++) {
      if (wv == 0) {
        int i = w * 64 + lane;
        unsigned long long row = 0ull;
        if (i < KTOT) {
          float4 v = ob4[i];
          float bai = __fmul_rn(__fsub_rn(v.z, v.x), __fsub_rn(v.w, v.y));
          for (int jj = 0; jj < 64; jj++) {
            int j = w * 64 + jj;
            if (j > i && j < KTOT)
              row |= ((unsigned long long)iou_gt(v.x, v.y, v.z, v.w, bai, ob4[j])) << jj;
          }
        }
        unsigned long long m = __ballot(row != 0ull);
        unsigned long long sa = sup[w];
        unsigned long long sval = svl[w];
        unsigned int rlo = (unsigned int)row, rhi = (unsigned int)(row >> 32);
        while (m) {
          int i2 = __ffsll((long long)m) - 1;
          m &= m - 1;
          if (((sval >> i2) & 1ull) && !((sa >> i2) & 1ull)) {
            unsigned int lo = (unsigned int)__builtin_amdgcn_readlane((int)rlo, i2);
            unsigned int hi = (unsigned int)__builtin_amdgcn_readlane((int)rhi, i2);
            sa |= (((unsigned long long)hi) << 32) | (unsigned long long)lo;
          }
        }
        unsigned long long kw = sval & ~sa;
        if (lane == 0) { keepw[b * NWIN + w] = kw; kwsh = kw; }
      }
      __syncthreads();
      unsigned long long kw = kwsh;
      for (int ii = 0; ii < 64; ii++) {
        if (!((kw >> ii) & 1ull)) continue;
        int i = w * 64 + ii;
        if (i >= KTOT) break;
        float4 v = ob4[i];
        float bai = __fmul_rn(__fsub_rn(v.z, v.x), __fsub_rn(v.w, v.y));
        for (int j = (w + 1) * 64 + tid; j < KTOT; j += 256)
          if (iou_gt(v.x, v.y, v.z, v.w, bai, ob4[j]))
            atomicOr(&sup32[j >> 5], 1u << (j & 31));
      }
      __syncthreads();
    }
  }
}

// ---------------- final outputs ----------------
__global__ void k_out(const float* __restrict__ ss, const uint32_t* __restrict__ sl,
                      const float* __restrict__ sb, const unsigned long long* __restrict__ keepw,
                      float* __restrict__ out) {
  int r = blockIdx.x * blockDim.x + threadIdx.x;
  if (r >= BN * KTOT) return;
  int b = r / KTOT;
  int e = r - b * KTOT;
  unsigned int kp = (unsigned int)((keepw[b * NWIN + (e >> 6)] >> (e & 63)) & 1ull);
  out[(size_t)r * 5 + 0] = sb[(size_t)r * 4 + 0];
  out[(size_t)r * 5 + 1] = sb[(size_t)r * 4 + 1];
  out[(size_t)r * 5 + 2] = sb[(size_t)r * 4 + 2];
  out[(size_t)r * 5 + 3] = sb[(size_t)r * 4 + 3];
  out[(size_t)r * 5 + 4] = ss[r];
  out[(size_t)BN * KTOT * 5 + r] = (float)sl[r];
  out[(size_t)BN * KTOT * 6 + r] = kp ? 1.0f : 0.0f;
}

extern "C" void kernel_launch(void* const* d_in, const int* in_sizes, int n_in,
                              void* d_out, int out_size, void* d_ws, size_t ws_size,
                              hipStream_t stream) {
  InPtrs ip;
  for (int l = 0; l < 5; l++) {
    ip.cls[l]  = (const float*)d_in[3 * l + 0];
    ip.bbox[l] = (const float*)d_in[3 * l + 1];
    ip.ctr[l]  = (const float*)d_in[3 * l + 2];
  }

  size_t off = 0;
  auto alloc = [&](size_t n) {
    char* p = (char*)d_ws + off;
    off = (off + n + 255) & ~(size_t)255;
    return p;
  };
  const size_t SU_BYTES   = (size_t)BN * TOT * 4;                  // 2.73 MB
  const size_t HIST_BYTES = (20ull * 1024 + 20ull * 1024 + 20ull * 4096) * 4; // 480 KB
  const size_t EXTRA      = 256;                                   // selcnt/tiecnt/maxcb
  char* r0p = (char*)alloc(((SU_BYTES + 255) & ~(size_t)255) + HIST_BYTES + EXTRA);
  uint32_t* su    = (uint32_t*)r0p;
  uint32_t* hist0 = (uint32_t*)(r0p + ((SU_BYTES + 255) & ~(size_t)255));
  uint32_t* hist1 = hist0 + 20ull * 1024;
  uint32_t* hist2 = hist1 + 20ull * 1024;
  uint32_t* selcnt = hist2 + 20ull * 4096;
  uint32_t* tiecnt = selcnt + 20;
  uint32_t* maxcb  = tiecnt + 20;

  uint32_t* mpfx   = (uint32_t*)alloc(20 * 4);
  uint32_t* mk     = (uint32_t*)alloc(20 * 4);
  uint32_t* selu   = (uint32_t*)alloc(20ull * 1024 * 4);
  uint32_t* seli   = (uint32_t*)alloc(20ull * 1024 * 4);
  uint32_t* tiei   = (uint32_t*)alloc(20ull * TIE_CAP * 4);
  float*    ccs    = (float*)   alloc((size_t)BN * KTOT * 4);
  uint32_t* ccl    = (uint32_t*)alloc((size_t)BN * KTOT * 4);
  uint32_t* ccv    = (uint32_t*)alloc((size_t)BN * KTOT * 4);
  float*    ccb    = (float*)   alloc((size_t)BN * KTOT * 16);
  float*    ss     = (float*)   alloc((size_t)BN * KTOT * 4);
  uint32_t* sl     = (uint32_t*)alloc((size_t)BN * KTOT * 4);
  uint32_t* sv     = (uint32_t*)alloc((size_t)BN * KTOT * 4);
  float*    sb     = (float*)   alloc((size_t)BN * KTOT * 16);
  float*    ob     = (float*)   alloc((size_t)BN * KTOT * 16);
  uint32_t* rankp  = (uint32_t*)alloc((size_t)BN * NJT * KTOT * 4); // 1.43 MB
  unsigned long long* vbits = (unsigned long long*)alloc((size_t)BN * NWIN * 8);
  unsigned long long* keepw = (unsigned long long*)alloc((size_t)BN * NWIN * 8);
  uint32_t* pairs   = (uint32_t*)alloc((size_t)BN * PAIR_CAP * 4);  // 2 MB
  uint32_t* paircnt = (uint32_t*)alloc(BN * 4);
  (void)ws_size; (void)in_sizes; (void)n_in; (void)out_size;

  dim3 gscan((TOT + 255) / 256, BN);
  hipMemsetAsync(hist0, 0, HIST_BYTES + EXTRA, stream);   // all hists + counters
  k_score<<<dim3(36, BN), 256, 0, stream>>>(ip, su, hist0);
  k_findp<<<20, 256, 0, stream>>>(hist0, mpfx, mk, 1024, 22, 0);
  k_scan1<<<gscan, 256, 0, stream>>>(su, mpfx, hist1);
  k_findp<<<20, 256, 0, stream>>>(hist1, mpfx, mk, 1024, 12, 1);
  k_scan2<<<gscan, 256, 0, stream>>>(su, mpfx, hist2);
  k_findp<<<20, 256, 0, stream>>>(hist2, mpfx, mk, 4096, 0, 2);
  k_compact<<<gscan, 256, 0, stream>>>(su, mpfx, selcnt, tiecnt, selu, seli, tiei);
  k_ties<<<20, 256, 0, stream>>>(mpfx, mk, tiecnt, tiei, selu, seli);
  k_emit<<<dim3(20, 4), 256, 0, stream>>>(ip, selu, seli, ccs, ccl, ccv, ccb);
  k_rank<<<dim3(19, NJT, BN), 256, 0, stream>>>(ccs, rankp);
  k_scatter<<<dim3(19, BN), 256, 0, stream>>>(ccs, ccl, ccv, ccb, rankp, ss, sl, sv, sb, maxcb);
  k_offbits<<<dim3(19, BN), 256, 0, stream>>>(sb, sl, maxcb, sv, ob, vbits, paircnt);
  k_pairs<<<dim3(NC, BN), 256, 0, stream>>>(sl, ob, pairs, paircnt);
  k_nms<<<BN, 256, 0, stream>>>(ob, vbits, keepw, pairs, paircnt);
  k_out<<<(BN * KTOT + 255) / 256, 256, 0, stream>>>(ss, sl, sb, keepw, (float*)d_out);
}

// Round 9
// 240.893 us; speedup vs baseline: 3.6069x; 1.0794x over previous
//
#include <hip/hip_runtime.h>
#include <stdint.h>

// FCOS bbox post-processing, B=4 images — bit-exact np/XLA-f32 replication
// (R7 semantics). R16: 3-digit radix selection. R17: 2D rank decomposition.
// R18: class-bucketed IoU. R19: 1-wave NMS, fused offbits.
// R20: pair generation de-latency:
//  - member lists are UNORDERED (pair set only needs gj>gi on indices), so
//    the 19-chunk ballot compaction (38 barriers/block) is deleted;
//    k_offbits scatters each element into clist via per-class atomics.
//  - k_pairs: single IoU pass, LDS pair staging + one global atomicAdd,
//    cooperative copy-out. Overflow (>4096 staged) -> correct re-pass.

#define BN 4
#define NC 80
#define TOT 170720       // 128000+32000+8000+2000+720
#define KTOT 4720        // 1000*4+720
#define NWIN 74          // ceil(4720/64)
#define NJT 19           // rank j-tiles
#define TIE_CAP 4096
#define IMGSZ 320.0f
#define PAIR_CAP 131072  // pairs per image (global)
#define LDSP 12288       // pairs staged in LDS (k_nms)
#define SPC_CAP 4096     // pairs staged in LDS (k_pairs)

struct InPtrs {
  const float* cls[5];
  const float* bbox[5];
  const float* ctr[5];
};

__device__ __forceinline__ uint32_t f2s(float f) {
  uint32_t x = __float_as_uint(f);
  return (x & 0x80000000u) ? ~x : (x | 0x80000000u);
}
__device__ __forceinline__ float s2f(uint32_t s) {
  uint32_t x = (s & 0x80000000u) ? (s & 0x7fffffffu) : ~s;
  return __uint_as_float(x);
}
// np/XLA logistic: 1/(1+exp(-x)) with per-op f32 rounding.
__device__ __forceinline__ float sigmoid32(float v) {
  float e = (float)exp(-(double)v);          // CR f32 exp(-v)
  return __fdiv_rn(1.0f, __fadd_rn(1.0f, e));
}
__device__ __forceinline__ void lvl_of(int e, int& l, int& le) {
  if (e < 128000)      { l = 0; le = e; }
  else if (e < 160000) { l = 1; le = e - 128000; }
  else if (e < 168000) { l = 2; le = e - 160000; }
  else if (e < 170000) { l = 3; le = e - 168000; }
  else                 { l = 4; le = e - 170000; }
}
__device__ __forceinline__ int kl_of(int l) {
  constexpr int KL[5] = {1000, 1000, 1000, 1000, 720};
  return KL[l];
}
__device__ __forceinline__ float clip32(float v) {
  return fminf(fmaxf(v, 0.0f), IMGSZ);
}
// tile table for k_score: 36 tiles/image of (<=64 p) x (80 c)
__device__ __forceinline__ void tile_of(int t, int& l, int& p0) {
  if (t < 25)       { l = 0; p0 = t * 64; }
  else if (t < 32)  { l = 1; p0 = (t - 25) * 64; }
  else if (t < 34)  { l = 2; p0 = (t - 32) * 64; }
  else if (t == 34) { l = 3; p0 = 0; }
  else              { l = 4; p0 = 0; }
}
// IoU > 0.5 predicate, exact np f32 op chain (identical to R7-R19).
__device__ __forceinline__ int iou_gt(float bx1, float by1, float bx2, float by2,
                                      float bai, float4 o) {
  float ta_ = __fmul_rn(__fsub_rn(o.z, o.x), __fsub_rn(o.w, o.y));
  float ltx = fmaxf(bx1, o.x), lty = fmaxf(by1, o.y);
  float rbx = fminf(bx2, o.z), rby = fminf(by2, o.w);
  float wd = fmaxf(__fsub_rn(rbx, ltx), 0.0f);
  float hg = fmaxf(__fsub_rn(rby, lty), 0.0f);
  float inter = __fmul_rn(wd, hg);
  float asum = __fadd_rn(bai, ta_);
  float uni  = __fsub_rn(asum, inter);
  float iou  = (uni > 0.0f) ? __fdiv_rn(inter, uni) : 0.0f;
  return (iou > 0.5f) ? 1 : 0;
}

// ---------------- scores -> sortable u32 keys + pass-0 LDS histogram -----------
__global__ void k_score(InPtrs in, uint32_t* __restrict__ su, uint32_t* __restrict__ hist0) {
  int b = blockIdx.y;
  int tl, p0; tile_of(blockIdx.x, tl, p0);
  constexpr int HWc[5]  = {1600, 400, 100, 25, 9};
  constexpr int LOFF[5] = {0, 128000, 160000, 168000, 170000};
  int hw = HWc[tl];
  int tw = min(64, hw - p0);
  int tid = threadIdx.x;
  __shared__ uint32_t lu[64 * 81];   // padded transpose tile (20.7 KB)
  __shared__ uint32_t lh[1024];      // pass-0 hist (4 KB)
  for (int i = tid; i < 1024; i += 256) lh[i] = 0;
  __syncthreads();
  int pf = tid & 63;
  if (pf < tw) {
    const float* cp = in.cls[tl] + (size_t)b * NC * hw + p0 + pf;
    for (int c = tid >> 6; c < NC; c += 4) {
      float v = cp[(size_t)c * hw];                 // coalesced (64-lane run)
      float s = sigmoid32(v);
      float m = (s > 0.025f) ? s : -1.0f;
      uint32_t u = f2s(m);
      lu[pf * 81 + c] = u;
      atomicAdd(&lh[u >> 22], 1u);                  // LDS atomic
    }
  }
  __syncthreads();
  int bl = b * 5 + tl;
  for (int i = tid; i < 1024; i += 256)
    if (lh[i]) atomicAdd(&hist0[(size_t)bl * 1024 + i], lh[i]);
  int n = tw * NC;
  uint32_t* dst = su + (size_t)b * TOT + LOFF[tl] + p0 * NC;
  for (int idx = tid; idx < n; idx += 256)
    dst[idx] = lu[(idx / 80) * 81 + (idx % 80)];    // contiguous store
}

// ---------------- radix pass 1: bits 21-12 of top-10 matches (LDS) -------------
__global__ void k_scan1(const uint32_t* __restrict__ su, const uint32_t* __restrict__ mpfx,
                        uint32_t* __restrict__ hist1) {
  int b = blockIdx.y;
  int tid = threadIdx.x;
  int e0 = blockIdx.x * 256;
  int e = e0 + tid;
  int l0, le0; lvl_of(e0, l0, le0);
  __shared__ uint32_t lh[2][1024];   // two slots: block may span 2 levels
  for (int i = tid; i < 2048; i += 256) lh[i >> 10][i & 1023] = 0;
  __syncthreads();
  if (e < TOT) {
    int l, le; lvl_of(e, l, le);
    uint32_t C = mpfx[b * 5 + l];
    uint32_t u = su[(size_t)b * TOT + e];
    if ((u >> 22) == (C >> 22)) atomicAdd(&lh[l - l0][(u >> 12) & 1023u], 1u);
  }
  __syncthreads();
  for (int s = 0; s < 2; s++) {
    int l = l0 + s;
    if (l >= 5) break;
    int bl = b * 5 + l;
    for (int i = tid; i < 1024; i += 256)
      if (lh[s][i]) atomicAdd(&hist1[(size_t)bl * 1024 + i], lh[s][i]);
  }
}

// ---------------- radix pass 2: low 12 bits of top-20 matches (rare) -----------
__global__ void k_scan2(const uint32_t* __restrict__ su, const uint32_t* __restrict__ mpfx,
                        uint32_t* __restrict__ hist2) {
  int b = blockIdx.y;
  int e = blockIdx.x * blockDim.x + threadIdx.x;
  if (e >= TOT) return;
  int l, le; lvl_of(e, l, le);
  int bl = b * 5 + l;
  uint32_t C = mpfx[bl];
  uint32_t u = su[(size_t)b * TOT + e];
  if ((u >> 12) == (C >> 12))
    atomicAdd(&hist2[(size_t)bl * 4096 + (u & 4095u)], 1u);
}

// ---------------- generic digit select (suffix-count crossing) -----------------
__global__ void k_findp(const uint32_t* __restrict__ hist, uint32_t* __restrict__ mpfx,
                        uint32_t* __restrict__ mk, int nbins, int shift, int pass) {
  int bl = blockIdx.x;
  uint32_t k = (pass == 0) ? (uint32_t)kl_of(bl % 5) : mk[bl];
  const uint32_t* h = hist + (size_t)bl * nbins;
  __shared__ uint32_t gsum[256];
  int tid = threadIdx.x;
  int per = nbins / 256;             // 4 or 16
  int base = tid * per;
  uint32_t s = 0;
  for (int i = 0; i < per; i++) s += h[base + i];
  gsum[tid] = s;
  __syncthreads();
  uint32_t above = 0;
  for (int t = tid + 1; t < 256; t++) above += gsum[t];
  if (above < k && above + s >= k) {
    uint32_t cum = above;
    for (int bin = base + per - 1; bin >= base; bin--) {
      uint32_t c = h[bin];
      if (cum < k && cum + c >= k) {
        uint32_t pfx = (pass == 0) ? 0u : mpfx[bl];
        mpfx[bl] = pfx | ((uint32_t)bin << shift);
        mk[bl] = k - cum;
        break;
      }
      cum += c;
    }
  }
}

// ---------------- compact selected (LDS-staged, block-aggregated atomics) -------
__global__ void k_compact(const uint32_t* __restrict__ su, const uint32_t* __restrict__ mpfx,
                          uint32_t* __restrict__ selcnt, uint32_t* __restrict__ tiecnt,
                          uint32_t* __restrict__ selu, uint32_t* __restrict__ seli,
                          uint32_t* __restrict__ tiei) {
  int b = blockIdx.y;
  int tid = threadIdx.x;
  int e0 = blockIdx.x * 256;
  int e = e0 + tid;
  int l0, le0; lvl_of(e0, l0, le0);
  __shared__ uint32_t cnt[2], tcnt[2], gbase[2], tgbase[2];
  __shared__ uint32_t su_s[2][256], si_s[2][256];   // staged selected (u, le)
  __shared__ uint32_t ti_s[2][256];                 // staged tie le
  if (tid < 2) { cnt[tid] = 0u; tcnt[tid] = 0u; }
  __syncthreads();
  if (e < TOT) {
    int l, le; lvl_of(e, l, le);
    int slot = l - l0;          // 0 or 1
    int bl = b * 5 + l;
    uint32_t u = su[(size_t)b * TOT + e];
    uint32_t C = mpfx[bl];
    if (u > C) {
      uint32_t p = atomicAdd(&cnt[slot], 1u);
      su_s[slot][p] = u;
      si_s[slot][p] = (uint32_t)le;
    } else if (u == C) {
      uint32_t p = atomicAdd(&tcnt[slot], 1u);
      ti_s[slot][p] = (uint32_t)le;
    }
  }
  __syncthreads();
  if (tid < 2) {
    int bl = b * 5 + l0 + tid;
    if (cnt[tid])  gbase[tid]  = atomicAdd(&selcnt[bl], cnt[tid]);
    if (tcnt[tid]) tgbase[tid] = atomicAdd(&tiecnt[bl], tcnt[tid]);
  }
  __syncthreads();
  for (int s = 0; s < 2; s++) {
    int bl = b * 5 + l0 + s;
    uint32_t n = cnt[s];
    for (uint32_t t = tid; t < n; t += 256) {
      uint32_t pos = gbase[s] + t;
      selu[(size_t)bl * 1024 + pos] = su_s[s][t];
      seli[(size_t)bl * 1024 + pos] = si_s[s][t];
    }
    uint32_t tn = tcnt[s];
    for (uint32_t t = tid; t < tn; t += 256) {
      uint32_t pos = tgbase[s] + t;
      if (pos < TIE_CAP) tiei[(size_t)bl * TIE_CAP + pos] = ti_s[s][t];
    }
  }
}

// Boundary ties: stable top_k -> smallest indices first.
__global__ void k_ties(const uint32_t* __restrict__ mpfx, const uint32_t* __restrict__ mk,
                       const uint32_t* __restrict__ tiecnt, const uint32_t* __restrict__ tiei,
                       uint32_t* __restrict__ selu, uint32_t* __restrict__ seli) {
  int bl = blockIdx.x;
  int l = bl % 5;
  uint32_t C = mpfx[bl];
  uint32_t T = mk[bl];
  uint32_t G = (uint32_t)kl_of(l) - T;
  uint32_t Tc = tiecnt[bl];
  if (Tc > TIE_CAP) Tc = TIE_CAP;
  __shared__ uint32_t sh[TIE_CAP];
  for (uint32_t t = threadIdx.x; t < Tc; t += blockDim.x) sh[t] = tiei[(size_t)bl * TIE_CAP + t];
  __syncthreads();
  for (uint32_t t = threadIdx.x; t < Tc; t += blockDim.x) {
    uint32_t my = sh[t];
    uint32_t rank = 0;
    for (uint32_t q = 0; q < Tc; q++) rank += (sh[q] < my) ? 1u : 0u;
    if (rank < T) {
      selu[(size_t)bl * 1024 + G + rank] = C;
      seli[(size_t)bl * 1024 + G + rank] = my;
    }
  }
}

// ---------------- exact rank within level + emit (packed u64 keys) --------------
__global__ void k_emit(InPtrs in, const uint32_t* __restrict__ selu, const uint32_t* __restrict__ seli,
                       float* __restrict__ ccs, uint32_t* __restrict__ ccl,
                       uint32_t* __restrict__ ccv, float* __restrict__ ccb) {
  int bl = blockIdx.x;
  int chunk = blockIdx.y;
  int b = bl / 5, l = bl % 5;
  int k = kl_of(l);
  __shared__ uint64_t z[1024];   // 8 KB
  int tid = threadIdx.x;
  for (int t = tid; t < 1024; t += 256) {
    if (t < k) {
      uint32_t u = selu[(size_t)bl * 1024 + t];
      uint32_t idx = seli[(size_t)bl * 1024 + t];
      z[t] = (((uint64_t)u) << 32) | (uint32_t)(~idx);
    } else z[t] = 0ull;
  }
  __syncthreads();
  int tg = chunk * 256 + tid;
  if (tg >= k) return;
  uint64_t zi = z[tg];
  uint32_t u = (uint32_t)(zi >> 32);
  uint32_t idx = ~(uint32_t)zi;
  int rank = 0;
  const uint4* z4 = (const uint4*)z;
  for (int j4 = 0; j4 < 512; j4++) {
    uint4 q = z4[j4];
    uint64_t za = (((uint64_t)q.y) << 32) | q.x;
    uint64_t zb = (((uint64_t)q.w) << 32) | q.z;
    rank += (za > zi) ? 1 : 0;
    rank += (zb > zi) ? 1 : 0;
  }
  constexpr int Wc[5]  = {40, 20, 10, 5, 3};
  constexpr int HWc[5] = {1600, 400, 100, 25, 9};
  constexpr float Sc[5] = {8.f, 16.f, 32.f, 64.f, 128.f};
  constexpr int COFF[5] = {0, 1000, 2000, 3000, 4000};
  int w = Wc[l], hw = HWc[l];
  float ms = s2f(u);
  int valid = (ms > 0.025f) ? 1 : 0;
  int p = (int)idx / NC, c = (int)idx % NC;
  int x = p % w, y = p / w;
  float sf = sigmoid32(in.ctr[l][(size_t)b * hw + p]);
  float score = valid ? __fmul_rn(ms, sf) : -1.0f;
  float px = __fmul_rn(__fadd_rn((float)x, 0.5f), Sc[l]);
  float py = __fmul_rn(__fadd_rn((float)y, 0.5f), Sc[l]);
  size_t bb = (size_t)b * 4 * hw;
  float d0 = in.bbox[l][bb + 0 * hw + p];
  float d1 = in.bbox[l][bb + 1 * hw + p];
  float d2 = in.bbox[l][bb + 2 * hw + p];
  float d3 = in.bbox[l][bb + 3 * hw + p];
  float x1 = clip32(__fsub_rn(px, d0)), y1 = clip32(__fsub_rn(py, d1));
  float x2 = clip32(__fadd_rn(px, d2)), y2 = clip32(__fadd_rn(py, d3));
  int o = b * KTOT + COFF[l] + rank;
  ccs[o] = score;
  ccl[o] = (uint32_t)c;
  ccv[o] = (uint32_t)valid;
  ccb[(size_t)o * 4 + 0] = x1; ccb[(size_t)o * 4 + 1] = y1;
  ccb[(size_t)o * 4 + 2] = x2; ccb[(size_t)o * 4 + 3] = y2;
}

// ---------------- partial ranks vs 256-key j-tiles ----------------
__global__ void k_rank(const float* __restrict__ ccs, uint32_t* __restrict__ rankp) {
  int b = blockIdx.z;
  int jt = blockIdx.y;
  int ib = blockIdx.x;
  int tid = threadIdx.x;
  __shared__ uint32_t jk[256];   // 1 KB
  int j0 = jt * 256;
  int jn = min(256, KTOT - j0);
  jk[tid] = (tid < jn) ? f2s(ccs[(size_t)b * KTOT + j0 + tid]) : 0u;
  __syncthreads();
  int e = ib * 256 + tid;
  if (e >= KTOT) return;
  uint32_t ke = f2s(ccs[(size_t)b * KTOT + e]);
  int rank = 0;
  const uint4* k4 = (const uint4*)jk;
#pragma unroll 8
  for (int q = 0; q < 64; q++) {
    uint4 kk = k4[q];
    int j = j0 + q * 4;
    rank += ((kk.x > ke) || (kk.x == ke && (j + 0) < e)) ? 1 : 0;
    rank += ((kk.y > ke) || (kk.y == ke && (j + 1) < e)) ? 1 : 0;
    rank += ((kk.z > ke) || (kk.z == ke && (j + 2) < e)) ? 1 : 0;
    rank += ((kk.w > ke) || (kk.w == ke && (j + 3) < e)) ? 1 : 0;
  }
  rankp[((size_t)b * NJT + jt) * KTOT + e] = (uint32_t)rank;   // contiguous
}

// ---------------- sum partials + permuted scatter + maxcb ----------------
__global__ void k_scatter(const float* __restrict__ ccs, const uint32_t* __restrict__ ccl,
                          const uint32_t* __restrict__ ccv, const float* __restrict__ ccb,
                          const uint32_t* __restrict__ rankp,
                          float* __restrict__ ss, uint32_t* __restrict__ sl,
                          uint32_t* __restrict__ sv, float* __restrict__ sb,
                          uint32_t* __restrict__ maxcb) {
  int b = blockIdx.y;
  __shared__ float red[4];
  int tid = threadIdx.x;
  int e = blockIdx.x * 256 + tid;
  float mx = 0.0f;
  if (e < KTOT) {
    uint32_t rank = 0;
    for (int jt = 0; jt < NJT; jt++)
      rank += rankp[((size_t)b * NJT + jt) * KTOT + e];   // coalesced
    int sidx = b * KTOT + e;
    int d = b * KTOT + (int)rank;
    ss[d] = ccs[sidx];
    sl[d] = ccl[sidx];
    sv[d] = ccv[sidx];
    float b0 = ccb[(size_t)sidx * 4 + 0], b1 = ccb[(size_t)sidx * 4 + 1];
    float b2 = ccb[(size_t)sidx * 4 + 2], b3 = ccb[(size_t)sidx * 4 + 3];
    sb[(size_t)d * 4 + 0] = b0; sb[(size_t)d * 4 + 1] = b1;
    sb[(size_t)d * 4 + 2] = b2; sb[(size_t)d * 4 + 3] = b3;
    mx = fmaxf(fmaxf(b0, b1), fmaxf(b2, b3));
  }
  for (int o = 32; o; o >>= 1) mx = fmaxf(mx, __shfl_xor(mx, o));
  if ((tid & 63) == 0) red[tid >> 6] = mx;
  __syncthreads();
  if (tid == 0)
    atomicMax(&maxcb[b], __float_as_uint(fmaxf(fmaxf(red[0], red[1]), fmaxf(red[2], red[3]))));
}

// -------- fused per-class offset + valid-bit ballot + class scatter (R20) ------
// grid (19, BN) x 256: wave v of block x covers window x*4+v of image b.
// Also scatters each element into its class member list (UNORDERED — the
// pair set only needs index comparisons, not list order).
__global__ void k_offbits(const float* __restrict__ sb, const uint32_t* __restrict__ sl,
                          const uint32_t* __restrict__ maxcb, const uint32_t* __restrict__ sv,
                          float* __restrict__ ob, unsigned long long* __restrict__ vbits,
                          uint32_t* __restrict__ paircnt,
                          uint32_t* __restrict__ clist, uint32_t* __restrict__ ccount) {
  int b = blockIdx.y;
  int tid = threadIdx.x;
  if (blockIdx.x == 0 && b == 0 && tid < BN) paircnt[tid] = 0u;
  int e = blockIdx.x * 256 + tid;
  int pred = 0;
  if (e < KTOT) {
    int r = b * KTOT + e;
    float scale = __fadd_rn(__uint_as_float(maxcb[b]), 1.0f);
    uint32_t c = sl[r];
    float offv = __fmul_rn((float)c, scale);
    float x1 = __fadd_rn(sb[(size_t)r * 4 + 0], offv);
    float y1 = __fadd_rn(sb[(size_t)r * 4 + 1], offv);
    float x2 = __fadd_rn(sb[(size_t)r * 4 + 2], offv);
    float y2 = __fadd_rn(sb[(size_t)r * 4 + 3], offv);
    ob[(size_t)r * 4 + 0] = x1; ob[(size_t)r * 4 + 1] = y1;
    ob[(size_t)r * 4 + 2] = x2; ob[(size_t)r * 4 + 3] = y2;
    pred = (sv[r] != 0u);
    uint32_t pos = atomicAdd(&ccount[b * NC + c], 1u);
    clist[((size_t)b * NC + c) * KTOT + pos] = (uint32_t)e;
  }
  unsigned long long m = __ballot(pred);
  int w = blockIdx.x * 4 + (tid >> 6);
  if ((tid & 63) == 0 && w < NWIN) vbits[b * NWIN + w] = m;
}

// -------- per-class pairwise IoU -> pairs, single pass + LDS staging (R20) -----
__global__ void k_pairs(const uint32_t* __restrict__ clist, const uint32_t* __restrict__ ccount,
                        const float* __restrict__ ob,
                        uint32_t* __restrict__ pairs, uint32_t* __restrict__ paircnt) {
  int b = blockIdx.y;
  int c = blockIdx.x;
  int m = (int)ccount[b * NC + c];
  if (m < 2) return;
  int tid = threadIdx.x;
  const uint32_t* cl = clist + ((size_t)b * NC + c) * KTOT;
  const float4* ob4 = (const float4*)ob + (size_t)b * KTOT;
  __shared__ uint32_t lst[KTOT];    // 18.9 KB — member indices (unordered)
  __shared__ uint32_t spc[SPC_CAP]; // 16 KB — staged pairs
  __shared__ float4 tb[256];        // 4 KB
  __shared__ uint32_t jidx[256];
  __shared__ uint32_t scnt, sbase;
  for (int t = tid; t < m; t += 256) lst[t] = cl[t];
  if (tid == 0) scnt = 0u;
  // single IoU pass, staging pairs in LDS
  for (int jt = 0; jt < m; jt += 256) {
    int jn = min(256, m - jt);
    __syncthreads();
    if (tid < jn) { uint32_t gj = lst[jt + tid]; jidx[tid] = gj; tb[tid] = ob4[gj]; }
    __syncthreads();
    for (int i = tid; i < m; i += 256) {
      uint32_t gi = lst[i];
      float4 v = ob4[gi];
      float bai = __fmul_rn(__fsub_rn(v.z, v.x), __fsub_rn(v.w, v.y));
      for (int jj = 0; jj < jn; jj++) {
        uint32_t gj = jidx[jj];
        if (gj > gi && iou_gt(v.x, v.y, v.z, v.w, bai, tb[jj])) {
          uint32_t pos = atomicAdd(&scnt, 1u);
          if (pos < SPC_CAP) spc[pos] = (gi << 13) | gj;
        }
      }
    }
  }
  __syncthreads();
  uint32_t total = scnt;
  if (total == 0u) return;
  if (tid == 0) sbase = atomicAdd(&paircnt[b], total);
  __syncthreads();
  uint32_t gb = sbase;
  uint32_t* gp = pairs + (size_t)b * PAIR_CAP;
  if (total <= (uint32_t)SPC_CAP) {
    for (uint32_t t = tid; t < total; t += 256)
      if (gb + t < PAIR_CAP) gp[gb + t] = spc[t];
  } else {
    // rare overflow: re-emit ALL pairs into the reserved range [gb, gb+total)
    if (tid == 0) scnt = 0u;
    for (int jt = 0; jt < m; jt += 256) {
      int jn = min(256, m - jt);
      __syncthreads();
      if (tid < jn) { uint32_t gj = lst[jt + tid]; jidx[tid] = gj; tb[tid] = ob4[gj]; }
      __syncthreads();
      for (int i = tid; i < m; i += 256) {
        uint32_t gi = lst[i];
        float4 v = ob4[gi];
        float bai = __fmul_rn(__fsub_rn(v.z, v.x), __fsub_rn(v.w, v.y));
        for (int jj = 0; jj < jn; jj++) {
          uint32_t gj = jidx[jj];
          if (gj > gi && iou_gt(v.x, v.y, v.z, v.w, bai, tb[jj])) {
            uint32_t pos = gb + atomicAdd(&scnt, 1u);
            if (pos < PAIR_CAP) gp[pos] = (gi << 13) | gj;
          }
        }
      }
    }
  }
}

// ---------- single-wave barrier-free sparse-pair greedy NMS (R19) --------------
__global__ void k_nms(const float* __restrict__ ob,
                      const unsigned long long* __restrict__ vbits,
                      unsigned long long* __restrict__ keepw,
                      const uint32_t* __restrict__ pairs,
                      const uint32_t* __restrict__ paircnt) {
  int b = blockIdx.x;
  int tid = threadIdx.x;
  int lane = tid & 63;
  __shared__ unsigned long long tdl[NWIN * 64];   // within-window rows; 37888 B
  __shared__ unsigned long long svl[NWIN];
  __shared__ unsigned long long sup[NWIN];
  __shared__ unsigned long long kwsh;
  __shared__ uint32_t plp[LDSP];                  // window-sorted pairs; 49152 B
  __shared__ uint32_t wstart[NWIN + 1];
  __shared__ uint32_t wtmp[NWIN];
  for (int i = tid; i < NWIN * 64; i += 256) tdl[i] = 0ull;
  if (tid < NWIN) { svl[tid] = vbits[b * NWIN + tid]; sup[tid] = 0ull; wtmp[tid] = 0u; }
  uint32_t npairs = paircnt[b];
  bool useP = (npairs <= (uint32_t)PAIR_CAP);
  bool useL = (npairs <= (uint32_t)LDSP);
  const uint32_t* gpl = pairs + (size_t)b * PAIR_CAP;
  __syncthreads();
  unsigned int* sup32 = (unsigned int*)sup;
  unsigned int* tdl32 = (unsigned int*)tdl;
  if (useP) {
    // setup with all 256 threads: tdl rows + cross-window bucket counts
    for (uint32_t t = tid; t < npairs; t += 256) {
      uint32_t p = gpl[t];
      int i = (int)(p >> 13), j = (int)(p & 8191u);
      if ((i >> 6) == (j >> 6)) {
        int r = ((i >> 6) * 64 + (i & 63)) * 2 + ((j & 63) >> 5);
        atomicOr(&tdl32[r], 1u << (j & 31));
      } else {
        atomicAdd(&wtmp[i >> 6], 1u);
      }
    }
    __syncthreads();
    if (tid == 0) {
      uint32_t acc = 0;
      for (int w = 0; w < NWIN; w++) { wstart[w] = acc; acc += wtmp[w]; }
      wstart[NWIN] = acc;
    }
    __syncthreads();
    if (tid < NWIN) wtmp[tid] = 0u;
    __syncthreads();
    if (useL) {
      for (uint32_t t = tid; t < npairs; t += 256) {
        uint32_t p = gpl[t];
        int i = (int)(p >> 13), j = (int)(p & 8191u);
        if ((i >> 6) == (j >> 6)) continue;
        uint32_t w = (uint32_t)(i >> 6);
        uint32_t pos = wstart[w] + atomicAdd(&wtmp[w], 1u);
        plp[pos] = p;
      }
    }
    __syncthreads();
    // main loop: single wave, no block barriers. DS ops from one wave
    // complete in program order; fence per window as belt-and-braces.
    if (tid < 64) {
      for (int w = 0; w < NWIN; w++) {
        unsigned long long row = tdl[w * 64 + lane];
        unsigned long long m = __ballot(row != 0ull);
        unsigned long long sa = sup[w];
        unsigned long long sval = svl[w];
        unsigned int rlo = (unsigned int)row, rhi = (unsigned int)(row >> 32);
        while (m) {
          int i = __ffsll((long long)m) - 1;
          m &= m - 1;
          if (((sval >> i) & 1ull) && !((sa >> i) & 1ull)) {
            unsigned int lo = (unsigned int)__builtin_amdgcn_readlane((int)rlo, i);
            unsigned int hi = (unsigned int)__builtin_amdgcn_readlane((int)rhi, i);
            sa |= (((unsigned long long)hi) << 32) | (unsigned long long)lo;
          }
        }
        unsigned long long kw = sval & ~sa;     // identical in all 64 lanes
        if (lane == 0) keepw[b * NWIN + w] = kw;
        if (useL) {
          for (uint32_t t = wstart[w] + lane; t < wstart[w + 1]; t += 64) {
            uint32_t p = plp[t];
            int i = (int)(p >> 13);
            if (!((kw >> (i & 63)) & 1ull)) continue;
            int j = (int)(p & 8191u);
            atomicOr(&sup32[j >> 5], 1u << (j & 31));
          }
        } else {
          for (uint32_t t = lane; t < npairs; t += 64) {
            uint32_t p = gpl[t];
            int i = (int)(p >> 13);
            if ((i >> 6) != w) continue;
            int j = (int)(p & 8191u);
            if ((j >> 6) == w) continue;   // same-window handled via tdl
            if (!((kw >> (i & 63)) & 1ull)) continue;
            atomicOr(&sup32[j >> 5], 1u << (j & 31));
          }
        }
        __threadfence_block();
      }
    }
  } else {
    // -------- overflow fallback: recompute IoU from ob (rare/never) --------
    int wv = tid >> 6;
    const float4* ob4 = (const float4*)ob + (size_t)b * KTOT;
    for (int w = 0; w < NWIN; w++) {
      if (wv == 0) {
        int i = w * 64 + lane;
        unsigned long long row = 0ull;
        if (i < KTOT) {
          float4 v = ob4[i];
          float bai = __fmul_rn(__fsub_rn(v.z, v.x), __fsub_rn(v.w, v.y));
          for (int jj = 0; jj < 64; jj++) {
            int j = w * 64 + jj;
            if (j > i && j < KTOT)
              row |= ((unsigned long long)iou_gt(v.x, v.y, v.z, v.w, bai, ob4[j])) << jj;
          }
        }
        unsigned long long m = __ballot(row != 0ull);
        unsigned long long sa = sup[w];
        unsigned long long sval = svl[w];
        unsigned int rlo = (unsigned int)row, rhi = (unsigned int)(row >> 32);
        while (m) {
          int i2 = __ffsll((long long)m) - 1;
          m &= m - 1;
          if (((sval >> i2) & 1ull) && !((sa >> i2) & 1ull)) {
            unsigned int lo = (unsigned int)__builtin_amdgcn_readlane((int)rlo, i2);
            unsigned int hi = (unsigned int)__builtin_amdgcn_readlane((int)rhi, i2);
            sa |= (((unsigned long long)hi) << 32) | (unsigned long long)lo;
          }
        }
        unsigned long long kw = sval & ~sa;
        if (lane == 0) { keepw[b * NWIN + w] = kw; kwsh = kw; }
      }
      __syncthreads();
      unsigned long long kw = kwsh;
      for (int ii = 0; ii < 64; ii++) {
        if (!((kw >> ii) & 1ull)) continue;
        int i = w * 64 + ii;
        if (i >= KTOT) break;
        float4 v = ob4[i];
        float bai = __fmul_rn(__fsub_rn(v.z, v.x), __fsub_rn(v.w, v.y));
        for (int j = (w + 1) * 64 + tid; j < KTOT; j += 256)
          if (iou_gt(v.x, v.y, v.z, v.w, bai, ob4[j]))
            atomicOr(&sup32[j >> 5], 1u << (j & 31));
      }
      __syncthreads();
    }
  }
}

// ---------------- final outputs ----------------
__global__ void k_out(const float* __restrict__ ss, const uint32_t* __restrict__ sl,
                      const float* __restrict__ sb, const unsigned long long* __restrict__ keepw,
                      float* __restrict__ out) {
  int r = blockIdx.x * blockDim.x + threadIdx.x;
  if (r >= BN * KTOT) return;
  int b = r / KTOT;
  int e = r - b * KTOT;
  unsigned int kp = (unsigned int)((keepw[b * NWIN + (e >> 6)] >> (e & 63)) & 1ull);
  out[(size_t)r * 5 + 0] = sb[(size_t)r * 4 + 0];
  out[(size_t)r * 5 + 1] = sb[(size_t)r * 4 + 1];
  out[(size_t)r * 5 + 2] = sb[(size_t)r * 4 + 2];
  out[(size_t)r * 5 + 3] = sb[(size_t)r * 4 + 3];
  out[(size_t)r * 5 + 4] = ss[r];
  out[(size_t)BN * KTOT * 5 + r] = (float)sl[r];
  out[(size_t)BN * KTOT * 6 + r] = kp ? 1.0f : 0.0f;
}

extern "C" void kernel_launch(void* const* d_in, const int* in_sizes, int n_in,
                              void* d_out, int out_size, void* d_ws, size_t ws_size,
                              hipStream_t stream) {
  InPtrs ip;
  for (int l = 0; l < 5; l++) {
    ip.cls[l]  = (const float*)d_in[3 * l + 0];
    ip.bbox[l] = (const float*)d_in[3 * l + 1];
    ip.ctr[l]  = (const float*)d_in[3 * l + 2];
  }

  size_t off = 0;
  auto alloc = [&](size_t n) {
    char* p = (char*)d_ws + off;
    off = (off + n + 255) & ~(size_t)255;
    return p;
  };
  const size_t SU_BYTES   = (size_t)BN * TOT * 4;                  // 2.73 MB
  const size_t HIST_BYTES = (20ull * 1024 + 20ull * 1024 + 20ull * 4096) * 4; // 480 KB
  const size_t EXTRA      = 2048;    // selcnt/tiecnt/maxcb/ccount (zeroed w/ hists)
  char* r0p = (char*)alloc(((SU_BYTES + 255) & ~(size_t)255) + HIST_BYTES + EXTRA);
  uint32_t* su    = (uint32_t*)r0p;
  uint32_t* hist0 = (uint32_t*)(r0p + ((SU_BYTES + 255) & ~(size_t)255));
  uint32_t* hist1 = hist0 + 20ull * 1024;
  uint32_t* hist2 = hist1 + 20ull * 1024;
  uint32_t* selcnt = hist2 + 20ull * 4096;
  uint32_t* tiecnt = selcnt + 20;
  uint32_t* maxcb  = tiecnt + 20;
  uint32_t* ccount = maxcb + BN;      // BN*NC = 320 u32, inside EXTRA

  uint32_t* mpfx   = (uint32_t*)alloc(20 * 4);
  uint32_t* mk     = (uint32_t*)alloc(20 * 4);
  uint32_t* selu   = (uint32_t*)alloc(20ull * 1024 * 4);
  uint32_t* seli   = (uint32_t*)alloc(20ull * 1024 * 4);
  uint32_t* tiei   = (uint32_t*)alloc(20ull * TIE_CAP * 4);
  float*    ccs    = (float*)   alloc((size_t)BN * KTOT * 4);
  uint32_t* ccl    = (uint32_t*)alloc((size_t)BN * KTOT * 4);
  uint32_t* ccv    = (uint32_t*)alloc((size_t)BN * KTOT * 4);
  float*    ccb    = (float*)   alloc((size_t)BN * KTOT * 16);
  float*    ss     = (float*)   alloc((size_t)BN * KTOT * 4);
  uint32_t* sl     = (uint32_t*)alloc((size_t)BN * KTOT * 4);
  uint32_t* sv     = (uint32_t*)alloc((size_t)BN * KTOT * 4);
  float*    sb     = (float*)   alloc((size_t)BN * KTOT * 16);
  float*    ob     = (float*)   alloc((size_t)BN * KTOT * 16);
  uint32_t* rankp  = (uint32_t*)alloc((size_t)BN * NJT * KTOT * 4); // 1.43 MB
  uint32_t* clist  = (uint32_t*)alloc((size_t)BN * NC * KTOT * 4);  // 6.04 MB
  unsigned long long* vbits = (unsigned long long*)alloc((size_t)BN * NWIN * 8);
  unsigned long long* keepw = (unsigned long long*)alloc((size_t)BN * NWIN * 8);
  uint32_t* pairs   = (uint32_t*)alloc((size_t)BN * PAIR_CAP * 4);  // 2 MB
  uint32_t* paircnt = (uint32_t*)alloc(BN * 4);
  (void)ws_size; (void)in_sizes; (void)n_in; (void)out_size;

  dim3 gscan((TOT + 255) / 256, BN);
  hipMemsetAsync(hist0, 0, HIST_BYTES + EXTRA, stream);   // hists + counters + ccount
  k_score<<<dim3(36, BN), 256, 0, stream>>>(ip, su, hist0);
  k_findp<<<20, 256, 0, stream>>>(hist0, mpfx, mk, 1024, 22, 0);
  k_scan1<<<gscan, 256, 0, stream>>>(su, mpfx, hist1);
  k_findp<<<20, 256, 0, stream>>>(hist1, mpfx, mk, 1024, 12, 1);
  k_scan2<<<gscan, 256, 0, stream>>>(su, mpfx, hist2);
  k_findp<<<20, 256, 0, stream>>>(hist2, mpfx, mk, 4096, 0, 2);
  k_compact<<<gscan, 256, 0, stream>>>(su, mpfx, selcnt, tiecnt, selu, seli, tiei);
  k_ties<<<20, 256, 0, stream>>>(mpfx, mk, tiecnt, tiei, selu, seli);
  k_emit<<<dim3(20, 4), 256, 0, stream>>>(ip, selu, seli, ccs, ccl, ccv, ccb);
  k_rank<<<dim3(19, NJT, BN), 256, 0, stream>>>(ccs, rankp);
  k_scatter<<<dim3(19, BN), 256, 0, stream>>>(ccs, ccl, ccv, ccb, rankp, ss, sl, sv, sb, maxcb);
  k_offbits<<<dim3(19, BN), 256, 0, stream>>>(sb, sl, maxcb, sv, ob, vbits, paircnt, clist, ccount);
  k_pairs<<<dim3(NC, BN), 256, 0, stream>>>(clist, ccount, ob, pairs, paircnt);
  k_nms<<<BN, 256, 0, stream>>>(ob, vbits, keepw, pairs, paircnt);
  k_out<<<(BN * KTOT + 255) / 256, 256, 0, stream>>>(ss, sl, sb, keepw, (float*)d_out);
}

// Round 10
// 238.706 us; speedup vs baseline: 3.6399x; 1.0092x over previous
//
#include <hip/hip_runtime.h>
#include <stdint.h>

// FCOS bbox post-processing, B=4 images — bit-exact np/XLA-f32 replication
// (R7 semantics). R16: radix selection. R17: 2D rank. R18: class-bucketed IoU.
// R19: 1-wave NMS. R20: unordered class lists, single-pass pairs.
// R21:
//  - radix pass 2 DELETED: k_emit re-ranks by full (u,~idx), so only the
//    selected SET matters. 20-bit prefix split is exact: u20>C20 ⇒ u>u' for
//    any boundary u', and #{u20>C20} = kl - mk1. k_compact selects on u>>12;
//    k_ties picks best mk1 boundary candidates by exact (u desc, idx asc).
//  - k_out fused into k_nms (keep bits stay in LDS; keepw buffer deleted).
//  Dispatches 16 -> 13; one full-TOT scan removed.

#define BN 4
#define NC 80
#define TOT 170720       // 128000+32000+8000+2000+720
#define KTOT 4720        // 1000*4+720
#define NWIN 74          // ceil(4720/64)
#define NJT 19           // rank j-tiles
#define TIE_CAP 4096
#define IMGSZ 320.0f
#define PAIR_CAP 131072  // pairs per image (global)
#define LDSP 12288       // pairs staged in LDS (k_nms)
#define SPC_CAP 4096     // pairs staged in LDS (k_pairs)

struct InPtrs {
  const float* cls[5];
  const float* bbox[5];
  const float* ctr[5];
};

__device__ __forceinline__ uint32_t f2s(float f) {
  uint32_t x = __float_as_uint(f);
  return (x & 0x80000000u) ? ~x : (x | 0x80000000u);
}
__device__ __forceinline__ float s2f(uint32_t s) {
  uint32_t x = (s & 0x80000000u) ? (s & 0x7fffffffu) : ~s;
  return __uint_as_float(x);
}
// np/XLA logistic: 1/(1+exp(-x)) with per-op f32 rounding.
__device__ __forceinline__ float sigmoid32(float v) {
  float e = (float)exp(-(double)v);          // CR f32 exp(-v)
  return __fdiv_rn(1.0f, __fadd_rn(1.0f, e));
}
__device__ __forceinline__ void lvl_of(int e, int& l, int& le) {
  if (e < 128000)      { l = 0; le = e; }
  else if (e < 160000) { l = 1; le = e - 128000; }
  else if (e < 168000) { l = 2; le = e - 160000; }
  else if (e < 170000) { l = 3; le = e - 168000; }
  else                 { l = 4; le = e - 170000; }
}
__device__ __forceinline__ int kl_of(int l) {
  constexpr int KL[5] = {1000, 1000, 1000, 1000, 720};
  return KL[l];
}
__device__ __forceinline__ float clip32(float v) {
  return fminf(fmaxf(v, 0.0f), IMGSZ);
}
// tile table for k_score: 36 tiles/image of (<=64 p) x (80 c)
__device__ __forceinline__ void tile_of(int t, int& l, int& p0) {
  if (t < 25)       { l = 0; p0 = t * 64; }
  else if (t < 32)  { l = 1; p0 = (t - 25) * 64; }
  else if (t < 34)  { l = 2; p0 = (t - 32) * 64; }
  else if (t == 34) { l = 3; p0 = 0; }
  else              { l = 4; p0 = 0; }
}
// IoU > 0.5 predicate, exact np f32 op chain (identical to R7-R20).
__device__ __forceinline__ int iou_gt(float bx1, float by1, float bx2, float by2,
                                      float bai, float4 o) {
  float ta_ = __fmul_rn(__fsub_rn(o.z, o.x), __fsub_rn(o.w, o.y));
  float ltx = fmaxf(bx1, o.x), lty = fmaxf(by1, o.y);
  float rbx = fminf(bx2, o.z), rby = fminf(by2, o.w);
  float wd = fmaxf(__fsub_rn(rbx, ltx), 0.0f);
  float hg = fmaxf(__fsub_rn(rby, lty), 0.0f);
  float inter = __fmul_rn(wd, hg);
  float asum = __fadd_rn(bai, ta_);
  float uni  = __fsub_rn(asum, inter);
  float iou  = (uni > 0.0f) ? __fdiv_rn(inter, uni) : 0.0f;
  return (iou > 0.5f) ? 1 : 0;
}

// ---------------- scores -> sortable u32 keys + pass-0 LDS histogram -----------
__global__ void k_score(InPtrs in, uint32_t* __restrict__ su, uint32_t* __restrict__ hist0) {
  int b = blockIdx.y;
  int tl, p0; tile_of(blockIdx.x, tl, p0);
  constexpr int HWc[5]  = {1600, 400, 100, 25, 9};
  constexpr int LOFF[5] = {0, 128000, 160000, 168000, 170000};
  int hw = HWc[tl];
  int tw = min(64, hw - p0);
  int tid = threadIdx.x;
  __shared__ uint32_t lu[64 * 81];   // padded transpose tile (20.7 KB)
  __shared__ uint32_t lh[1024];      // pass-0 hist (4 KB)
  for (int i = tid; i < 1024; i += 256) lh[i] = 0;
  __syncthreads();
  int pf = tid & 63;
  if (pf < tw) {
    const float* cp = in.cls[tl] + (size_t)b * NC * hw + p0 + pf;
    for (int c = tid >> 6; c < NC; c += 4) {
      float v = cp[(size_t)c * hw];                 // coalesced (64-lane run)
      float s = sigmoid32(v);
      float m = (s > 0.025f) ? s : -1.0f;
      uint32_t u = f2s(m);
      lu[pf * 81 + c] = u;
      atomicAdd(&lh[u >> 22], 1u);                  // LDS atomic
    }
  }
  __syncthreads();
  int bl = b * 5 + tl;
  for (int i = tid; i < 1024; i += 256)
    if (lh[i]) atomicAdd(&hist0[(size_t)bl * 1024 + i], lh[i]);
  int n = tw * NC;
  uint32_t* dst = su + (size_t)b * TOT + LOFF[tl] + p0 * NC;
  for (int idx = tid; idx < n; idx += 256)
    dst[idx] = lu[(idx / 80) * 81 + (idx % 80)];    // contiguous store
}

// ---------------- radix pass 1: bits 21-12 of top-10 matches (LDS) -------------
__global__ void k_scan1(const uint32_t* __restrict__ su, const uint32_t* __restrict__ mpfx,
                        uint32_t* __restrict__ hist1) {
  int b = blockIdx.y;
  int tid = threadIdx.x;
  int e0 = blockIdx.x * 256;
  int e = e0 + tid;
  int l0, le0; lvl_of(e0, l0, le0);
  __shared__ uint32_t lh[2][1024];   // two slots: block may span 2 levels
  for (int i = tid; i < 2048; i += 256) lh[i >> 10][i & 1023] = 0;
  __syncthreads();
  if (e < TOT) {
    int l, le; lvl_of(e, l, le);
    uint32_t C = mpfx[b * 5 + l];
    uint32_t u = su[(size_t)b * TOT + e];
    if ((u >> 22) == (C >> 22)) atomicAdd(&lh[l - l0][(u >> 12) & 1023u], 1u);
  }
  __syncthreads();
  for (int s = 0; s < 2; s++) {
    int l = l0 + s;
    if (l >= 5) break;
    int bl = b * 5 + l;
    for (int i = tid; i < 1024; i += 256)
      if (lh[s][i]) atomicAdd(&hist1[(size_t)bl * 1024 + i], lh[s][i]);
  }
}

// ---------------- generic digit select (suffix-count crossing) -----------------
__global__ void k_findp(const uint32_t* __restrict__ hist, uint32_t* __restrict__ mpfx,
                        uint32_t* __restrict__ mk, int nbins, int shift, int pass) {
  int bl = blockIdx.x;
  uint32_t k = (pass == 0) ? (uint32_t)kl_of(bl % 5) : mk[bl];
  const uint32_t* h = hist + (size_t)bl * nbins;
  __shared__ uint32_t gsum[256];
  int tid = threadIdx.x;
  int per = nbins / 256;             // 4
  int base = tid * per;
  uint32_t s = 0;
  for (int i = 0; i < per; i++) s += h[base + i];
  gsum[tid] = s;
  __syncthreads();
  uint32_t above = 0;
  for (int t = tid + 1; t < 256; t++) above += gsum[t];
  if (above < k && above + s >= k) {
    uint32_t cum = above;
    for (int bin = base + per - 1; bin >= base; bin--) {
      uint32_t c = h[bin];
      if (cum < k && cum + c >= k) {
        uint32_t pfx = (pass == 0) ? 0u : mpfx[bl];
        mpfx[bl] = pfx | ((uint32_t)bin << shift);
        mk[bl] = k - cum;
        break;
      }
      cum += c;
    }
  }
}

// ------ compact selected on 20-bit prefix (R21) + gather boundary candidates ---
// u20 > C20  => certainly in top-kl (prefix-greater => value-greater).
// u20 == C20 => boundary candidate (expected ~30-100); k_ties picks best mk1.
__global__ void k_compact(const uint32_t* __restrict__ su, const uint32_t* __restrict__ mpfx,
                          uint32_t* __restrict__ selcnt, uint32_t* __restrict__ tiecnt,
                          uint32_t* __restrict__ selu, uint32_t* __restrict__ seli,
                          uint32_t* __restrict__ tiei, uint32_t* __restrict__ tieu) {
  int b = blockIdx.y;
  int tid = threadIdx.x;
  int e0 = blockIdx.x * 256;
  int e = e0 + tid;
  int l0, le0; lvl_of(e0, l0, le0);
  __shared__ uint32_t cnt[2], tcnt[2], gbase[2], tgbase[2];
  __shared__ uint32_t su_s[2][256], si_s[2][256];   // staged selected (u, le)
  __shared__ uint32_t ti_s[2][256], tu_s[2][256];   // staged tie (le, u)
  if (tid < 2) { cnt[tid] = 0u; tcnt[tid] = 0u; }
  __syncthreads();
  if (e < TOT) {
    int l, le; lvl_of(e, l, le);
    int slot = l - l0;          // 0 or 1
    int bl = b * 5 + l;
    uint32_t u = su[(size_t)b * TOT + e];
    uint32_t C20 = mpfx[bl] >> 12;
    uint32_t u20 = u >> 12;
    if (u20 > C20) {
      uint32_t p = atomicAdd(&cnt[slot], 1u);
      su_s[slot][p] = u;
      si_s[slot][p] = (uint32_t)le;
    } else if (u20 == C20) {
      uint32_t p = atomicAdd(&tcnt[slot], 1u);
      ti_s[slot][p] = (uint32_t)le;
      tu_s[slot][p] = u;
    }
  }
  __syncthreads();
  if (tid < 2) {
    int bl = b * 5 + l0 + tid;
    if (cnt[tid])  gbase[tid]  = atomicAdd(&selcnt[bl], cnt[tid]);
    if (tcnt[tid]) tgbase[tid] = atomicAdd(&tiecnt[bl], tcnt[tid]);
  }
  __syncthreads();
  for (int s = 0; s < 2; s++) {
    int bl = b * 5 + l0 + s;
    uint32_t n = cnt[s];
    for (uint32_t t = tid; t < n; t += 256) {
      uint32_t pos = gbase[s] + t;
      selu[(size_t)bl * 1024 + pos] = su_s[s][t];
      seli[(size_t)bl * 1024 + pos] = si_s[s][t];
    }
    uint32_t tn = tcnt[s];
    for (uint32_t t = tid; t < tn; t += 256) {
      uint32_t pos = tgbase[s] + t;
      if (pos < TIE_CAP) {
        tiei[(size_t)bl * TIE_CAP + pos] = ti_s[s][t];
        tieu[(size_t)bl * TIE_CAP + pos] = tu_s[s][t];
      }
    }
  }
}

// Boundary: pick best T=mk1 candidates by exact (u desc, idx asc) ranking (R21).
__global__ void k_ties(const uint32_t* __restrict__ mk,
                       const uint32_t* __restrict__ tiecnt, const uint32_t* __restrict__ tiei,
                       const uint32_t* __restrict__ tieu,
                       uint32_t* __restrict__ selu, uint32_t* __restrict__ seli) {
  int bl = blockIdx.x;
  int l = bl % 5;
  uint32_t T = mk[bl];
  uint32_t G = (uint32_t)kl_of(l) - T;
  uint32_t Tc = tiecnt[bl];
  if (Tc > TIE_CAP) Tc = TIE_CAP;
  __shared__ uint32_t shi[TIE_CAP];   // 16 KB
  __shared__ uint32_t shu[TIE_CAP];   // 16 KB
  for (uint32_t t = threadIdx.x; t < Tc; t += blockDim.x) {
    shi[t] = tiei[(size_t)bl * TIE_CAP + t];
    shu[t] = tieu[(size_t)bl * TIE_CAP + t];
  }
  __syncthreads();
  for (uint32_t t = threadIdx.x; t < Tc; t += blockDim.x) {
    uint32_t mu = shu[t], mi = shi[t];
    uint32_t rank = 0;
    for (uint32_t q = 0; q < Tc; q++)
      rank += ((shu[q] > mu) || (shu[q] == mu && shi[q] < mi)) ? 1u : 0u;
    if (rank < T) {
      selu[(size_t)bl * 1024 + G + rank] = mu;
      seli[(size_t)bl * 1024 + G + rank] = mi;
    }
  }
}

// ---------------- exact rank within level + emit (packed u64 keys) --------------
__global__ void k_emit(InPtrs in, const uint32_t* __restrict__ selu, const uint32_t* __restrict__ seli,
                       float* __restrict__ ccs, uint32_t* __restrict__ ccl,
                       uint32_t* __restrict__ ccv, float* __restrict__ ccb) {
  int bl = blockIdx.x;
  int chunk = blockIdx.y;
  int b = bl / 5, l = bl % 5;
  int k = kl_of(l);
  __shared__ uint64_t z[1024];   // 8 KB
  int tid = threadIdx.x;
  for (int t = tid; t < 1024; t += 256) {
    if (t < k) {
      uint32_t u = selu[(size_t)bl * 1024 + t];
      uint32_t idx = seli[(size_t)bl * 1024 + t];
      z[t] = (((uint64_t)u) << 32) | (uint32_t)(~idx);
    } else z[t] = 0ull;
  }
  __syncthreads();
  int tg = chunk * 256 + tid;
  if (tg >= k) return;
  uint64_t zi = z[tg];
  uint32_t u = (uint32_t)(zi >> 32);
  uint32_t idx = ~(uint32_t)zi;
  int rank = 0;
  const uint4* z4 = (const uint4*)z;
  for (int j4 = 0; j4 < 512; j4++) {
    uint4 q = z4[j4];
    uint64_t za = (((uint64_t)q.y) << 32) | q.x;
    uint64_t zb = (((uint64_t)q.w) << 32) | q.z;
    rank += (za > zi) ? 1 : 0;
    rank += (zb > zi) ? 1 : 0;
  }
  constexpr int Wc[5]  = {40, 20, 10, 5, 3};
  constexpr int HWc[5] = {1600, 400, 100, 25, 9};
  constexpr float Sc[5] = {8.f, 16.f, 32.f, 64.f, 128.f};
  constexpr int COFF[5] = {0, 1000, 2000, 3000, 4000};
  int w = Wc[l], hw = HWc[l];
  float ms = s2f(u);
  int valid = (ms > 0.025f) ? 1 : 0;
  int p = (int)idx / NC, c = (int)idx % NC;
  int x = p % w, y = p / w;
  float sf = sigmoid32(in.ctr[l][(size_t)b * hw + p]);
  float score = valid ? __fmul_rn(ms, sf) : -1.0f;
  float px = __fmul_rn(__fadd_rn((float)x, 0.5f), Sc[l]);
  float py = __fmul_rn(__fadd_rn((float)y, 0.5f), Sc[l]);
  size_t bb = (size_t)b * 4 * hw;
  float d0 = in.bbox[l][bb + 0 * hw + p];
  float d1 = in.bbox[l][bb + 1 * hw + p];
  float d2 = in.bbox[l][bb + 2 * hw + p];
  float d3 = in.bbox[l][bb + 3 * hw + p];
  float x1 = clip32(__fsub_rn(px, d0)), y1 = clip32(__fsub_rn(py, d1));
  float x2 = clip32(__fadd_rn(px, d2)), y2 = clip32(__fadd_rn(py, d3));
  int o = b * KTOT + COFF[l] + rank;
  ccs[o] = score;
  ccl[o] = (uint32_t)c;
  ccv[o] = (uint32_t)valid;
  ccb[(size_t)o * 4 + 0] = x1; ccb[(size_t)o * 4 + 1] = y1;
  ccb[(size_t)o * 4 + 2] = x2; ccb[(size_t)o * 4 + 3] = y2;
}

// ---------------- partial ranks vs 256-key j-tiles ----------------
__global__ void k_rank(const float* __restrict__ ccs, uint32_t* __restrict__ rankp) {
  int b = blockIdx.z;
  int jt = blockIdx.y;
  int ib = blockIdx.x;
  int tid = threadIdx.x;
  __shared__ uint32_t jk[256];   // 1 KB
  int j0 = jt * 256;
  int jn = min(256, KTOT - j0);
  jk[tid] = (tid < jn) ? f2s(ccs[(size_t)b * KTOT + j0 + tid]) : 0u;
  __syncthreads();
  int e = ib * 256 + tid;
  if (e >= KTOT) return;
  uint32_t ke = f2s(ccs[(size_t)b * KTOT + e]);
  int rank = 0;
  const uint4* k4 = (const uint4*)jk;
#pragma unroll 8
  for (int q = 0; q < 64; q++) {
    uint4 kk = k4[q];
    int j = j0 + q * 4;
    rank += ((kk.x > ke) || (kk.x == ke && (j + 0) < e)) ? 1 : 0;
    rank += ((kk.y > ke) || (kk.y == ke && (j + 1) < e)) ? 1 : 0;
    rank += ((kk.z > ke) || (kk.z == ke && (j + 2) < e)) ? 1 : 0;
    rank += ((kk.w > ke) || (kk.w == ke && (j + 3) < e)) ? 1 : 0;
  }
  rankp[((size_t)b * NJT + jt) * KTOT + e] = (uint32_t)rank;   // contiguous
}

// ---------------- sum partials + permuted scatter + maxcb ----------------
__global__ void k_scatter(const float* __restrict__ ccs, const uint32_t* __restrict__ ccl,
                          const uint32_t* __restrict__ ccv, const float* __restrict__ ccb,
                          const uint32_t* __restrict__ rankp,
                          float* __restrict__ ss, uint32_t* __restrict__ sl,
                          uint32_t* __restrict__ sv, float* __restrict__ sb,
                          uint32_t* __restrict__ maxcb) {
  int b = blockIdx.y;
  __shared__ float red[4];
  int tid = threadIdx.x;
  int e = blockIdx.x * 256 + tid;
  float mx = 0.0f;
  if (e < KTOT) {
    uint32_t rank = 0;
    for (int jt = 0; jt < NJT; jt++)
      rank += rankp[((size_t)b * NJT + jt) * KTOT + e];   // coalesced
    int sidx = b * KTOT + e;
    int d = b * KTOT + (int)rank;
    ss[d] = ccs[sidx];
    sl[d] = ccl[sidx];
    sv[d] = ccv[sidx];
    float b0 = ccb[(size_t)sidx * 4 + 0], b1 = ccb[(size_t)sidx * 4 + 1];
    float b2 = ccb[(size_t)sidx * 4 + 2], b3 = ccb[(size_t)sidx * 4 + 3];
    sb[(size_t)d * 4 + 0] = b0; sb[(size_t)d * 4 + 1] = b1;
    sb[(size_t)d * 4 + 2] = b2; sb[(size_t)d * 4 + 3] = b3;
    mx = fmaxf(fmaxf(b0, b1), fmaxf(b2, b3));
  }
  for (int o = 32; o; o >>= 1) mx = fmaxf(mx, __shfl_xor(mx, o));
  if ((tid & 63) == 0) red[tid >> 6] = mx;
  __syncthreads();
  if (tid == 0)
    atomicMax(&maxcb[b], __float_as_uint(fmaxf(fmaxf(red[0], red[1]), fmaxf(red[2], red[3]))));
}

// -------- fused per-class offset + valid-bit ballot + class scatter (R20) ------
__global__ void k_offbits(const float* __restrict__ sb, const uint32_t* __restrict__ sl,
                          const uint32_t* __restrict__ maxcb, const uint32_t* __restrict__ sv,
                          float* __restrict__ ob, unsigned long long* __restrict__ vbits,
                          uint32_t* __restrict__ paircnt,
                          uint32_t* __restrict__ clist, uint32_t* __restrict__ ccount) {
  int b = blockIdx.y;
  int tid = threadIdx.x;
  if (blockIdx.x == 0 && b == 0 && tid < BN) paircnt[tid] = 0u;
  int e = blockIdx.x * 256 + tid;
  int pred = 0;
  if (e < KTOT) {
    int r = b * KTOT + e;
    float scale = __fadd_rn(__uint_as_float(maxcb[b]), 1.0f);
    uint32_t c = sl[r];
    float offv = __fmul_rn((float)c, scale);
    float x1 = __fadd_rn(sb[(size_t)r * 4 + 0], offv);
    float y1 = __fadd_rn(sb[(size_t)r * 4 + 1], offv);
    float x2 = __fadd_rn(sb[(size_t)r * 4 + 2], offv);
    float y2 = __fadd_rn(sb[(size_t)r * 4 + 3], offv);
    ob[(size_t)r * 4 + 0] = x1; ob[(size_t)r * 4 + 1] = y1;
    ob[(size_t)r * 4 + 2] = x2; ob[(size_t)r * 4 + 3] = y2;
    pred = (sv[r] != 0u);
    uint32_t pos = atomicAdd(&ccount[b * NC + c], 1u);
    clist[((size_t)b * NC + c) * KTOT + pos] = (uint32_t)e;
  }
  unsigned long long m = __ballot(pred);
  int w = blockIdx.x * 4 + (tid >> 6);
  if ((tid & 63) == 0 && w < NWIN) vbits[b * NWIN + w] = m;
}

// -------- per-class pairwise IoU -> pairs, single pass + LDS staging (R20) -----
__global__ void k_pairs(const uint32_t* __restrict__ clist, const uint32_t* __restrict__ ccount,
                        const float* __restrict__ ob,
                        uint32_t* __restrict__ pairs, uint32_t* __restrict__ paircnt) {
  int b = blockIdx.y;
  int c = blockIdx.x;
  int m = (int)ccount[b * NC + c];
  if (m < 2) return;
  int tid = threadIdx.x;
  const uint32_t* cl = clist + ((size_t)b * NC + c) * KTOT;
  const float4* ob4 = (const float4*)ob + (size_t)b * KTOT;
  __shared__ uint32_t lst[KTOT];    // 18.9 KB — member indices (unordered)
  __shared__ uint32_t spc[SPC_CAP]; // 16 KB — staged pairs
  __shared__ float4 tb[256];        // 4 KB
  __shared__ uint32_t jidx[256];
  __shared__ uint32_t scnt, sbase;
  for (int t = tid; t < m; t += 256) lst[t] = cl[t];
  if (tid == 0) scnt = 0u;
  // single IoU pass, staging pairs in LDS
  for (int jt = 0; jt < m; jt += 256) {
    int jn = min(256, m - jt);
    __syncthreads();
    if (tid < jn) { uint32_t gj = lst[jt + tid]; jidx[tid] = gj; tb[tid] = ob4[gj]; }
    __syncthreads();
    for (int i = tid; i < m; i += 256) {
      uint32_t gi = lst[i];
      float4 v = ob4[gi];
      float bai = __fmul_rn(__fsub_rn(v.z, v.x), __fsub_rn(v.w, v.y));
      for (int jj = 0; jj < jn; jj++) {
        uint32_t gj = jidx[jj];
        if (gj > gi && iou_gt(v.x, v.y, v.z, v.w, bai, tb[jj])) {
          uint32_t pos = atomicAdd(&scnt, 1u);
          if (pos < SPC_CAP) spc[pos] = (gi << 13) | gj;
        }
      }
    }
  }
  __syncthreads();
  uint32_t total = scnt;
  if (total == 0u) return;
  if (tid == 0) sbase = atomicAdd(&paircnt[b], total);
  __syncthreads();
  uint32_t gb = sbase;
  uint32_t* gp = pairs + (size_t)b * PAIR_CAP;
  if (total <= (uint32_t)SPC_CAP) {
    for (uint32_t t = tid; t < total; t += 256)
      if (gb + t < PAIR_CAP) gp[gb + t] = spc[t];
  } else {
    // rare overflow: re-emit ALL pairs into the reserved range [gb, gb+total)
    if (tid == 0) scnt = 0u;
    for (int jt = 0; jt < m; jt += 256) {
      int jn = min(256, m - jt);
      __syncthreads();
      if (tid < jn) { uint32_t gj = lst[jt + tid]; jidx[tid] = gj; tb[tid] = ob4[gj]; }
      __syncthreads();
      for (int i = tid; i < m; i += 256) {
        uint32_t gi = lst[i];
        float4 v = ob4[gi];
        float bai = __fmul_rn(__fsub_rn(v.z, v.x), __fsub_rn(v.w, v.y));
        for (int jj = 0; jj < jn; jj++) {
          uint32_t gj = jidx[jj];
          if (gj > gi && iou_gt(v.x, v.y, v.z, v.w, bai, tb[jj])) {
            uint32_t pos = gb + atomicAdd(&scnt, 1u);
            if (pos < PAIR_CAP) gp[pos] = (gi << 13) | gj;
          }
        }
      }
    }
  }
}

// ---- single-wave barrier-free sparse-pair greedy NMS + fused output (R21) -----
__global__ void k_nms(const float* __restrict__ ob,
                      const unsigned long long* __restrict__ vbits,
                      const float* __restrict__ ss, const uint32_t* __restrict__ sl,
                      const float* __restrict__ sb,
                      const uint32_t* __restrict__ pairs,
                      const uint32_t* __restrict__ paircnt,
                      float* __restrict__ out) {
  int b = blockIdx.x;
  int tid = threadIdx.x;
  int lane = tid & 63;
  __shared__ unsigned long long tdl[NWIN * 64];   // within-window rows; 37888 B
  __shared__ unsigned long long svl[NWIN];
  __shared__ unsigned long long sup[NWIN];
  __shared__ unsigned long long kws[NWIN];        // keep bits (LDS, no global rt)
  __shared__ unsigned long long kwsh;
  __shared__ uint32_t plp[LDSP];                  // window-sorted pairs; 49152 B
  __shared__ uint32_t wstart[NWIN + 1];
  __shared__ uint32_t wtmp[NWIN];
  for (int i = tid; i < NWIN * 64; i += 256) tdl[i] = 0ull;
  if (tid < NWIN) { svl[tid] = vbits[b * NWIN + tid]; sup[tid] = 0ull; wtmp[tid] = 0u; }
  uint32_t npairs = paircnt[b];
  bool useP = (npairs <= (uint32_t)PAIR_CAP);
  bool useL = (npairs <= (uint32_t)LDSP);
  const uint32_t* gpl = pairs + (size_t)b * PAIR_CAP;
  __syncthreads();
  unsigned int* sup32 = (unsigned int*)sup;
  unsigned int* tdl32 = (unsigned int*)tdl;
  if (useP) {
    // setup with all 256 threads: tdl rows + cross-window bucket counts
    for (uint32_t t = tid; t < npairs; t += 256) {
      uint32_t p = gpl[t];
      int i = (int)(p >> 13), j = (int)(p & 8191u);
      if ((i >> 6) == (j >> 6)) {
        int r = ((i >> 6) * 64 + (i & 63)) * 2 + ((j & 63) >> 5);
        atomicOr(&tdl32[r], 1u << (j & 31));
      } else {
        atomicAdd(&wtmp[i >> 6], 1u);
      }
    }
    __syncthreads();
    if (tid == 0) {
      uint32_t acc = 0;
      for (int w = 0; w < NWIN; w++) { wstart[w] = acc; acc += wtmp[w]; }
      wstart[NWIN] = acc;
    }
    __syncthreads();
    if (tid < NWIN) wtmp[tid] = 0u;
    __syncthreads();
    if (useL) {
      for (uint32_t t = tid; t < npairs; t += 256) {
        uint32_t p = gpl[t];
        int i = (int)(p >> 13), j = (int)(p & 8191u);
        if ((i >> 6) == (j >> 6)) continue;
        uint32_t w = (uint32_t)(i >> 6);
        uint32_t pos = wstart[w] + atomicAdd(&wtmp[w], 1u);
        plp[pos] = p;
      }
    }
    __syncthreads();
    // main loop: single wave, no block barriers. DS ops from one wave
    // complete in program order; fence per window as belt-and-braces.
    if (tid < 64) {
      for (int w = 0; w < NWIN; w++) {
        unsigned long long row = tdl[w * 64 + lane];
        unsigned long long m = __ballot(row != 0ull);
        unsigned long long sa = sup[w];
        unsigned long long sval = svl[w];
        unsigned int rlo = (unsigned int)row, rhi = (unsigned int)(row >> 32);
        while (m) {
          int i = __ffsll((long long)m) - 1;
          m &= m - 1;
          if (((sval >> i) & 1ull) && !((sa >> i) & 1ull)) {
            unsigned int lo = (unsigned int)__builtin_amdgcn_readlane((int)rlo, i);
            unsigned int hi = (unsigned int)__builtin_amdgcn_readlane((int)rhi, i);
            sa |= (((unsigned long long)hi) << 32) | (unsigned long long)lo;
          }
        }
        unsigned long long kw = sval & ~sa;     // identical in all 64 lanes
        if (lane == 0) kws[w] = kw;
        if (useL) {
          for (uint32_t t = wstart[w] + lane; t < wstart[w + 1]; t += 64) {
            uint32_t p = plp[t];
            int i = (int)(p >> 13);
            if (!((kw >> (i & 63)) & 1ull)) continue;
            int j = (int)(p & 8191u);
            atomicOr(&sup32[j >> 5], 1u << (j & 31));
          }
        } else {
          for (uint32_t t = lane; t < npairs; t += 64) {
            uint32_t p = gpl[t];
            int i = (int)(p >> 13);
            if ((i >> 6) != w) continue;
            int j = (int)(p & 8191u);
            if ((j >> 6) == w) continue;   // same-window handled via tdl
            if (!((kw >> (i & 63)) & 1ull)) continue;
            atomicOr(&sup32[j >> 5], 1u << (j & 31));
          }
        }
        __threadfence_block();
      }
    }
  } else {
    // -------- overflow fallback: recompute IoU from ob (rare/never) --------
    int wv = tid >> 6;
    const float4* ob4 = (const float4*)ob + (size_t)b * KTOT;
    for (int w = 0; w < NWIN; w++) {
      if (wv == 0) {
        int i = w * 64 + lane;
        unsigned long long row = 0ull;
        if (i < KTOT) {
          float4 v = ob4[i];
          float bai = __fmul_rn(__fsub_rn(v.z, v.x), __fsub_rn(v.w, v.y));
          for (int jj = 0; jj < 64; jj++) {
            int j = w * 64 + jj;
            if (j > i && j < KTOT)
              row |= ((unsigned long long)iou_gt(v.x, v.y, v.z, v.w, bai, ob4[j])) << jj;
          }
        }
        unsigned long long m = __ballot(row != 0ull);
        unsigned long long sa = sup[w];
        unsigned long long sval = svl[w];
        unsigned int rlo = (unsigned int)row, rhi = (unsigned int)(row >> 32);
        while (m) {
          int i2 = __ffsll((long long)m) - 1;
          m &= m - 1;
          if (((sval >> i2) & 1ull) && !((sa >> i2) & 1ull)) {
            unsigned int lo = (unsigned int)__builtin_amdgcn_readlane((int)rlo, i2);
            unsigned int hi = (unsigned int)__builtin_amdgcn_readlane((int)rhi, i2);
            sa |= (((unsigned long long)hi) << 32) | (unsigned long long)lo;
          }
        }
        unsigned long long kw = sval & ~sa;
        if (lane == 0) { kws[w] = kw; kwsh = kw; }
      }
      __syncthreads();
      unsigned long long kw = kwsh;
      for (int ii = 0; ii < 64; ii++) {
        if (!((kw >> ii) & 1ull)) continue;
        int i = w * 64 + ii;
        if (i >= KTOT) break;
        float4 v = ob4[i];
        float bai = __fmul_rn(__fsub_rn(v.z, v.x), __fsub_rn(v.w, v.y));
        for (int j = (w + 1) * 64 + tid; j < KTOT; j += 256)
          if (iou_gt(v.x, v.y, v.z, v.w, bai, ob4[j]))
            atomicOr(&sup32[j >> 5], 1u << (j & 31));
      }
      __syncthreads();
    }
  }
  __syncthreads();
  // fused final output for image b
  for (int e = tid; e < KTOT; e += 256) {
    int r = b * KTOT + e;
    unsigned int kp = (unsigned int)((kws[e >> 6] >> (e & 63)) & 1ull);
    out[(size_t)r * 5 + 0] = sb[(size_t)r * 4 + 0];
    out[(size_t)r * 5 + 1] = sb[(size_t)r * 4 + 1];
    out[(size_t)r * 5 + 2] = sb[(size_t)r * 4 + 2];
    out[(size_t)r * 5 + 3] = sb[(size_t)r * 4 + 3];
    out[(size_t)r * 5 + 4] = ss[r];
    out[(size_t)BN * KTOT * 5 + r] = (float)sl[r];
    out[(size_t)BN * KTOT * 6 + r] = kp ? 1.0f : 0.0f;
  }
}

extern "C" void kernel_launch(void* const* d_in, const int* in_sizes, int n_in,
                              void* d_out, int out_size, void* d_ws, size_t ws_size,
                              hipStream_t stream) {
  InPtrs ip;
  for (int l = 0; l < 5; l++) {
    ip.cls[l]  = (const float*)d_in[3 * l + 0];
    ip.bbox[l] = (const float*)d_in[3 * l + 1];
    ip.ctr[l]  = (const float*)d_in[3 * l + 2];
  }

  size_t off = 0;
  auto alloc = [&](size_t n) {
    char* p = (char*)d_ws + off;
    off = (off + n + 255) & ~(size_t)255;
    return p;
  };
  const size_t SU_BYTES   = (size_t)BN * TOT * 4;                  // 2.73 MB
  const size_t HIST_BYTES = (20ull * 1024 + 20ull * 1024) * 4;     // 160 KB
  const size_t EXTRA      = 2048;    // selcnt/tiecnt/maxcb/ccount (zeroed w/ hists)
  char* r0p = (char*)alloc(((SU_BYTES + 255) & ~(size_t)255) + HIST_BYTES + EXTRA);
  uint32_t* su    = (uint32_t*)r0p;
  uint32_t* hist0 = (uint32_t*)(r0p + ((SU_BYTES + 255) & ~(size_t)255));
  uint32_t* hist1 = hist0 + 20ull * 1024;
  uint32_t* selcnt = hist1 + 20ull * 1024;
  uint32_t* tiecnt = selcnt + 20;
  uint32_t* maxcb  = tiecnt + 20;
  uint32_t* ccount = maxcb + BN;      // BN*NC = 320 u32, inside EXTRA

  uint32_t* mpfx   = (uint32_t*)alloc(20 * 4);
  uint32_t* mk     = (uint32_t*)alloc(20 * 4);
  uint32_t* selu   = (uint32_t*)alloc(20ull * 1024 * 4);
  uint32_t* seli   = (uint32_t*)alloc(20ull * 1024 * 4);
  uint32_t* tiei   = (uint32_t*)alloc(20ull * TIE_CAP * 4);
  uint32_t* tieu   = (uint32_t*)alloc(20ull * TIE_CAP * 4);
  float*    ccs    = (float*)   alloc((size_t)BN * KTOT * 4);
  uint32_t* ccl    = (uint32_t*)alloc((size_t)BN * KTOT * 4);
  uint32_t* ccv    = (uint32_t*)alloc((size_t)BN * KTOT * 4);
  float*    ccb    = (float*)   alloc((size_t)BN * KTOT * 16);
  float*    ss     = (float*)   alloc((size_t)BN * KTOT * 4);
  uint32_t* sl     = (uint32_t*)alloc((size_t)BN * KTOT * 4);
  uint32_t* sv     = (uint32_t*)alloc((size_t)BN * KTOT * 4);
  float*    sb     = (float*)   alloc((size_t)BN * KTOT * 16);
  float*    ob     = (float*)   alloc((size_t)BN * KTOT * 16);
  uint32_t* rankp  = (uint32_t*)alloc((size_t)BN * NJT * KTOT * 4); // 1.43 MB
  uint32_t* clist  = (uint32_t*)alloc((size_t)BN * NC * KTOT * 4);  // 6.04 MB
  unsigned long long* vbits = (unsigned long long*)alloc((size_t)BN * NWIN * 8);
  uint32_t* pairs   = (uint32_t*)alloc((size_t)BN * PAIR_CAP * 4);  // 2 MB
  uint32_t* paircnt = (uint32_t*)alloc(BN * 4);
  (void)ws_size; (void)in_sizes; (void)n_in; (void)out_size;

  dim3 gscan((TOT + 255) / 256, BN);
  hipMemsetAsync(hist0, 0, HIST_BYTES + EXTRA, stream);   // hists + counters + ccount
  k_score<<<dim3(36, BN), 256, 0, stream>>>(ip, su, hist0);
  k_findp<<<20, 256, 0, stream>>>(hist0, mpfx, mk, 1024, 22, 0);
  k_scan1<<<gscan, 256, 0, stream>>>(su, mpfx, hist1);
  k_findp<<<20, 256, 0, stream>>>(hist1, mpfx, mk, 1024, 12, 1);
  k_compact<<<gscan, 256, 0, stream>>>(su, mpfx, selcnt, tiecnt, selu, seli, tiei, tieu);
  k_ties<<<20, 256, 0, stream>>>(mk, tiecnt, tiei, tieu, selu, seli);
  k_emit<<<dim3(20, 4), 256, 0, stream>>>(ip, selu, seli, ccs, ccl, ccv, ccb);
  k_rank<<<dim3(19, NJT, BN), 256, 0, stream>>>(ccs, rankp);
  k_scatter<<<dim3(19, BN), 256, 0, stream>>>(ccs, ccl, ccv, ccb, rankp, ss, sl, sv, sb, maxcb);
  k_offbits<<<dim3(19, BN), 256, 0, stream>>>(sb, sl, maxcb, sv, ob, vbits, paircnt, clist, ccount);
  k_pairs<<<dim3(NC, BN), 256, 0, stream>>>(clist, ccount, ob, pairs, paircnt);
  k_nms<<<BN, 256, 0, stream>>>(ob, vbits, ss, sl, sb, pairs, paircnt, (float*)d_out);
}